// Round 1
// baseline (328.240 us; speedup 1.0000x reference)
//
#include <hip/hip_runtime.h>
#include <hip/hip_bf16.h>

// Shapes (fixed): B=4, N=2048, C=512, H=8, D=64, GROUPS=8, C/G=64
typedef __attribute__((ext_vector_type(8))) short bf16x8;
typedef __attribute__((ext_vector_type(4))) float f32x4;

__device__ __forceinline__ float bfu2f(unsigned int u) {
    return __uint_as_float(u << 16);
}
__device__ __forceinline__ unsigned short f2bfu(float f) {
    unsigned int u = __float_as_uint(f);
    u += 0x7fffu + ((u >> 16) & 1u);   // RNE
    return (unsigned short)(u >> 16);
}

// ---------------- fp32 -> bf16 conversion ----------------
__global__ __launch_bounds__(256) void cvt_f32_bf16(const float* __restrict__ src,
                                                    unsigned short* __restrict__ dst, int n4) {
    int i = blockIdx.x * 256 + threadIdx.x;
    const int stride = gridDim.x * 256;
    for (; i < n4; i += stride) {
        float4 v = reinterpret_cast<const float4*>(src)[i];
        ushort4 o;
        o.x = f2bfu(v.x); o.y = f2bfu(v.y); o.z = f2bfu(v.z); o.w = f2bfu(v.w);
        reinterpret_cast<ushort4*>(dst)[i] = o;
    }
}

// ---------------- generic NT GEMM, bf16 in, MFMA 16x16x32 ----------------
// C[m][n] = sum_k A[m][k] * B[n][k].  128x128 tile, BK=32, 4 waves (2x2 of 64x64).
// EPI: 0 = conv (bf16 out ld512, +bias), 1 = qkv scatter (q,k,vT), 2 = sigmoid bf16 (ld2048, batched),
//      3 = proj (f32 out ld512, +bias)
template <int EPI>
__global__ __launch_bounds__(256) void gemm_nt(
    const unsigned short* __restrict__ A, const unsigned short* __restrict__ B,
    void* __restrict__ C0, void* __restrict__ C1, void* __restrict__ C2,
    const float* __restrict__ bias, int K, long sA, long sB, long sC) {
    __shared__ unsigned short As[128 * 40];
    __shared__ unsigned short Bs[128 * 40];
    const int tid = threadIdx.x;
    const int l = tid & 63, w = tid >> 6;
    const int wr = w >> 1, wc = w & 1, lr = l & 15, lh = l >> 4;
    const int m0 = blockIdx.y * 128, n0 = blockIdx.x * 128;
    A += (size_t)blockIdx.z * sA;
    B += (size_t)blockIdx.z * sB;
    f32x4 acc[4][4] = {};
    const int rowS = tid >> 2, partS = tid & 3;

    for (int k0 = 0; k0 < K; k0 += 32) {
        *reinterpret_cast<uint4*>(&As[rowS * 40 + partS * 8]) =
            *reinterpret_cast<const uint4*>(A + (size_t)(m0 + rowS) * K + k0 + partS * 8);
        *reinterpret_cast<uint4*>(&As[(rowS + 64) * 40 + partS * 8]) =
            *reinterpret_cast<const uint4*>(A + (size_t)(m0 + rowS + 64) * K + k0 + partS * 8);
        *reinterpret_cast<uint4*>(&Bs[rowS * 40 + partS * 8]) =
            *reinterpret_cast<const uint4*>(B + (size_t)(n0 + rowS) * K + k0 + partS * 8);
        *reinterpret_cast<uint4*>(&Bs[(rowS + 64) * 40 + partS * 8]) =
            *reinterpret_cast<const uint4*>(B + (size_t)(n0 + rowS + 64) * K + k0 + partS * 8);
        __syncthreads();
        bf16x8 af[4], bfr[4];
#pragma unroll
        for (int i = 0; i < 4; i++)
            af[i] = *reinterpret_cast<const bf16x8*>(&As[(wr * 64 + i * 16 + lr) * 40 + lh * 8]);
#pragma unroll
        for (int i = 0; i < 4; i++)
            bfr[i] = *reinterpret_cast<const bf16x8*>(&Bs[(wc * 64 + i * 16 + lr) * 40 + lh * 8]);
#pragma unroll
        for (int mi = 0; mi < 4; mi++)
#pragma unroll
            for (int ni = 0; ni < 4; ni++)
                acc[mi][ni] = __builtin_amdgcn_mfma_f32_16x16x32_bf16(af[mi], bfr[ni], acc[mi][ni], 0, 0, 0);
        __syncthreads();
    }

#pragma unroll
    for (int mi = 0; mi < 4; mi++) {
#pragma unroll
        for (int ni = 0; ni < 4; ni++) {
#pragma unroll
            for (int r = 0; r < 4; r++) {
                const int row = m0 + wr * 64 + mi * 16 + lh * 4 + r;
                const int col = n0 + wc * 64 + ni * 16 + lr;
                float v = acc[mi][ni][r];
                if constexpr (EPI == 0) {
                    v += bias[col];
                    ((unsigned short*)C0)[(size_t)row * 512 + col] = f2bfu(v);
                } else if constexpr (EPI == 1) {
                    // col in [0,1536): j = part*512 + h*64 + d ; row = b*2048 + n
                    const int part = col >> 9, hh = (col >> 6) & 7, d = col & 63;
                    const int b = row >> 11, n = row & 2047;
                    const size_t bh = (size_t)(b * 8 + hh);
                    if (part == 0)
                        ((unsigned short*)C0)[(bh * 2048 + n) * 64 + d] = f2bfu(v);
                    else if (part == 1)
                        ((unsigned short*)C1)[(bh * 2048 + n) * 64 + d] = f2bfu(v);
                    else
                        ((unsigned short*)C2)[(bh * 64 + d) * 2048 + n] = f2bfu(v);
                } else if constexpr (EPI == 2) {
                    const float sg = 1.0f / (1.0f + __expf(-v));
                    ((unsigned short*)C0)[(size_t)blockIdx.z * sC + (size_t)row * 2048 + col] = f2bfu(sg);
                } else {
                    ((float*)C0)[(size_t)row * 512 + col] = v + bias[col];
                }
            }
        }
    }
}

// ---------------- GroupNorm stats: per (b,g) over 64 channels x 2048 positions ----------------
__global__ __launch_bounds__(256) void gn_stats(const unsigned short* __restrict__ c1,
                                                const unsigned short* __restrict__ c2,
                                                float* __restrict__ stats) {
    const int bg = blockIdx.x, b = bg >> 3, g = bg & 7;
    const int tid = threadIdx.x;
    const size_t base = ((size_t)b * 2048) * 512 + g * 64;
    float s1 = 0.f, q1 = 0.f, s2 = 0.f, q2 = 0.f;
    for (int c = tid; c < 16384; c += 256) {
        const int n = c >> 3, i8 = (c & 7) * 8;
        const size_t off = base + (size_t)n * 512 + i8;
        uint4 v1 = *reinterpret_cast<const uint4*>(c1 + off);
        uint4 v2 = *reinterpret_cast<const uint4*>(c2 + off);
        unsigned int a1[4] = {v1.x, v1.y, v1.z, v1.w};
        unsigned int a2[4] = {v2.x, v2.y, v2.z, v2.w};
#pragma unroll
        for (int j = 0; j < 4; j++) {
            float x0 = bfu2f(a1[j] & 0xffffu), x1 = bfu2f(a1[j] >> 16);
            s1 += x0 + x1; q1 += x0 * x0 + x1 * x1;
            float y0 = bfu2f(a2[j] & 0xffffu), y1 = bfu2f(a2[j] >> 16);
            s2 += y0 + y1; q2 += y0 * y0 + y1 * y1;
        }
    }
#pragma unroll
    for (int off = 32; off >= 1; off >>= 1) {
        s1 += __shfl_down(s1, off); q1 += __shfl_down(q1, off);
        s2 += __shfl_down(s2, off); q2 += __shfl_down(q2, off);
    }
    __shared__ float red[4][4];
    if ((tid & 63) == 0) {
        const int wv = tid >> 6;
        red[0][wv] = s1; red[1][wv] = q1; red[2][wv] = s2; red[3][wv] = q2;
    }
    __syncthreads();
    if (tid == 0) {
        float S1 = red[0][0] + red[0][1] + red[0][2] + red[0][3];
        float Q1 = red[1][0] + red[1][1] + red[1][2] + red[1][3];
        float S2 = red[2][0] + red[2][1] + red[2][2] + red[2][3];
        float Q2 = red[3][0] + red[3][1] + red[3][2] + red[3][3];
        const float inv = 1.0f / 131072.0f;
        float m1 = S1 * inv, m2 = S2 * inv;
        float v1 = fmaxf(Q1 * inv - m1 * m1, 0.f);
        float v2 = fmaxf(Q2 * inv - m2 * m2, 0.f);
        stats[bg * 4 + 0] = m1;
        stats[bg * 4 + 1] = rsqrtf(v1 + 1e-5f);
        stats[bg * 4 + 2] = m2;
        stats[bg * 4 + 3] = rsqrtf(v2 + 1e-5f);
    }
}

// ---------------- GroupNorm apply (in place), both tensors ----------------
__global__ __launch_bounds__(256) void gn_apply(unsigned short* __restrict__ c1,
                                                unsigned short* __restrict__ c2,
                                                const float* __restrict__ stats,
                                                const float* __restrict__ g1, const float* __restrict__ b1,
                                                const float* __restrict__ g2, const float* __restrict__ b2) {
    int i = blockIdx.x * 256 + threadIdx.x;
    const int stride = gridDim.x * 256;
    for (; i < 524288; i += stride) {           // 4*2048*512/8 chunks
        const size_t e = (size_t)i * 8;
        const int b = (int)(e >> 20);           // N*C = 2^20
        const int o = (int)(e & 511);
        const int g = o >> 6;
        const float* st = stats + ((b << 3) + g) * 4;
        const float m1 = st[0], r1 = st[1], m2 = st[2], r2 = st[3];
        uint4 v1 = *reinterpret_cast<const uint4*>(c1 + e);
        uint4 v2 = *reinterpret_cast<const uint4*>(c2 + e);
        unsigned int a1[4] = {v1.x, v1.y, v1.z, v1.w};
        unsigned int a2[4] = {v2.x, v2.y, v2.z, v2.w};
        unsigned int o1[4], o2[4];
#pragma unroll
        for (int j = 0; j < 4; j++) {
            const int oo = o + j * 2;
            float x0 = (bfu2f(a1[j] & 0xffffu) - m1) * r1 * g1[oo] + b1[oo];
            float x1 = (bfu2f(a1[j] >> 16) - m1) * r1 * g1[oo + 1] + b1[oo + 1];
            o1[j] = (unsigned int)f2bfu(x0) | ((unsigned int)f2bfu(x1) << 16);
            float y0 = (bfu2f(a2[j] & 0xffffu) - m2) * r2 * g2[oo] + b2[oo];
            float y1 = (bfu2f(a2[j] >> 16) - m2) * r2 * g2[oo + 1] + b2[oo + 1];
            o2[j] = (unsigned int)f2bfu(y0) | ((unsigned int)f2bfu(y1) << 16);
        }
        uint4 w1; w1.x = o1[0]; w1.y = o1[1]; w1.z = o1[2]; w1.w = o1[3];
        uint4 w2; w2.x = o2[0]; w2.y = o2[1]; w2.z = o2[2]; w2.w = o2[3];
        *reinterpret_cast<uint4*>(c1 + e) = w1;
        *reinterpret_cast<uint4*>(c2 + e) = w2;
    }
}

// ---------------- fused flash attention with pe_attn modulation ----------------
// grid (32, 8, 4) = (n-tile of 64 rows, h, b); block 256 = 4 waves, each wave owns 16 rows.
__global__ __launch_bounds__(256) void attn_fused(
    const unsigned short* __restrict__ qb, const unsigned short* __restrict__ kb,
    const unsigned short* __restrict__ vT, const unsigned short* __restrict__ pea,
    unsigned short* __restrict__ hbuf) {
    __shared__ unsigned short Ks[64 * 72];
    __shared__ unsigned short Vs[64 * 72];
    __shared__ unsigned short Pl[4][16 * 72];
    const int tid = threadIdx.x, l = tid & 63, w = tid >> 6;
    const int lr = l & 15, lh = l >> 4;
    const int nt = blockIdx.x, h = blockIdx.y, b = blockIdx.z;
    const size_t bh = (size_t)(b * 8 + h);
    const unsigned short* qp = qb + bh * 2048 * 64;
    const unsigned short* kp = kb + bh * 2048 * 64;
    const unsigned short* vp = vT + bh * 64 * 2048;
    const unsigned short* pep = pea + (size_t)b * 2048 * 2048;
    const int n0 = nt * 64 + w * 16;

    bf16x8 qf[2];
    qf[0] = *reinterpret_cast<const bf16x8*>(qp + (size_t)(n0 + lr) * 64 + lh * 8);
    qf[1] = *reinterpret_cast<const bf16x8*>(qp + (size_t)(n0 + lr) * 64 + 32 + lh * 8);

    f32x4 oacc[4] = {};
    float mrun[4], lrun[4];
#pragma unroll
    for (int r = 0; r < 4; r++) { mrun[r] = -1e30f; lrun[r] = 0.f; }

    const int rowS = tid >> 3, partS = tid & 7;
    for (int mt = 0; mt < 32; mt++) {
        const int m0 = mt * 64;
        *reinterpret_cast<uint4*>(&Ks[rowS * 72 + partS * 8]) =
            *reinterpret_cast<const uint4*>(kp + (size_t)(m0 + rowS) * 64 + partS * 8);
        *reinterpret_cast<uint4*>(&Vs[rowS * 72 + partS * 8]) =
            *reinterpret_cast<const uint4*>(vp + (size_t)rowS * 2048 + m0 + partS * 8);
        *reinterpret_cast<uint4*>(&Ks[(rowS + 32) * 72 + partS * 8]) =
            *reinterpret_cast<const uint4*>(kp + (size_t)(m0 + rowS + 32) * 64 + partS * 8);
        *reinterpret_cast<uint4*>(&Vs[(rowS + 32) * 72 + partS * 8]) =
            *reinterpret_cast<const uint4*>(vp + (size_t)(rowS + 32) * 2048 + m0 + partS * 8);
        __syncthreads();

        f32x4 sacc[4] = {};
#pragma unroll
        for (int mf = 0; mf < 4; mf++) {
#pragma unroll
            for (int ks = 0; ks < 2; ks++) {
                bf16x8 kf = *reinterpret_cast<const bf16x8*>(&Ks[(mf * 16 + lr) * 72 + ks * 32 + lh * 8]);
                sacc[mf] = __builtin_amdgcn_mfma_f32_16x16x32_bf16(qf[ks], kf, sacc[mf], 0, 0, 0);
            }
        }
        // logits = S * scale * pe
        float p[4][4];
#pragma unroll
        for (int mf = 0; mf < 4; mf++) {
#pragma unroll
            for (int r = 0; r < 4; r++) {
                const float pe = bfu2f(pep[(size_t)(n0 + lh * 4 + r) * 2048 + m0 + mf * 16 + lr]);
                p[mf][r] = sacc[mf][r] * 0.125f * pe;
            }
        }
        float fac[4];
#pragma unroll
        for (int r = 0; r < 4; r++) {
            float pm = fmaxf(fmaxf(p[0][r], p[1][r]), fmaxf(p[2][r], p[3][r]));
            pm = fmaxf(pm, __shfl_xor(pm, 1));
            pm = fmaxf(pm, __shfl_xor(pm, 2));
            pm = fmaxf(pm, __shfl_xor(pm, 4));
            pm = fmaxf(pm, __shfl_xor(pm, 8));
            const float mnew = fmaxf(mrun[r], pm);
            fac[r] = __expf(mrun[r] - mnew);
            float ss = 0.f;
#pragma unroll
            for (int mf = 0; mf < 4; mf++) {
                // round to bf16 BEFORE summing so numerator/denominator stay consistent
                p[mf][r] = bfu2f((unsigned int)f2bfu(__expf(p[mf][r] - mnew)));
                ss += p[mf][r];
            }
            ss += __shfl_xor(ss, 1);
            ss += __shfl_xor(ss, 2);
            ss += __shfl_xor(ss, 4);
            ss += __shfl_xor(ss, 8);
            lrun[r] = lrun[r] * fac[r] + ss;
            mrun[r] = mnew;
        }
#pragma unroll
        for (int df = 0; df < 4; df++)
#pragma unroll
            for (int r = 0; r < 4; r++) oacc[df][r] *= fac[r];
        // P -> LDS (per-wave region), then re-read as A-fragments
#pragma unroll
        for (int mf = 0; mf < 4; mf++)
#pragma unroll
            for (int r = 0; r < 4; r++)
                Pl[w][(lh * 4 + r) * 72 + mf * 16 + lr] = f2bfu(p[mf][r]);
        __syncthreads();
        bf16x8 pa0 = *reinterpret_cast<const bf16x8*>(&Pl[w][lr * 72 + lh * 8]);
        bf16x8 pa1 = *reinterpret_cast<const bf16x8*>(&Pl[w][lr * 72 + 32 + lh * 8]);
#pragma unroll
        for (int df = 0; df < 4; df++) {
            bf16x8 vf0 = *reinterpret_cast<const bf16x8*>(&Vs[(df * 16 + lr) * 72 + lh * 8]);
            bf16x8 vf1 = *reinterpret_cast<const bf16x8*>(&Vs[(df * 16 + lr) * 72 + 32 + lh * 8]);
            oacc[df] = __builtin_amdgcn_mfma_f32_16x16x32_bf16(pa0, vf0, oacc[df], 0, 0, 0);
            oacc[df] = __builtin_amdgcn_mfma_f32_16x16x32_bf16(pa1, vf1, oacc[df], 0, 0, 0);
        }
        __syncthreads();
    }
    const size_t outb = ((size_t)b * 2048 + n0 + lh * 4) * 512 + h * 64 + lr;
#pragma unroll
    for (int df = 0; df < 4; df++)
#pragma unroll
        for (int r = 0; r < 4; r++)
            hbuf[outb + (size_t)r * 512 + df * 16] = f2bfu(oacc[df][r] / lrun[r]);
}

extern "C" void kernel_launch(void* const* d_in, const int* in_sizes, int n_in,
                              void* d_out, int out_size, void* d_ws, size_t ws_size,
                              hipStream_t stream) {
    const float* x       = (const float*)d_in[0];
    const float* pe      = (const float*)d_in[1];
    const float* qkv_w   = (const float*)d_in[2];
    const float* proj_w  = (const float*)d_in[3];
    const float* proj_b  = (const float*)d_in[4];
    const float* conv1_w = (const float*)d_in[5];
    const float* conv1_b = (const float*)d_in[6];
    const float* gn1_g   = (const float*)d_in[7];
    const float* gn1_b   = (const float*)d_in[8];
    const float* conv2_w = (const float*)d_in[9];
    const float* conv2_b = (const float*)d_in[10];
    const float* gn2_g   = (const float*)d_in[11];
    const float* gn2_b   = (const float*)d_in[12];
    float* out = (float*)d_out;

    char* ws = (char*)d_ws;
    size_t off = 0;
    auto alloc = [&](size_t bytes) -> void* {
        void* p = ws + off;
        off += (bytes + 255) & ~(size_t)255;
        return p;
    };
    unsigned short* xb     = (unsigned short*)alloc(8388608);   // x bf16 [B*N, C]
    unsigned short* peb    = (unsigned short*)alloc(8388608);   // pe bf16
    unsigned short* qkvwb  = (unsigned short*)alloc(1572864);   // qkv_w bf16 [1536,512]
    unsigned short* projwb = (unsigned short*)alloc(524288);
    unsigned short* w1b    = (unsigned short*)alloc(524288);
    unsigned short* w2b    = (unsigned short*)alloc(524288);
    unsigned short* c1b    = (unsigned short*)alloc(8388608);   // conv1 out -> p1 (in place GN)
    unsigned short* c2b    = (unsigned short*)alloc(8388608);
    unsigned short* qbuf   = (unsigned short*)alloc(8388608);   // [B,H,N,D]
    unsigned short* kbuf   = (unsigned short*)alloc(8388608);
    unsigned short* vtb    = (unsigned short*)alloc(8388608);   // [B,H,D,N]
    unsigned short* peatt  = (unsigned short*)alloc(33554432);  // [B,N,N] bf16
    unsigned short* hbuf   = (unsigned short*)alloc(8388608);   // [B,N,C] bf16
    float* stats           = (float*)alloc(512);

    dim3 blk(256);
    cvt_f32_bf16<<<1024, blk, 0, stream>>>(x, xb, 1048576);
    cvt_f32_bf16<<<1024, blk, 0, stream>>>(pe, peb, 1048576);
    cvt_f32_bf16<<<256, blk, 0, stream>>>(qkv_w, qkvwb, 196608);
    cvt_f32_bf16<<<128, blk, 0, stream>>>(proj_w, projwb, 65536);
    cvt_f32_bf16<<<128, blk, 0, stream>>>(conv1_w, w1b, 65536);
    cvt_f32_bf16<<<128, blk, 0, stream>>>(conv2_w, w2b, 65536);

    // conv1/conv2 (per-position linear over channels), bias, bf16 out [B,N,C]
    gemm_nt<0><<<dim3(4, 64, 1), blk, 0, stream>>>(peb, w1b, c1b, nullptr, nullptr, conv1_b, 512, 0, 0, 0);
    gemm_nt<0><<<dim3(4, 64, 1), blk, 0, stream>>>(peb, w2b, c2b, nullptr, nullptr, conv2_b, 512, 0, 0, 0);
    gn_stats<<<32, blk, 0, stream>>>(c1b, c2b, stats);
    gn_apply<<<1024, blk, 0, stream>>>(c1b, c2b, stats, gn1_g, gn1_b, gn2_g, gn2_b);
    // qkv = x @ qkv_w.T, scattered to q,k [B,H,N,D] and vT [B,H,D,N]
    gemm_nt<1><<<dim3(12, 64, 1), blk, 0, stream>>>(xb, qkvwb, qbuf, kbuf, vtb, nullptr, 512, 0, 0, 0);
    // pe_attn[b] = sigmoid(p1[b] @ p2[b]^T), batched over b
    gemm_nt<2><<<dim3(16, 16, 4), blk, 0, stream>>>(c1b, c2b, peatt, nullptr, nullptr, nullptr, 512,
                                                    1048576, 1048576, 4194304);
    attn_fused<<<dim3(32, 8, 4), blk, 0, stream>>>(qbuf, kbuf, vtb, peatt, hbuf);
    // proj: out = h @ proj_w.T + proj_b (f32)
    gemm_nt<3><<<dim3(4, 64, 1), blk, 0, stream>>>(hbuf, projwb, out, nullptr, nullptr, proj_b, 512, 0, 0, 0);
}

// Round 2
// 289.839 us; speedup vs baseline: 1.1325x; 1.1325x over previous
//
#include <hip/hip_runtime.h>
#include <hip/hip_bf16.h>

// Shapes (fixed): B=4, N=2048, C=512, H=8, D=64, GROUPS=8, C/G=64
typedef __attribute__((ext_vector_type(8))) short bf16x8;
typedef __attribute__((ext_vector_type(4))) float f32x4;

__device__ __forceinline__ float bfu2f(unsigned int u) {
    return __uint_as_float(u << 16);
}
__device__ __forceinline__ unsigned short f2bfu(float f) {
    unsigned int u = __float_as_uint(f);
    u += 0x7fffu + ((u >> 16) & 1u);   // RNE
    return (unsigned short)(u >> 16);
}

// ---------------- fp32 -> bf16 conversion ----------------
__global__ __launch_bounds__(256) void cvt_f32_bf16(const float* __restrict__ src,
                                                    unsigned short* __restrict__ dst, int n4) {
    int i = blockIdx.x * 256 + threadIdx.x;
    const int stride = gridDim.x * 256;
    for (; i < n4; i += stride) {
        float4 v = reinterpret_cast<const float4*>(src)[i];
        ushort4 o;
        o.x = f2bfu(v.x); o.y = f2bfu(v.y); o.z = f2bfu(v.z); o.w = f2bfu(v.w);
        reinterpret_cast<ushort4*>(dst)[i] = o;
    }
}

// ---------------- generic NT GEMM, bf16 in, MFMA 16x16x32 ----------------
// C[m][n] = sum_k A[m][k] * B[n][k].  128x128 tile, BK=32, 4 waves (2x2 of 64x64).
// EPI: 0 = conv (bf16 out ld512, +bias), 1 = qkv scatter (q*0.125, k, vT), 2 = sigmoid bf16 (ld2048, batched),
//      3 = proj (f32 out ld512, +bias)
template <int EPI>
__global__ __launch_bounds__(256) void gemm_nt(
    const unsigned short* __restrict__ A, const unsigned short* __restrict__ B,
    void* __restrict__ C0, void* __restrict__ C1, void* __restrict__ C2,
    const float* __restrict__ bias, int K, long sA, long sB, long sC) {
    __shared__ unsigned short As[128 * 40];
    __shared__ unsigned short Bs[128 * 40];
    const int tid = threadIdx.x;
    const int l = tid & 63, w = tid >> 6;
    const int wr = w >> 1, wc = w & 1, lr = l & 15, lh = l >> 4;
    const int m0 = blockIdx.y * 128, n0 = blockIdx.x * 128;
    A += (size_t)blockIdx.z * sA;
    B += (size_t)blockIdx.z * sB;
    f32x4 acc[4][4] = {};
    const int rowS = tid >> 2, partS = tid & 3;

    for (int k0 = 0; k0 < K; k0 += 32) {
        *reinterpret_cast<uint4*>(&As[rowS * 40 + partS * 8]) =
            *reinterpret_cast<const uint4*>(A + (size_t)(m0 + rowS) * K + k0 + partS * 8);
        *reinterpret_cast<uint4*>(&As[(rowS + 64) * 40 + partS * 8]) =
            *reinterpret_cast<const uint4*>(A + (size_t)(m0 + rowS + 64) * K + k0 + partS * 8);
        *reinterpret_cast<uint4*>(&Bs[rowS * 40 + partS * 8]) =
            *reinterpret_cast<const uint4*>(B + (size_t)(n0 + rowS) * K + k0 + partS * 8);
        *reinterpret_cast<uint4*>(&Bs[(rowS + 64) * 40 + partS * 8]) =
            *reinterpret_cast<const uint4*>(B + (size_t)(n0 + rowS + 64) * K + k0 + partS * 8);
        __syncthreads();
        bf16x8 af[4], bfr[4];
#pragma unroll
        for (int i = 0; i < 4; i++)
            af[i] = *reinterpret_cast<const bf16x8*>(&As[(wr * 64 + i * 16 + lr) * 40 + lh * 8]);
#pragma unroll
        for (int i = 0; i < 4; i++)
            bfr[i] = *reinterpret_cast<const bf16x8*>(&Bs[(wc * 64 + i * 16 + lr) * 40 + lh * 8]);
#pragma unroll
        for (int mi = 0; mi < 4; mi++)
#pragma unroll
            for (int ni = 0; ni < 4; ni++)
                acc[mi][ni] = __builtin_amdgcn_mfma_f32_16x16x32_bf16(af[mi], bfr[ni], acc[mi][ni], 0, 0, 0);
        __syncthreads();
    }

#pragma unroll
    for (int mi = 0; mi < 4; mi++) {
#pragma unroll
        for (int ni = 0; ni < 4; ni++) {
#pragma unroll
            for (int r = 0; r < 4; r++) {
                const int row = m0 + wr * 64 + mi * 16 + lh * 4 + r;
                const int col = n0 + wc * 64 + ni * 16 + lr;
                float v = acc[mi][ni][r];
                if constexpr (EPI == 0) {
                    v += bias[col];
                    ((unsigned short*)C0)[(size_t)row * 512 + col] = f2bfu(v);
                } else if constexpr (EPI == 1) {
                    // col in [0,1536): j = part*512 + h*64 + d ; row = b*2048 + n
                    const int part = col >> 9, hh = (col >> 6) & 7, d = col & 63;
                    const int b = row >> 11, n = row & 2047;
                    const size_t bh = (size_t)(b * 8 + hh);
                    if (part == 0)
                        ((unsigned short*)C0)[(bh * 2048 + n) * 64 + d] = f2bfu(v * 0.125f);
                    else if (part == 1)
                        ((unsigned short*)C1)[(bh * 2048 + n) * 64 + d] = f2bfu(v);
                    else
                        ((unsigned short*)C2)[(bh * 64 + d) * 2048 + n] = f2bfu(v);
                } else if constexpr (EPI == 2) {
                    const float sg = 1.0f / (1.0f + __expf(-v));
                    ((unsigned short*)C0)[(size_t)blockIdx.z * sC + (size_t)row * 2048 + col] = f2bfu(sg);
                } else {
                    ((float*)C0)[(size_t)row * 512 + col] = v + bias[col];
                }
            }
        }
    }
}

// ---------------- GroupNorm partial stats: 256 blocks = (b,g,chunk) ----------------
__global__ __launch_bounds__(256) void gn_stats_part(const unsigned short* __restrict__ c1,
                                                     const unsigned short* __restrict__ c2,
                                                     float* __restrict__ part) {
    const int bgc = blockIdx.x;                 // b*64 + g*8 + ch
    const int b = bgc >> 6, g = (bgc >> 3) & 7, ch = bgc & 7;
    const int tid = threadIdx.x;
    const size_t base = ((size_t)b * 2048 + ch * 256) * 512 + g * 64;
    float s1 = 0.f, q1 = 0.f, s2 = 0.f, q2 = 0.f;
    for (int c = tid; c < 2048; c += 256) {     // 256 rows x 8 vec8 chunks
        const int n = c >> 3, i8 = (c & 7) * 8;
        const size_t off = base + (size_t)n * 512 + i8;
        uint4 v1 = *reinterpret_cast<const uint4*>(c1 + off);
        uint4 v2 = *reinterpret_cast<const uint4*>(c2 + off);
        unsigned int a1[4] = {v1.x, v1.y, v1.z, v1.w};
        unsigned int a2[4] = {v2.x, v2.y, v2.z, v2.w};
#pragma unroll
        for (int j = 0; j < 4; j++) {
            float x0 = bfu2f(a1[j] & 0xffffu), x1 = bfu2f(a1[j] >> 16);
            s1 += x0 + x1; q1 += x0 * x0 + x1 * x1;
            float y0 = bfu2f(a2[j] & 0xffffu), y1 = bfu2f(a2[j] >> 16);
            s2 += y0 + y1; q2 += y0 * y0 + y1 * y1;
        }
    }
#pragma unroll
    for (int off = 32; off >= 1; off >>= 1) {
        s1 += __shfl_down(s1, off); q1 += __shfl_down(q1, off);
        s2 += __shfl_down(s2, off); q2 += __shfl_down(q2, off);
    }
    __shared__ float red[4][4];
    if ((tid & 63) == 0) {
        const int wv = tid >> 6;
        red[0][wv] = s1; red[1][wv] = q1; red[2][wv] = s2; red[3][wv] = q2;
    }
    __syncthreads();
    if (tid == 0) {
        part[bgc * 4 + 0] = red[0][0] + red[0][1] + red[0][2] + red[0][3];
        part[bgc * 4 + 1] = red[1][0] + red[1][1] + red[1][2] + red[1][3];
        part[bgc * 4 + 2] = red[2][0] + red[2][1] + red[2][2] + red[2][3];
        part[bgc * 4 + 3] = red[3][0] + red[3][1] + red[3][2] + red[3][3];
    }
}

__global__ __launch_bounds__(64) void gn_finish(const float* __restrict__ part,
                                                float* __restrict__ stats) {
    const int t = threadIdx.x;
    if (t < 32) {
        float S1 = 0.f, Q1 = 0.f, S2 = 0.f, Q2 = 0.f;
        for (int ch = 0; ch < 8; ch++) {
            const float* p = part + ((t << 3) + ch) * 4;
            S1 += p[0]; Q1 += p[1]; S2 += p[2]; Q2 += p[3];
        }
        const float inv = 1.0f / 131072.0f;
        float m1 = S1 * inv, m2 = S2 * inv;
        float v1 = fmaxf(Q1 * inv - m1 * m1, 0.f);
        float v2 = fmaxf(Q2 * inv - m2 * m2, 0.f);
        stats[t * 4 + 0] = m1;
        stats[t * 4 + 1] = rsqrtf(v1 + 1e-5f);
        stats[t * 4 + 2] = m2;
        stats[t * 4 + 3] = rsqrtf(v2 + 1e-5f);
    }
}

// ---------------- GroupNorm apply (in place), both tensors ----------------
__global__ __launch_bounds__(256) void gn_apply(unsigned short* __restrict__ c1,
                                                unsigned short* __restrict__ c2,
                                                const float* __restrict__ stats,
                                                const float* __restrict__ g1, const float* __restrict__ b1,
                                                const float* __restrict__ g2, const float* __restrict__ b2) {
    int i = blockIdx.x * 256 + threadIdx.x;
    const int stride = gridDim.x * 256;
    for (; i < 524288; i += stride) {           // 4*2048*512/8 chunks
        const size_t e = (size_t)i * 8;
        const int b = (int)(e >> 20);           // N*C = 2^20
        const int o = (int)(e & 511);
        const int g = o >> 6;
        const float* st = stats + ((b << 3) + g) * 4;
        const float m1 = st[0], r1 = st[1], m2 = st[2], r2 = st[3];
        uint4 v1 = *reinterpret_cast<const uint4*>(c1 + e);
        uint4 v2 = *reinterpret_cast<const uint4*>(c2 + e);
        unsigned int a1[4] = {v1.x, v1.y, v1.z, v1.w};
        unsigned int a2[4] = {v2.x, v2.y, v2.z, v2.w};
        unsigned int o1[4], o2[4];
#pragma unroll
        for (int j = 0; j < 4; j++) {
            const int oo = o + j * 2;
            float x0 = (bfu2f(a1[j] & 0xffffu) - m1) * r1 * g1[oo] + b1[oo];
            float x1 = (bfu2f(a1[j] >> 16) - m1) * r1 * g1[oo + 1] + b1[oo + 1];
            o1[j] = (unsigned int)f2bfu(x0) | ((unsigned int)f2bfu(x1) << 16);
            float y0 = (bfu2f(a2[j] & 0xffffu) - m2) * r2 * g2[oo] + b2[oo];
            float y1 = (bfu2f(a2[j] >> 16) - m2) * r2 * g2[oo + 1] + b2[oo + 1];
            o2[j] = (unsigned int)f2bfu(y0) | ((unsigned int)f2bfu(y1) << 16);
        }
        uint4 w1; w1.x = o1[0]; w1.y = o1[1]; w1.z = o1[2]; w1.w = o1[3];
        uint4 w2; w2.x = o2[0]; w2.y = o2[1]; w2.z = o2[2]; w2.w = o2[3];
        *reinterpret_cast<uint4*>(c1 + e) = w1;
        *reinterpret_cast<uint4*>(c2 + e) = w2;
    }
}

// ---------------- fused flash attention, swapped-QK^T, peT from LDS ----------------
// grid (32, 8, 4) = (n-tile of 64 rows, h, b); block 256 = 4 waves, wave w owns q-rows [16w,16w+16).
// S^T = mfma(K,Q): lane holds q = lane&15, k = 16*mf + 4*lh + r  -> softmax is lane-local + 2 shfl.
// K/V^T/peT tiles staged via global_load_lds with pre-swizzled source (XOR 16B slot by row&7).
__global__ __launch_bounds__(256) void attn_fused(
    const unsigned short* __restrict__ qb, const unsigned short* __restrict__ kb,
    const unsigned short* __restrict__ vT, const unsigned short* __restrict__ peaT,
    unsigned short* __restrict__ hbuf) {
    __shared__ unsigned short Ks[2][64 * 64];
    __shared__ unsigned short Vs[2][64 * 64];
    __shared__ unsigned short Pe[2][64 * 64];
    __shared__ unsigned short Pl[4][16 * 72];
    const int tid = threadIdx.x, l = tid & 63, w = tid >> 6;
    const int lr = l & 15, lh = l >> 4;
    const int nt = blockIdx.x, h = blockIdx.y, b = blockIdx.z;
    const size_t bh = (size_t)(b * 8 + h);
    const unsigned short* qp = qb + bh * 2048 * 64;
    const unsigned short* kp = kb + bh * 2048 * 64;
    const unsigned short* vp = vT + bh * 64 * 2048;
    const unsigned short* pepT = peaT + (size_t)b * 2048 * 2048;
    const int n0 = nt * 64;

    // Q B-fragments (pre-scaled by 0.125 at QKV epilogue)
    bf16x8 qf[2];
    qf[0] = *reinterpret_cast<const bf16x8*>(qp + (size_t)(n0 + 16 * w + lr) * 64 + lh * 8);
    qf[1] = *reinterpret_cast<const bf16x8*>(qp + (size_t)(n0 + 16 * w + lr) * 64 + 32 + lh * 8);

    // swizzled read columns (shorts) for K/V A-fragments
    const int swz = (lr & 7) << 4;                       // byte XOR
    const int colK0 = ((16 * lh) ^ swz) >> 1;
    const int colK1 = ((64 + 16 * lh) ^ swz) >> 1;
    const int pecol = (16 * w + lr) * 2;                 // byte col in pe tile row

    f32x4 oacc[4] = {};
    float mrun = -1e30f, lrun = 0.f;

    // async staging: lane -> (row = base + l>>3, slot = l&7), source col-slot = slot ^ (row&7)
    const int srow = l >> 3, sslot = l & 7;
    auto stage = [&](int bufi, int m0) {
#pragma unroll
        for (int i = 0; i < 2; i++) {
            const int row = w * 16 + i * 8 + srow;
            const int cs = (sslot ^ (row & 7)) * 8;
            const int ldsoff = (w * 16 + i * 8) * 64;
            __builtin_amdgcn_global_load_lds(
                (const __attribute__((address_space(1))) void*)(kp + (size_t)(m0 + row) * 64 + cs),
                (__attribute__((address_space(3))) void*)&Ks[bufi][ldsoff], 16, 0, 0);
            __builtin_amdgcn_global_load_lds(
                (const __attribute__((address_space(1))) void*)(vp + (size_t)row * 2048 + m0 + cs),
                (__attribute__((address_space(3))) void*)&Vs[bufi][ldsoff], 16, 0, 0);
            __builtin_amdgcn_global_load_lds(
                (const __attribute__((address_space(1))) void*)(pepT + (size_t)(m0 + row) * 2048 + n0 + cs),
                (__attribute__((address_space(3))) void*)&Pe[bufi][ldsoff], 16, 0, 0);
        }
    };

    stage(0, 0);
    asm volatile("s_waitcnt vmcnt(0)" ::: "memory");
    __syncthreads();

    for (int mt = 0; mt < 32; mt++) {
        const int cur = mt & 1;
        if (mt + 1 < 32) stage(cur ^ 1, (mt + 1) * 64);
        const unsigned short* Kb = Ks[cur];
        const unsigned short* Vb = Vs[cur];
        const unsigned short* Peb = Pe[cur];

        // S^T: rows k (4 frags), cols q
        f32x4 st[4] = {};
#pragma unroll
        for (int mf = 0; mf < 4; mf++) {
            bf16x8 kf0 = *reinterpret_cast<const bf16x8*>(&Kb[(mf * 16 + lr) * 64 + colK0]);
            bf16x8 kf1 = *reinterpret_cast<const bf16x8*>(&Kb[(mf * 16 + lr) * 64 + colK1]);
            st[mf] = __builtin_amdgcn_mfma_f32_16x16x32_bf16(kf0, qf[0], st[mf], 0, 0, 0);
            st[mf] = __builtin_amdgcn_mfma_f32_16x16x32_bf16(kf1, qf[1], st[mf], 0, 0, 0);
        }
        // logits = S^T * peT  (scale already folded into Q)
        float p[4][4];
#pragma unroll
        for (int mf = 0; mf < 4; mf++) {
#pragma unroll
            for (int r = 0; r < 4; r++) {
                const int k = mf * 16 + lh * 4 + r;
                const int cb = pecol ^ ((k & 7) << 4);
                p[mf][r] = st[mf][r] * bfu2f(Peb[k * 64 + (cb >> 1)]);
            }
        }
        // row max (lane-local tree + butterfly over lh groups)
        float pm = p[0][0];
#pragma unroll
        for (int mf = 0; mf < 4; mf++)
#pragma unroll
            for (int r = 0; r < 4; r++) pm = fmaxf(pm, p[mf][r]);
        pm = fmaxf(pm, __shfl_xor(pm, 16));
        pm = fmaxf(pm, __shfl_xor(pm, 32));
        // defer-max: only rescale when max grew past threshold
        if (__any(pm > mrun + 8.f)) {
            const float mnew = fmaxf(mrun, pm);
            const float fac = __expf(mrun - mnew);
            lrun *= fac;
#pragma unroll
            for (int df = 0; df < 4; df++)
#pragma unroll
                for (int r = 0; r < 4; r++) oacc[df][r] *= fac;
            mrun = mnew;
        }
        float ss = 0.f;
        unsigned int pk[8];
#pragma unroll
        for (int mf = 0; mf < 4; mf++) {
#pragma unroll
            for (int t = 0; t < 2; t++) {
                const float a = __expf(p[mf][2 * t] - mrun);
                const float c = __expf(p[mf][2 * t + 1] - mrun);
                const unsigned int ua = f2bfu(a), uc = f2bfu(c);
                pk[mf * 2 + t] = ua | (uc << 16);
                ss += bfu2f(ua) + bfu2f(uc);   // sum the ROUNDED values (num/denom consistent)
            }
        }
        ss += __shfl_xor(ss, 16);
        ss += __shfl_xor(ss, 32);
        lrun += ss;
        // P -> per-wave LDS in [q][k] layout (u32 pairs), re-read as B-fragments
#pragma unroll
        for (int mf = 0; mf < 4; mf++)
#pragma unroll
            for (int t = 0; t < 2; t++)
                *reinterpret_cast<unsigned int*>(&Pl[w][lr * 72 + mf * 16 + lh * 4 + 2 * t]) = pk[mf * 2 + t];
        bf16x8 pb0 = *reinterpret_cast<const bf16x8*>(&Pl[w][lr * 72 + lh * 8]);
        bf16x8 pb1 = *reinterpret_cast<const bf16x8*>(&Pl[w][lr * 72 + 32 + lh * 8]);
        // out^T[d][q] += sum_k V^T[d][k] * P[q][k]
#pragma unroll
        for (int df = 0; df < 4; df++) {
            bf16x8 vf0 = *reinterpret_cast<const bf16x8*>(&Vb[(df * 16 + lr) * 64 + colK0]);
            bf16x8 vf1 = *reinterpret_cast<const bf16x8*>(&Vb[(df * 16 + lr) * 64 + colK1]);
            oacc[df] = __builtin_amdgcn_mfma_f32_16x16x32_bf16(vf0, pb0, oacc[df], 0, 0, 0);
            oacc[df] = __builtin_amdgcn_mfma_f32_16x16x32_bf16(vf1, pb1, oacc[df], 0, 0, 0);
        }
        if (mt + 1 < 32) {
            asm volatile("s_waitcnt vmcnt(0)" ::: "memory");
            __syncthreads();
        }
    }
    const float inv = 1.0f / lrun;
    const size_t base = ((size_t)b * 2048 + n0 + 16 * w + lr) * 512 + h * 64;
#pragma unroll
    for (int df = 0; df < 4; df++) {
#pragma unroll
        for (int t = 0; t < 2; t++) {
            const unsigned int ua = f2bfu(oacc[df][2 * t] * inv);
            const unsigned int uc = f2bfu(oacc[df][2 * t + 1] * inv);
            *reinterpret_cast<unsigned int*>(&hbuf[base + 16 * df + 4 * lh + 2 * t]) = ua | (uc << 16);
        }
    }
}

extern "C" void kernel_launch(void* const* d_in, const int* in_sizes, int n_in,
                              void* d_out, int out_size, void* d_ws, size_t ws_size,
                              hipStream_t stream) {
    const float* x       = (const float*)d_in[0];
    const float* pe      = (const float*)d_in[1];
    const float* qkv_w   = (const float*)d_in[2];
    const float* proj_w  = (const float*)d_in[3];
    const float* proj_b  = (const float*)d_in[4];
    const float* conv1_w = (const float*)d_in[5];
    const float* conv1_b = (const float*)d_in[6];
    const float* gn1_g   = (const float*)d_in[7];
    const float* gn1_b   = (const float*)d_in[8];
    const float* conv2_w = (const float*)d_in[9];
    const float* conv2_b = (const float*)d_in[10];
    const float* gn2_g   = (const float*)d_in[11];
    const float* gn2_b   = (const float*)d_in[12];
    float* out = (float*)d_out;

    char* ws = (char*)d_ws;
    size_t off = 0;
    auto alloc = [&](size_t bytes) -> void* {
        void* p = ws + off;
        off += (bytes + 255) & ~(size_t)255;
        return p;
    };
    unsigned short* xb     = (unsigned short*)alloc(8388608);   // x bf16 [B*N, C]
    unsigned short* peb    = (unsigned short*)alloc(8388608);   // pe bf16
    unsigned short* qkvwb  = (unsigned short*)alloc(1572864);   // qkv_w bf16 [1536,512]
    unsigned short* projwb = (unsigned short*)alloc(524288);
    unsigned short* w1b    = (unsigned short*)alloc(524288);
    unsigned short* w2b    = (unsigned short*)alloc(524288);
    unsigned short* c1b    = (unsigned short*)alloc(8388608);   // conv1 out -> p1 (in place GN)
    unsigned short* c2b    = (unsigned short*)alloc(8388608);
    unsigned short* qbuf   = (unsigned short*)alloc(8388608);   // [B,H,N,D] (q pre-scaled)
    unsigned short* kbuf   = (unsigned short*)alloc(8388608);
    unsigned short* vtb    = (unsigned short*)alloc(8388608);   // [B,H,D,N]
    unsigned short* peatt  = (unsigned short*)alloc(33554432);  // peT = pe_attn^T [B,M,N] bf16
    unsigned short* hbuf   = (unsigned short*)alloc(8388608);   // [B,N,C] bf16
    float* stats           = (float*)alloc(512);
    float* part            = (float*)alloc(4096);

    dim3 blk(256);
    cvt_f32_bf16<<<1024, blk, 0, stream>>>(x, xb, 1048576);
    cvt_f32_bf16<<<1024, blk, 0, stream>>>(pe, peb, 1048576);
    cvt_f32_bf16<<<256, blk, 0, stream>>>(qkv_w, qkvwb, 196608);
    cvt_f32_bf16<<<128, blk, 0, stream>>>(proj_w, projwb, 65536);
    cvt_f32_bf16<<<128, blk, 0, stream>>>(conv1_w, w1b, 65536);
    cvt_f32_bf16<<<128, blk, 0, stream>>>(conv2_w, w2b, 65536);

    // conv1/conv2 (per-position linear over channels), bias, bf16 out [B,N,C]
    gemm_nt<0><<<dim3(4, 64, 1), blk, 0, stream>>>(peb, w1b, c1b, nullptr, nullptr, conv1_b, 512, 0, 0, 0);
    gemm_nt<0><<<dim3(4, 64, 1), blk, 0, stream>>>(peb, w2b, c2b, nullptr, nullptr, conv2_b, 512, 0, 0, 0);
    gn_stats_part<<<256, blk, 0, stream>>>(c1b, c2b, part);
    gn_finish<<<1, 64, 0, stream>>>(part, stats);
    gn_apply<<<1024, blk, 0, stream>>>(c1b, c2b, stats, gn1_g, gn1_b, gn2_g, gn2_b);
    // qkv = x @ qkv_w.T, scattered to q (x0.125), k [B,H,N,D] and vT [B,H,D,N]
    gemm_nt<1><<<dim3(12, 64, 1), blk, 0, stream>>>(xb, qkvwb, qbuf, kbuf, vtb, nullptr, 512, 0, 0, 0);
    // peT[b][m][n] = sigmoid(sum_k p2[m][k] p1[n][k]) = pe_attn[n][m]  (operands swapped on purpose)
    gemm_nt<2><<<dim3(16, 16, 4), blk, 0, stream>>>(c2b, c1b, peatt, nullptr, nullptr, nullptr, 512,
                                                    1048576, 1048576, 4194304);
    attn_fused<<<dim3(32, 8, 4), blk, 0, stream>>>(qbuf, kbuf, vtb, peatt, hbuf);
    // proj: out = h @ proj_w.T + proj_b (f32)
    gemm_nt<3><<<dim3(4, 64, 1), blk, 0, stream>>>(hbuf, projwb, out, nullptr, nullptr, proj_b, 512, 0, 0, 0);
}

// Round 4
// 264.972 us; speedup vs baseline: 1.2388x; 1.0939x over previous
//
#include <hip/hip_runtime.h>
#include <hip/hip_bf16.h>

// Shapes (fixed): B=4, N=2048, C=512, H=8, D=64, GROUPS=8, C/G=64
typedef __attribute__((ext_vector_type(8))) short bf16x8;
typedef __attribute__((ext_vector_type(4))) float f32x4;

__device__ __forceinline__ float bfu2f(unsigned int u) {
    return __uint_as_float(u << 16);
}
__device__ __forceinline__ unsigned short f2bfu(float f) {
    unsigned int u = __float_as_uint(f);
    u += 0x7fffu + ((u >> 16) & 1u);   // RNE
    return (unsigned short)(u >> 16);
}

// ---------------- fp32 -> bf16 conversion ----------------
__global__ __launch_bounds__(256) void cvt_f32_bf16(const float* __restrict__ src,
                                                    unsigned short* __restrict__ dst, int n4) {
    int i = blockIdx.x * 256 + threadIdx.x;
    const int stride = gridDim.x * 256;
    for (; i < n4; i += stride) {
        float4 v = reinterpret_cast<const float4*>(src)[i];
        ushort4 o;
        o.x = f2bfu(v.x); o.y = f2bfu(v.y); o.z = f2bfu(v.z); o.w = f2bfu(v.w);
        reinterpret_cast<ushort4*>(dst)[i] = o;
    }
}

// ---------------- generic NT GEMM, bf16 in, MFMA 16x16x32 ----------------
// C[m][n] = sum_k A[m][k] * B[n][k].  128x128 tile, BK=32, 4 waves (2x2 of 64x64).
// EPI: 0 = conv (bf16 out ld512, +bias), 1 = qkv scatter (q*0.125*log2e, k, vT),
//      2 = sigmoid bf16 (ld2048, batched), 3 = proj (f32 out ld512, +bias)
template <int EPI>
__global__ __launch_bounds__(256) void gemm_nt(
    const unsigned short* __restrict__ A, const unsigned short* __restrict__ B,
    void* __restrict__ C0, void* __restrict__ C1, void* __restrict__ C2,
    const float* __restrict__ bias, int K, long sA, long sB, long sC) {
    __shared__ unsigned short As[128 * 40];
    __shared__ unsigned short Bs[128 * 40];
    const int tid = threadIdx.x;
    const int l = tid & 63, w = tid >> 6;
    const int wr = w >> 1, wc = w & 1, lr = l & 15, lh = l >> 4;
    const int m0 = blockIdx.y * 128, n0 = blockIdx.x * 128;
    A += (size_t)blockIdx.z * sA;
    B += (size_t)blockIdx.z * sB;
    f32x4 acc[4][4] = {};
    const int rowS = tid >> 2, partS = tid & 3;

    for (int k0 = 0; k0 < K; k0 += 32) {
        *reinterpret_cast<uint4*>(&As[rowS * 40 + partS * 8]) =
            *reinterpret_cast<const uint4*>(A + (size_t)(m0 + rowS) * K + k0 + partS * 8);
        *reinterpret_cast<uint4*>(&As[(rowS + 64) * 40 + partS * 8]) =
            *reinterpret_cast<const uint4*>(A + (size_t)(m0 + rowS + 64) * K + k0 + partS * 8);
        *reinterpret_cast<uint4*>(&Bs[rowS * 40 + partS * 8]) =
            *reinterpret_cast<const uint4*>(B + (size_t)(n0 + rowS) * K + k0 + partS * 8);
        *reinterpret_cast<uint4*>(&Bs[(rowS + 64) * 40 + partS * 8]) =
            *reinterpret_cast<const uint4*>(B + (size_t)(n0 + rowS + 64) * K + k0 + partS * 8);
        __syncthreads();
        bf16x8 af[4], bfr[4];
#pragma unroll
        for (int i = 0; i < 4; i++)
            af[i] = *reinterpret_cast<const bf16x8*>(&As[(wr * 64 + i * 16 + lr) * 40 + lh * 8]);
#pragma unroll
        for (int i = 0; i < 4; i++)
            bfr[i] = *reinterpret_cast<const bf16x8*>(&Bs[(wc * 64 + i * 16 + lr) * 40 + lh * 8]);
#pragma unroll
        for (int mi = 0; mi < 4; mi++)
#pragma unroll
            for (int ni = 0; ni < 4; ni++)
                acc[mi][ni] = __builtin_amdgcn_mfma_f32_16x16x32_bf16(af[mi], bfr[ni], acc[mi][ni], 0, 0, 0);
        __syncthreads();
    }

#pragma unroll
    for (int mi = 0; mi < 4; mi++) {
#pragma unroll
        for (int ni = 0; ni < 4; ni++) {
#pragma unroll
            for (int r = 0; r < 4; r++) {
                const int row = m0 + wr * 64 + mi * 16 + lh * 4 + r;
                const int col = n0 + wc * 64 + ni * 16 + lr;
                float v = acc[mi][ni][r];
                if constexpr (EPI == 0) {
                    v += bias[col];
                    ((unsigned short*)C0)[(size_t)row * 512 + col] = f2bfu(v);
                } else if constexpr (EPI == 1) {
                    // col in [0,1536): j = part*512 + h*64 + d ; row = b*2048 + n
                    const int part = col >> 9, hh = (col >> 6) & 7, d = col & 63;
                    const int b = row >> 11, n = row & 2047;
                    const size_t bh = (size_t)(b * 8 + hh);
                    if (part == 0)
                        ((unsigned short*)C0)[(bh * 2048 + n) * 64 + d] = f2bfu(v * 0.1803368801111244f);
                    else if (part == 1)
                        ((unsigned short*)C1)[(bh * 2048 + n) * 64 + d] = f2bfu(v);
                    else
                        ((unsigned short*)C2)[(bh * 64 + d) * 2048 + n] = f2bfu(v);
                } else if constexpr (EPI == 2) {
                    const float sg = 1.0f / (1.0f + __expf(-v));
                    ((unsigned short*)C0)[(size_t)blockIdx.z * sC + (size_t)row * 2048 + col] = f2bfu(sg);
                } else {
                    ((float*)C0)[(size_t)row * 512 + col] = v + bias[col];
                }
            }
        }
    }
}

// ---------------- GroupNorm partial stats: 256 blocks = (b,g,chunk) ----------------
__global__ __launch_bounds__(256) void gn_stats_part(const unsigned short* __restrict__ c1,
                                                     const unsigned short* __restrict__ c2,
                                                     float* __restrict__ part) {
    const int bgc = blockIdx.x;                 // b*64 + g*8 + ch
    const int b = bgc >> 6, g = (bgc >> 3) & 7, ch = bgc & 7;
    const int tid = threadIdx.x;
    const size_t base = ((size_t)b * 2048 + ch * 256) * 512 + g * 64;
    float s1 = 0.f, q1 = 0.f, s2 = 0.f, q2 = 0.f;
    for (int c = tid; c < 2048; c += 256) {     // 256 rows x 8 vec8 chunks
        const int n = c >> 3, i8 = (c & 7) * 8;
        const size_t off = base + (size_t)n * 512 + i8;
        uint4 v1 = *reinterpret_cast<const uint4*>(c1 + off);
        uint4 v2 = *reinterpret_cast<const uint4*>(c2 + off);
        unsigned int a1[4] = {v1.x, v1.y, v1.z, v1.w};
        unsigned int a2[4] = {v2.x, v2.y, v2.z, v2.w};
#pragma unroll
        for (int j = 0; j < 4; j++) {
            float x0 = bfu2f(a1[j] & 0xffffu), x1 = bfu2f(a1[j] >> 16);
            s1 += x0 + x1; q1 += x0 * x0 + x1 * x1;
            float y0 = bfu2f(a2[j] & 0xffffu), y1 = bfu2f(a2[j] >> 16);
            s2 += y0 + y1; q2 += y0 * y0 + y1 * y1;
        }
    }
#pragma unroll
    for (int off = 32; off >= 1; off >>= 1) {
        s1 += __shfl_down(s1, off); q1 += __shfl_down(q1, off);
        s2 += __shfl_down(s2, off); q2 += __shfl_down(q2, off);
    }
    __shared__ float red[4][4];
    if ((tid & 63) == 0) {
        const int wv = tid >> 6;
        red[0][wv] = s1; red[1][wv] = q1; red[2][wv] = s2; red[3][wv] = q2;
    }
    __syncthreads();
    if (tid == 0) {
        part[bgc * 4 + 0] = red[0][0] + red[0][1] + red[0][2] + red[0][3];
        part[bgc * 4 + 1] = red[1][0] + red[1][1] + red[1][2] + red[1][3];
        part[bgc * 4 + 2] = red[2][0] + red[2][1] + red[2][2] + red[2][3];
        part[bgc * 4 + 3] = red[3][0] + red[3][1] + red[3][2] + red[3][3];
    }
}

__global__ __launch_bounds__(64) void gn_finish(const float* __restrict__ part,
                                                float* __restrict__ stats) {
    const int t = threadIdx.x;
    if (t < 32) {
        float S1 = 0.f, Q1 = 0.f, S2 = 0.f, Q2 = 0.f;
        for (int ch = 0; ch < 8; ch++) {
            const float* p = part + ((t << 3) + ch) * 4;
            S1 += p[0]; Q1 += p[1]; S2 += p[2]; Q2 += p[3];
        }
        const float inv = 1.0f / 131072.0f;
        float m1 = S1 * inv, m2 = S2 * inv;
        float v1 = fmaxf(Q1 * inv - m1 * m1, 0.f);
        float v2 = fmaxf(Q2 * inv - m2 * m2, 0.f);
        stats[t * 4 + 0] = m1;
        stats[t * 4 + 1] = rsqrtf(v1 + 1e-5f);
        stats[t * 4 + 2] = m2;
        stats[t * 4 + 3] = rsqrtf(v2 + 1e-5f);
    }
}

// ---------------- GroupNorm apply (in place), both tensors ----------------
__global__ __launch_bounds__(256) void gn_apply(unsigned short* __restrict__ c1,
                                                unsigned short* __restrict__ c2,
                                                const float* __restrict__ stats,
                                                const float* __restrict__ g1, const float* __restrict__ b1,
                                                const float* __restrict__ g2, const float* __restrict__ b2) {
    int i = blockIdx.x * 256 + threadIdx.x;
    const int stride = gridDim.x * 256;
    for (; i < 524288; i += stride) {           // 4*2048*512/8 chunks
        const size_t e = (size_t)i * 8;
        const int b = (int)(e >> 20);           // N*C = 2^20
        const int o = (int)(e & 511);
        const int g = o >> 6;
        const float* st = stats + ((b << 3) + g) * 4;
        const float m1 = st[0], r1 = st[1], m2 = st[2], r2 = st[3];
        uint4 v1 = *reinterpret_cast<const uint4*>(c1 + e);
        uint4 v2 = *reinterpret_cast<const uint4*>(c2 + e);
        unsigned int a1[4] = {v1.x, v1.y, v1.z, v1.w};
        unsigned int a2[4] = {v2.x, v2.y, v2.z, v2.w};
        unsigned int o1[4], o2[4];
#pragma unroll
        for (int j = 0; j < 4; j++) {
            const int oo = o + j * 2;
            float x0 = (bfu2f(a1[j] & 0xffffu) - m1) * r1 * g1[oo] + b1[oo];
            float x1 = (bfu2f(a1[j] >> 16) - m1) * r1 * g1[oo + 1] + b1[oo + 1];
            o1[j] = (unsigned int)f2bfu(x0) | ((unsigned int)f2bfu(x1) << 16);
            float y0 = (bfu2f(a2[j] & 0xffffu) - m2) * r2 * g2[oo] + b2[oo];
            float y1 = (bfu2f(a2[j] >> 16) - m2) * r2 * g2[oo + 1] + b2[oo + 1];
            o2[j] = (unsigned int)f2bfu(y0) | ((unsigned int)f2bfu(y1) << 16);
        }
        uint4 w1; w1.x = o1[0]; w1.y = o1[1]; w1.z = o1[2]; w1.w = o1[3];
        uint4 w2; w2.x = o2[0]; w2.y = o2[1]; w2.z = o2[2]; w2.w = o2[3];
        *reinterpret_cast<uint4*>(c1 + e) = w1;
        *reinterpret_cast<uint4*>(c2 + e) = w2;
    }
}

// ---------------- fused flash attention, swapped-QK^T, exp2-domain softmax ----------------
// flat grid 1024: h = bid>>7 (same (nt,b) => same bid mod 8 => same XCD for all 8 heads).
// block 256 = 4 waves, wave w owns q-rows [16w,16w+16).  S^T = mfma(K,Q): lane: q=lr, k=16mf+4lh+r.
// K/V^T double-buffered via global_load_lds (XOR-16B-slot swizzle); pe [q][k] tile SINGLE-buffered
// (read early; next tile staged after a mid-iteration barrier).  P->PV via per-wave Pl roundtrip.
// LDS = 16+16+8+9.2 = 49.4KB -> 3 blocks/CU.
__global__ __launch_bounds__(256, 3) void attn_fused(
    const unsigned short* __restrict__ qb, const unsigned short* __restrict__ kb,
    const unsigned short* __restrict__ vT, const unsigned short* __restrict__ pea,
    unsigned short* __restrict__ hbuf) {
    __shared__ unsigned short Ks[2][64 * 64];
    __shared__ unsigned short Vs[2][64 * 64];
    __shared__ unsigned short Pe[64 * 64];
    __shared__ unsigned short Pl[4][16 * 72];
    const int tid = threadIdx.x, l = tid & 63, w = tid >> 6;
    const int lr = l & 15, lh = l >> 4;
    const int bid = blockIdx.x;
    const int h = bid >> 7, rst = bid & 127, nt = rst & 31, b = rst >> 5;
    const size_t bh = (size_t)(b * 8 + h);
    const unsigned short* qp = qb + bh * 2048 * 64;
    const unsigned short* kp = kb + bh * 2048 * 64;
    const unsigned short* vp = vT + bh * 64 * 2048;
    const unsigned short* pep = pea + (size_t)b * 2048 * 2048;   // [q][k] orientation
    const int n0 = nt * 64;

    // Q B-fragments (pre-scaled by 0.125*log2e at QKV epilogue)
    bf16x8 qf[2];
    qf[0] = *reinterpret_cast<const bf16x8*>(qp + (size_t)(n0 + 16 * w + lr) * 64 + lh * 8);
    qf[1] = *reinterpret_cast<const bf16x8*>(qp + (size_t)(n0 + 16 * w + lr) * 64 + 32 + lh * 8);

    // swizzled read columns (shorts) for K/V A-fragments
    const int swz = (lr & 7) << 4;                       // byte XOR
    const int colK0 = ((16 * lh) ^ swz) >> 1;
    const int colK1 = ((64 + 16 * lh) ^ swz) >> 1;
    // pe b64 read offset (shorts) within row (16w+lr): slot mf*2+(lh>>1), XOR by lr&7
    const int perow = (16 * w + lr) * 64;
    int peoff[4];
#pragma unroll
    for (int mf = 0; mf < 4; mf++)
        peoff[mf] = perow + (((mf * 2 + (lh >> 1)) ^ (lr & 7)) << 3) + ((lh & 1) << 2);

    f32x4 oacc[4] = {};
    float mrun = -1e30f, lrun = 0.f;

    // async staging: lane -> (row = base + l>>3, slot = l&7), source col-slot = slot ^ (row&7)
    const int srow = l >> 3, sslot = l & 7;
    auto stage_kv = [&](int bufi, int m0) {
#pragma unroll
        for (int i = 0; i < 2; i++) {
            const int row = w * 16 + i * 8 + srow;
            const int cs = (sslot ^ (row & 7)) * 8;
            const int ldsoff = (w * 16 + i * 8) * 64;
            __builtin_amdgcn_global_load_lds(
                (const __attribute__((address_space(1))) void*)(kp + (size_t)(m0 + row) * 64 + cs),
                (__attribute__((address_space(3))) void*)&Ks[bufi][ldsoff], 16, 0, 0);
            __builtin_amdgcn_global_load_lds(
                (const __attribute__((address_space(1))) void*)(vp + (size_t)row * 2048 + m0 + cs),
                (__attribute__((address_space(3))) void*)&Vs[bufi][ldsoff], 16, 0, 0);
        }
    };
    auto stage_pe = [&](int m0) {
#pragma unroll
        for (int i = 0; i < 2; i++) {
            const int row = w * 16 + i * 8 + srow;
            const int cs = (sslot ^ (row & 7)) * 8;
            const int ldsoff = (w * 16 + i * 8) * 64;
            // pe tile: rows q = n0 + row (fixed), cols k = m0 + cs (advancing)
            __builtin_amdgcn_global_load_lds(
                (const __attribute__((address_space(1))) void*)(pep + (size_t)(n0 + row) * 2048 + m0 + cs),
                (__attribute__((address_space(3))) void*)&Pe[ldsoff], 16, 0, 0);
        }
    };

    stage_kv(0, 0);
    stage_pe(0);
    asm volatile("s_waitcnt vmcnt(0)" ::: "memory");
    __syncthreads();

    for (int mt = 0; mt < 32; mt++) {
        const int cur = mt & 1;
        if (mt + 1 < 32) stage_kv(cur ^ 1, (mt + 1) * 64);
        const unsigned short* Kb = Ks[cur];
        const unsigned short* Vb = Vs[cur];

        // S^T: rows k (4 frags), cols q
        f32x4 st[4] = {};
        __builtin_amdgcn_s_setprio(1);
#pragma unroll
        for (int mf = 0; mf < 4; mf++) {
            bf16x8 kf0 = *reinterpret_cast<const bf16x8*>(&Kb[(mf * 16 + lr) * 64 + colK0]);
            bf16x8 kf1 = *reinterpret_cast<const bf16x8*>(&Kb[(mf * 16 + lr) * 64 + colK1]);
            st[mf] = __builtin_amdgcn_mfma_f32_16x16x32_bf16(kf0, qf[0], st[mf], 0, 0, 0);
            st[mf] = __builtin_amdgcn_mfma_f32_16x16x32_bf16(kf1, qf[1], st[mf], 0, 0, 0);
        }
        __builtin_amdgcn_s_setprio(0);
        // logits (log2-domain): p = S^T * pe   (0.125*log2e folded into Q)
        float p[4][4];
#pragma unroll
        for (int mf = 0; mf < 4; mf++) {
            const uint2 pv = *reinterpret_cast<const uint2*>(&Pe[peoff[mf]]);
            p[mf][0] = st[mf][0] * bfu2f(pv.x & 0xffffu);
            p[mf][1] = st[mf][1] * bfu2f(pv.x >> 16);
            p[mf][2] = st[mf][2] * bfu2f(pv.y & 0xffffu);
            p[mf][3] = st[mf][3] * bfu2f(pv.y >> 16);
        }
        // all waves done reading Pe -> safe to overwrite with next tile (async)
        __syncthreads();
        if (mt + 1 < 32) stage_pe((mt + 1) * 64);
        // row max: lane-local max chain + butterfly across lh groups
        float pm = fmaxf(p[0][0], p[0][1]);
        pm = fmaxf(fmaxf(pm, p[0][2]), p[0][3]);
#pragma unroll
        for (int mf = 1; mf < 4; mf++) {
            pm = fmaxf(fmaxf(pm, p[mf][0]), p[mf][1]);
            pm = fmaxf(fmaxf(pm, p[mf][2]), p[mf][3]);
        }
        pm = fmaxf(pm, __shfl_xor(pm, 16));
        pm = fmaxf(pm, __shfl_xor(pm, 32));
        // defer-max (threshold 8*log2e in log2 domain)
        if (__any(pm > mrun + 11.5416f)) {
            const float mnew = fmaxf(mrun, pm);
            const float fac = __builtin_amdgcn_exp2f(mrun - mnew);
            lrun *= fac;
#pragma unroll
            for (int df = 0; df < 4; df++)
#pragma unroll
                for (int r = 0; r < 4; r++) oacc[df][r] *= fac;
            mrun = mnew;
        }
        // P = exp2(p - mrun); pack pairs with v_cvt_pk_bf16_f32; sum unrounded (bias ~1e-5, ok)
        float ss = 0.f;
        unsigned int pk[8];
#pragma unroll
        for (int mf = 0; mf < 4; mf++) {
#pragma unroll
            for (int t = 0; t < 2; t++) {
                const float a = __builtin_amdgcn_exp2f(p[mf][2 * t] - mrun);
                const float c = __builtin_amdgcn_exp2f(p[mf][2 * t + 1] - mrun);
                unsigned int pkv;
                asm("v_cvt_pk_bf16_f32 %0, %1, %2" : "=v"(pkv) : "v"(a), "v"(c));
                pk[mf * 2 + t] = pkv;
                ss += a + c;
            }
        }
        ss += __shfl_xor(ss, 16);
        ss += __shfl_xor(ss, 32);
        lrun += ss;
        // P -> per-wave LDS [q=lr][k] (u32 words), re-read as PV B-fragments (R2-verified path)
#pragma unroll
        for (int mf = 0; mf < 4; mf++)
#pragma unroll
            for (int t = 0; t < 2; t++)
                *reinterpret_cast<unsigned int*>(&Pl[w][lr * 72 + mf * 16 + lh * 4 + 2 * t]) = pk[mf * 2 + t];
        bf16x8 pb0 = *reinterpret_cast<const bf16x8*>(&Pl[w][lr * 72 + lh * 8]);
        bf16x8 pb1 = *reinterpret_cast<const bf16x8*>(&Pl[w][lr * 72 + 32 + lh * 8]);
        // out^T[d][q] += sum_k V^T[d][k] * P[q][k]
        __builtin_amdgcn_s_setprio(1);
#pragma unroll
        for (int df = 0; df < 4; df++) {
            bf16x8 vf0 = *reinterpret_cast<const bf16x8*>(&Vb[(df * 16 + lr) * 64 + colK0]);
            bf16x8 vf1 = *reinterpret_cast<const bf16x8*>(&Vb[(df * 16 + lr) * 64 + colK1]);
            oacc[df] = __builtin_amdgcn_mfma_f32_16x16x32_bf16(vf0, pb0, oacc[df], 0, 0, 0);
            oacc[df] = __builtin_amdgcn_mfma_f32_16x16x32_bf16(vf1, pb1, oacc[df], 0, 0, 0);
        }
        __builtin_amdgcn_s_setprio(0);
        if (mt + 1 < 32) {
            asm volatile("s_waitcnt vmcnt(0)" ::: "memory");
            __syncthreads();
        }
    }
    const float inv = 1.0f / lrun;
    const size_t base = ((size_t)b * 2048 + n0 + 16 * w + lr) * 512 + h * 64;
#pragma unroll
    for (int df = 0; df < 4; df++) {
#pragma unroll
        for (int t = 0; t < 2; t++) {
            const unsigned int ua = f2bfu(oacc[df][2 * t] * inv);
            const unsigned int uc = f2bfu(oacc[df][2 * t + 1] * inv);
            *reinterpret_cast<unsigned int*>(&hbuf[base + 16 * df + 4 * lh + 2 * t]) = ua | (uc << 16);
        }
    }
}

extern "C" void kernel_launch(void* const* d_in, const int* in_sizes, int n_in,
                              void* d_out, int out_size, void* d_ws, size_t ws_size,
                              hipStream_t stream) {
    const float* x       = (const float*)d_in[0];
    const float* pe      = (const float*)d_in[1];
    const float* qkv_w   = (const float*)d_in[2];
    const float* proj_w  = (const float*)d_in[3];
    const float* proj_b  = (const float*)d_in[4];
    const float* conv1_w = (const float*)d_in[5];
    const float* conv1_b = (const float*)d_in[6];
    const float* gn1_g   = (const float*)d_in[7];
    const float* gn1_b   = (const float*)d_in[8];
    const float* conv2_w = (const float*)d_in[9];
    const float* conv2_b = (const float*)d_in[10];
    const float* gn2_g   = (const float*)d_in[11];
    const float* gn2_b   = (const float*)d_in[12];
    float* out = (float*)d_out;

    char* ws = (char*)d_ws;
    size_t off = 0;
    auto alloc = [&](size_t bytes) -> void* {
        void* p = ws + off;
        off += (bytes + 255) & ~(size_t)255;
        return p;
    };
    unsigned short* xb     = (unsigned short*)alloc(8388608);   // x bf16 [B*N, C]
    unsigned short* peb    = (unsigned short*)alloc(8388608);   // pe bf16
    unsigned short* qkvwb  = (unsigned short*)alloc(1572864);   // qkv_w bf16 [1536,512]
    unsigned short* projwb = (unsigned short*)alloc(524288);
    unsigned short* w1b    = (unsigned short*)alloc(524288);
    unsigned short* w2b    = (unsigned short*)alloc(524288);
    unsigned short* c1b    = (unsigned short*)alloc(8388608);   // conv1 out -> p1 (in place GN)
    unsigned short* c2b    = (unsigned short*)alloc(8388608);
    unsigned short* qbuf   = (unsigned short*)alloc(8388608);   // [B,H,N,D] (q pre-scaled)
    unsigned short* kbuf   = (unsigned short*)alloc(8388608);
    unsigned short* vtb    = (unsigned short*)alloc(8388608);   // [B,H,D,N]
    unsigned short* peatt  = (unsigned short*)alloc(33554432);  // pe_attn [B,N(q),N(k)] bf16
    unsigned short* hbuf   = (unsigned short*)alloc(8388608);   // [B,N,C] bf16
    float* stats           = (float*)alloc(512);
    float* part            = (float*)alloc(4096);

    dim3 blk(256);
    cvt_f32_bf16<<<1024, blk, 0, stream>>>(x, xb, 1048576);
    cvt_f32_bf16<<<1024, blk, 0, stream>>>(pe, peb, 1048576);
    cvt_f32_bf16<<<256, blk, 0, stream>>>(qkv_w, qkvwb, 196608);
    cvt_f32_bf16<<<128, blk, 0, stream>>>(proj_w, projwb, 65536);
    cvt_f32_bf16<<<128, blk, 0, stream>>>(conv1_w, w1b, 65536);
    cvt_f32_bf16<<<128, blk, 0, stream>>>(conv2_w, w2b, 65536);

    // conv1/conv2 (per-position linear over channels), bias, bf16 out [B,N,C]
    gemm_nt<0><<<dim3(4, 64, 1), blk, 0, stream>>>(peb, w1b, c1b, nullptr, nullptr, conv1_b, 512, 0, 0, 0);
    gemm_nt<0><<<dim3(4, 64, 1), blk, 0, stream>>>(peb, w2b, c2b, nullptr, nullptr, conv2_b, 512, 0, 0, 0);
    gn_stats_part<<<256, blk, 0, stream>>>(c1b, c2b, part);
    gn_finish<<<1, 64, 0, stream>>>(part, stats);
    gn_apply<<<1024, blk, 0, stream>>>(c1b, c2b, stats, gn1_g, gn1_b, gn2_g, gn2_b);
    // qkv = x @ qkv_w.T, scattered to q (x0.125*log2e), k [B,H,N,D] and vT [B,H,D,N]
    gemm_nt<1><<<dim3(12, 64, 1), blk, 0, stream>>>(xb, qkvwb, qbuf, kbuf, vtb, nullptr, 512, 0, 0, 0);
    // pe_attn[b][n][m] = sigmoid(sum_k p1[n][k] p2[m][k])  ([q][k] orientation)
    gemm_nt<2><<<dim3(16, 16, 4), blk, 0, stream>>>(c1b, c2b, peatt, nullptr, nullptr, nullptr, 512,
                                                    1048576, 1048576, 4194304);
    attn_fused<<<dim3(1024, 1, 1), blk, 0, stream>>>(qbuf, kbuf, vtb, peatt, hbuf);
    // proj: out = h @ proj_w.T + proj_b (f32)
    gemm_nt<3><<<dim3(4, 64, 1), blk, 0, stream>>>(hbuf, projwb, out, nullptr, nullptr, proj_b, 512, 0, 0, 0);
}

// Round 6
// 250.429 us; speedup vs baseline: 1.3107x; 1.0581x over previous
//
#include <hip/hip_runtime.h>
#include <hip/hip_bf16.h>

// Shapes (fixed): B=4, N=2048, C=512, H=8, D=64, GROUPS=8, C/G=64
typedef __attribute__((ext_vector_type(8))) short bf16x8;
typedef __attribute__((ext_vector_type(4))) float f32x4;

__device__ __forceinline__ float bfu2f(unsigned int u) {
    return __uint_as_float(u << 16);
}
__device__ __forceinline__ unsigned short f2bfu(float f) {
    unsigned int u = __float_as_uint(f);
    u += 0x7fffu + ((u >> 16) & 1u);   // RNE
    return (unsigned short)(u >> 16);
}

// ---------------- fp32 -> bf16 conversion: x and pe in one launch ----------------
__global__ __launch_bounds__(256) void cvt2(const float* __restrict__ s0, unsigned short* __restrict__ d0,
                                            const float* __restrict__ s1, unsigned short* __restrict__ d1) {
    int i = blockIdx.x * 256 + threadIdx.x;
    const int stride = gridDim.x * 256;
    for (; i < 1048576; i += stride) {
        float4 v = reinterpret_cast<const float4*>(s0)[i];
        ushort4 o;
        o.x = f2bfu(v.x); o.y = f2bfu(v.y); o.z = f2bfu(v.z); o.w = f2bfu(v.w);
        reinterpret_cast<ushort4*>(d0)[i] = o;
        float4 u = reinterpret_cast<const float4*>(s1)[i];
        ushort4 p;
        p.x = f2bfu(u.x); p.y = f2bfu(u.y); p.z = f2bfu(u.z); p.w = f2bfu(u.w);
        reinterpret_cast<ushort4*>(d1)[i] = p;
    }
}

// ---------------- all 4 weight tensors in one launch ----------------
__global__ __launch_bounds__(256) void cvtw(const float* __restrict__ s0, unsigned short* __restrict__ d0,
                                            const float* __restrict__ s1, unsigned short* __restrict__ d1,
                                            const float* __restrict__ s2, unsigned short* __restrict__ d2,
                                            const float* __restrict__ s3, unsigned short* __restrict__ d3) {
    int i = blockIdx.x * 256 + threadIdx.x;
    const int stride = gridDim.x * 256;
    for (; i < 393216; i += stride) {
        const float* s; unsigned short* d; int j;
        if (i < 196608)      { s = s0; d = d0; j = i; }
        else if (i < 262144) { s = s1; d = d1; j = i - 196608; }
        else if (i < 327680) { s = s2; d = d2; j = i - 262144; }
        else                 { s = s3; d = d3; j = i - 327680; }
        float4 v = reinterpret_cast<const float4*>(s)[j];
        ushort4 o;
        o.x = f2bfu(v.x); o.y = f2bfu(v.y); o.z = f2bfu(v.z); o.w = f2bfu(v.w);
        reinterpret_cast<ushort4*>(d)[j] = o;
    }
}

// ---------------- generic NT GEMM, bf16 in, MFMA 16x16x32 ----------------
// C[m][n] = sum_k A[m][k] * B[n][k].  128x128 tile, BK=32, 4 waves (2x2 of 64x64).
// EPI: 0 = conv (bf16 out ld512, +bias), 1 = qkv scatter (q*0.125*log2e, k, vT),
//      2 = sigmoid bf16 (ld2048, batched), 3 = proj (f32 out ld512, +bias)
template <int EPI>
__global__ __launch_bounds__(256) void gemm_nt(
    const unsigned short* __restrict__ A, const unsigned short* __restrict__ B,
    void* __restrict__ C0, void* __restrict__ C1, void* __restrict__ C2,
    const float* __restrict__ bias, int K, long sA, long sB, long sC) {
    __shared__ unsigned short As[128 * 40];
    __shared__ unsigned short Bs[128 * 40];
    const int tid = threadIdx.x;
    const int l = tid & 63, w = tid >> 6;
    const int wr = w >> 1, wc = w & 1, lr = l & 15, lh = l >> 4;
    const int m0 = blockIdx.y * 128, n0 = blockIdx.x * 128;
    A += (size_t)blockIdx.z * sA;
    B += (size_t)blockIdx.z * sB;
    f32x4 acc[4][4] = {};
    const int rowS = tid >> 2, partS = tid & 3;

    for (int k0 = 0; k0 < K; k0 += 32) {
        *reinterpret_cast<uint4*>(&As[rowS * 40 + partS * 8]) =
            *reinterpret_cast<const uint4*>(A + (size_t)(m0 + rowS) * K + k0 + partS * 8);
        *reinterpret_cast<uint4*>(&As[(rowS + 64) * 40 + partS * 8]) =
            *reinterpret_cast<const uint4*>(A + (size_t)(m0 + rowS + 64) * K + k0 + partS * 8);
        *reinterpret_cast<uint4*>(&Bs[rowS * 40 + partS * 8]) =
            *reinterpret_cast<const uint4*>(B + (size_t)(n0 + rowS) * K + k0 + partS * 8);
        *reinterpret_cast<uint4*>(&Bs[(rowS + 64) * 40 + partS * 8]) =
            *reinterpret_cast<const uint4*>(B + (size_t)(n0 + rowS + 64) * K + k0 + partS * 8);
        __syncthreads();
        bf16x8 af[4], bfr[4];
#pragma unroll
        for (int i = 0; i < 4; i++)
            af[i] = *reinterpret_cast<const bf16x8*>(&As[(wr * 64 + i * 16 + lr) * 40 + lh * 8]);
#pragma unroll
        for (int i = 0; i < 4; i++)
            bfr[i] = *reinterpret_cast<const bf16x8*>(&Bs[(wc * 64 + i * 16 + lr) * 40 + lh * 8]);
#pragma unroll
        for (int mi = 0; mi < 4; mi++)
#pragma unroll
            for (int ni = 0; ni < 4; ni++)
                acc[mi][ni] = __builtin_amdgcn_mfma_f32_16x16x32_bf16(af[mi], bfr[ni], acc[mi][ni], 0, 0, 0);
        __syncthreads();
    }

#pragma unroll
    for (int mi = 0; mi < 4; mi++) {
#pragma unroll
        for (int ni = 0; ni < 4; ni++) {
#pragma unroll
            for (int r = 0; r < 4; r++) {
                const int row = m0 + wr * 64 + mi * 16 + lh * 4 + r;
                const int col = n0 + wc * 64 + ni * 16 + lr;
                float v = acc[mi][ni][r];
                if constexpr (EPI == 0) {
                    v += bias[col];
                    ((unsigned short*)C0)[(size_t)row * 512 + col] = f2bfu(v);
                } else if constexpr (EPI == 1) {
                    // col in [0,1536): j = part*512 + h*64 + d ; row = b*2048 + n
                    const int part = col >> 9, hh = (col >> 6) & 7, d = col & 63;
                    const int b = row >> 11, n = row & 2047;
                    const size_t bh = (size_t)(b * 8 + hh);
                    if (part == 0)
                        ((unsigned short*)C0)[(bh * 2048 + n) * 64 + d] = f2bfu(v * 0.1803368801111244f);
                    else if (part == 1)
                        ((unsigned short*)C1)[(bh * 2048 + n) * 64 + d] = f2bfu(v);
                    else
                        ((unsigned short*)C2)[(bh * 64 + d) * 2048 + n] = f2bfu(v);
                } else if constexpr (EPI == 2) {
                    const float sg = 1.0f / (1.0f + __expf(-v));
                    ((unsigned short*)C0)[(size_t)blockIdx.z * sC + (size_t)row * 2048 + col] = f2bfu(sg);
                } else {
                    ((float*)C0)[(size_t)row * 512 + col] = v + bias[col];
                }
            }
        }
    }
}

// ---------------- GroupNorm partial stats: 256 blocks = (b,g,chunk) ----------------
__global__ __launch_bounds__(256) void gn_stats_part(const unsigned short* __restrict__ c1,
                                                     const unsigned short* __restrict__ c2,
                                                     float* __restrict__ part) {
    const int bgc = blockIdx.x;                 // b*64 + g*8 + ch
    const int b = bgc >> 6, g = (bgc >> 3) & 7, ch = bgc & 7;
    const int tid = threadIdx.x;
    const size_t base = ((size_t)b * 2048 + ch * 256) * 512 + g * 64;
    float s1 = 0.f, q1 = 0.f, s2 = 0.f, q2 = 0.f;
    for (int c = tid; c < 2048; c += 256) {     // 256 rows x 8 vec8 chunks
        const int n = c >> 3, i8 = (c & 7) * 8;
        const size_t off = base + (size_t)n * 512 + i8;
        uint4 v1 = *reinterpret_cast<const uint4*>(c1 + off);
        uint4 v2 = *reinterpret_cast<const uint4*>(c2 + off);
        unsigned int a1[4] = {v1.x, v1.y, v1.z, v1.w};
        unsigned int a2[4] = {v2.x, v2.y, v2.z, v2.w};
#pragma unroll
        for (int j = 0; j < 4; j++) {
            float x0 = bfu2f(a1[j] & 0xffffu), x1 = bfu2f(a1[j] >> 16);
            s1 += x0 + x1; q1 += x0 * x0 + x1 * x1;
            float y0 = bfu2f(a2[j] & 0xffffu), y1 = bfu2f(a2[j] >> 16);
            s2 += y0 + y1; q2 += y0 * y0 + y1 * y1;
        }
    }
#pragma unroll
    for (int off = 32; off >= 1; off >>= 1) {
        s1 += __shfl_down(s1, off); q1 += __shfl_down(q1, off);
        s2 += __shfl_down(s2, off); q2 += __shfl_down(q2, off);
    }
    __shared__ float red[4][4];
    if ((tid & 63) == 0) {
        const int wv = tid >> 6;
        red[0][wv] = s1; red[1][wv] = q1; red[2][wv] = s2; red[3][wv] = q2;
    }
    __syncthreads();
    if (tid == 0) {
        part[bgc * 4 + 0] = red[0][0] + red[0][1] + red[0][2] + red[0][3];
        part[bgc * 4 + 1] = red[1][0] + red[1][1] + red[1][2] + red[1][3];
        part[bgc * 4 + 2] = red[2][0] + red[2][1] + red[2][2] + red[2][3];
        part[bgc * 4 + 3] = red[3][0] + red[3][1] + red[3][2] + red[3][3];
    }
}

// ---------------- GroupNorm apply (in place), finish folded in ----------------
__global__ __launch_bounds__(256) void gn_apply(unsigned short* __restrict__ c1,
                                                unsigned short* __restrict__ c2,
                                                const float* __restrict__ part,
                                                const float* __restrict__ g1, const float* __restrict__ b1,
                                                const float* __restrict__ g2, const float* __restrict__ b2) {
    __shared__ float sst[32][4];
    const int tid = threadIdx.x;
    if (tid < 32) {
        float S1 = 0.f, Q1 = 0.f, S2 = 0.f, Q2 = 0.f;
        for (int ch = 0; ch < 8; ch++) {
            const float* p = part + ((tid << 3) + ch) * 4;
            S1 += p[0]; Q1 += p[1]; S2 += p[2]; Q2 += p[3];
        }
        const float inv = 1.0f / 131072.0f;
        float m1 = S1 * inv, m2 = S2 * inv;
        float v1 = fmaxf(Q1 * inv - m1 * m1, 0.f);
        float v2 = fmaxf(Q2 * inv - m2 * m2, 0.f);
        sst[tid][0] = m1;
        sst[tid][1] = rsqrtf(v1 + 1e-5f);
        sst[tid][2] = m2;
        sst[tid][3] = rsqrtf(v2 + 1e-5f);
    }
    __syncthreads();
    int i = blockIdx.x * 256 + tid;
    const int stride = gridDim.x * 256;
    for (; i < 524288; i += stride) {           // 4*2048*512/8 chunks
        const size_t e = (size_t)i * 8;
        const int b = (int)(e >> 20);           // N*C = 2^20
        const int o = (int)(e & 511);
        const int g = o >> 6;
        const float* st = sst[(b << 3) + g];
        const float m1 = st[0], r1 = st[1], m2 = st[2], r2 = st[3];
        uint4 v1 = *reinterpret_cast<const uint4*>(c1 + e);
        uint4 v2 = *reinterpret_cast<const uint4*>(c2 + e);
        unsigned int a1[4] = {v1.x, v1.y, v1.z, v1.w};
        unsigned int a2[4] = {v2.x, v2.y, v2.z, v2.w};
        unsigned int o1[4], o2[4];
#pragma unroll
        for (int j = 0; j < 4; j++) {
            const int oo = o + j * 2;
            float x0 = (bfu2f(a1[j] & 0xffffu) - m1) * r1 * g1[oo] + b1[oo];
            float x1 = (bfu2f(a1[j] >> 16) - m1) * r1 * g1[oo + 1] + b1[oo + 1];
            o1[j] = (unsigned int)f2bfu(x0) | ((unsigned int)f2bfu(x1) << 16);
            float y0 = (bfu2f(a2[j] & 0xffffu) - m2) * r2 * g2[oo] + b2[oo];
            float y1 = (bfu2f(a2[j] >> 16) - m2) * r2 * g2[oo + 1] + b2[oo + 1];
            o2[j] = (unsigned int)f2bfu(y0) | ((unsigned int)f2bfu(y1) << 16);
        }
        uint4 w1; w1.x = o1[0]; w1.y = o1[1]; w1.z = o1[2]; w1.w = o1[3];
        uint4 w2; w2.x = o2[0]; w2.y = o2[1]; w2.z = o2[2]; w2.w = o2[3];
        *reinterpret_cast<uint4*>(c1 + e) = w1;
        *reinterpret_cast<uint4*>(c2 + e) = w2;
    }
}

// ---------------- fused flash attention, swapped-QK^T, exp2-domain softmax ----------------
// flat grid 1024: h = bid>>7 (same (nt,b) => same bid mod 8 => same XCD for all 8 heads).
// block 256 = 4 waves, wave w owns q-rows [16w,16w+16).  S^T = mfma(K,Q): lane: q=lr, k=16mf+4lh+r.
// K/V^T double-buffered via global_load_lds (XOR-16B-slot swizzle).
// pe held in REGISTERS (4x dwordx2/lane), prefetched one tile ahead.
// P round-trip ALIASED into Ks[cur] (free after QK^T): stride 64 shorts/row (full k range,
// 4 waves x 16x64 = exactly the 8KB buffer) + XOR-16B swizzle by lr&7 (else 16-way bank conflict).
// LDS 32KB -> 4 blocks/CU, no tail.  Raw s_barrier with manual waitcnt: barrier#1 lgkm-only.
__global__ __launch_bounds__(256, 4) void attn_fused(
    const unsigned short* __restrict__ qb, const unsigned short* __restrict__ kb,
    const unsigned short* __restrict__ vT, const unsigned short* __restrict__ pea,
    unsigned short* __restrict__ hbuf) {
    __shared__ unsigned short Ks[2][64 * 64];
    __shared__ unsigned short Vs[2][64 * 64];
    const int tid = threadIdx.x, l = tid & 63, w = tid >> 6;
    const int lr = l & 15, lh = l >> 4;
    const int bid = blockIdx.x;
    const int h = bid >> 7, rst = bid & 127, nt = rst & 31, b = rst >> 5;
    const size_t bh = (size_t)(b * 8 + h);
    const unsigned short* qp = qb + bh * 2048 * 64;
    const unsigned short* kp = kb + bh * 2048 * 64;
    const unsigned short* vp = vT + bh * 64 * 2048;
    const unsigned short* pep = pea + (size_t)b * 2048 * 2048;   // [q][k] orientation
    const int n0 = nt * 64;

    // Q B-fragments (pre-scaled by 0.125*log2e at QKV epilogue)
    bf16x8 qf[2];
    qf[0] = *reinterpret_cast<const bf16x8*>(qp + (size_t)(n0 + 16 * w + lr) * 64 + lh * 8);
    qf[1] = *reinterpret_cast<const bf16x8*>(qp + (size_t)(n0 + 16 * w + lr) * 64 + 32 + lh * 8);

    // swizzled read columns (shorts) for K/V A-fragments
    const int swz = (lr & 7) << 4;                       // byte XOR
    const int colK0 = ((16 * lh) ^ swz) >> 1;
    const int colK1 = ((64 + 16 * lh) ^ swz) >> 1;

    // pe register path: lane's q-row pointer; per tile 4x 8B loads (k = 16mf+4lh .. +3)
    const unsigned short* perp = pep + (size_t)(n0 + 16 * w + lr) * 2048;
    uint2 peR[4];
#pragma unroll
    for (int mf = 0; mf < 4; mf++)
        peR[mf] = *reinterpret_cast<const uint2*>(perp + 16 * mf + 4 * lh);

    f32x4 oacc[4] = {};
    float mrun = -1e30f, lrun = 0.f;

    // async staging: lane -> (row = base + l>>3, slot = l&7), source col-slot = slot ^ (row&7)
    const int srow = l >> 3, sslot = l & 7;
    auto stage_kv = [&](int bufi, int m0) {
#pragma unroll
        for (int i = 0; i < 2; i++) {
            const int row = w * 16 + i * 8 + srow;
            const int cs = (sslot ^ (row & 7)) * 8;
            const int ldsoff = (w * 16 + i * 8) * 64;
            __builtin_amdgcn_global_load_lds(
                (const __attribute__((address_space(1))) void*)(kp + (size_t)(m0 + row) * 64 + cs),
                (__attribute__((address_space(3))) void*)&Ks[bufi][ldsoff], 16, 0, 0);
            __builtin_amdgcn_global_load_lds(
                (const __attribute__((address_space(1))) void*)(vp + (size_t)row * 2048 + m0 + cs),
                (__attribute__((address_space(3))) void*)&Vs[bufi][ldsoff], 16, 0, 0);
        }
    };

    stage_kv(0, 0);
    asm volatile("s_waitcnt vmcnt(0)" ::: "memory");
    __builtin_amdgcn_s_barrier();
    __builtin_amdgcn_sched_barrier(0);

    for (int mt = 0; mt < 32; mt++) {
        const int cur = mt & 1;
        if (mt + 1 < 32) stage_kv(cur ^ 1, (mt + 1) * 64);
        const unsigned short* Kb = Ks[cur];
        const unsigned short* Vb = Vs[cur];

        // S^T: rows k (4 frags), cols q
        f32x4 st[4] = {};
        __builtin_amdgcn_s_setprio(1);
#pragma unroll
        for (int mf = 0; mf < 4; mf++) {
            bf16x8 kf0 = *reinterpret_cast<const bf16x8*>(&Kb[(mf * 16 + lr) * 64 + colK0]);
            bf16x8 kf1 = *reinterpret_cast<const bf16x8*>(&Kb[(mf * 16 + lr) * 64 + colK1]);
            st[mf] = __builtin_amdgcn_mfma_f32_16x16x32_bf16(kf0, qf[0], st[mf], 0, 0, 0);
            st[mf] = __builtin_amdgcn_mfma_f32_16x16x32_bf16(kf1, qf[1], st[mf], 0, 0, 0);
        }
        __builtin_amdgcn_s_setprio(0);
        // barrier#1: all waves' K ds_reads complete (lgkm only; async stage stays in flight)
        asm volatile("s_waitcnt lgkmcnt(0)" ::: "memory");
        __builtin_amdgcn_s_barrier();
        __builtin_amdgcn_sched_barrier(0);

        // logits (log2-domain): p = S^T * pe   (0.125*log2e folded into Q)
        float p[4][4];
#pragma unroll
        for (int mf = 0; mf < 4; mf++) {
            p[mf][0] = st[mf][0] * bfu2f(peR[mf].x & 0xffffu);
            p[mf][1] = st[mf][1] * bfu2f(peR[mf].x >> 16);
            p[mf][2] = st[mf][2] * bfu2f(peR[mf].y & 0xffffu);
            p[mf][3] = st[mf][3] * bfu2f(peR[mf].y >> 16);
        }
        // prefetch next pe tile into regs (latency hidden under softmax+PV)
        uint2 peN[4];
        if (mt + 1 < 32) {
            const unsigned short* pn = perp + (mt + 1) * 64;
#pragma unroll
            for (int mf = 0; mf < 4; mf++)
                peN[mf] = *reinterpret_cast<const uint2*>(pn + 16 * mf + 4 * lh);
        }
        // row max: lane-local max chain + butterfly across lh groups
        float pm = fmaxf(p[0][0], p[0][1]);
        pm = fmaxf(fmaxf(pm, p[0][2]), p[0][3]);
#pragma unroll
        for (int mf = 1; mf < 4; mf++) {
            pm = fmaxf(fmaxf(pm, p[mf][0]), p[mf][1]);
            pm = fmaxf(fmaxf(pm, p[mf][2]), p[mf][3]);
        }
        pm = fmaxf(pm, __shfl_xor(pm, 16));
        pm = fmaxf(pm, __shfl_xor(pm, 32));
        // defer-max (threshold 8*log2e in log2 domain)
        if (__any(pm > mrun + 11.5416f)) {
            const float mnew = fmaxf(mrun, pm);
            const float fac = __builtin_amdgcn_exp2f(mrun - mnew);
            lrun *= fac;
#pragma unroll
            for (int df = 0; df < 4; df++)
#pragma unroll
                for (int r = 0; r < 4; r++) oacc[df][r] *= fac;
            mrun = mnew;
        }
        // P = exp2(p - mrun); pack pairs with v_cvt_pk_bf16_f32; sum unrounded (bias ~1e-5, ok)
        float ss = 0.f;
        unsigned int pk[8];
#pragma unroll
        for (int mf = 0; mf < 4; mf++) {
#pragma unroll
            for (int t = 0; t < 2; t++) {
                const float a = __builtin_amdgcn_exp2f(p[mf][2 * t] - mrun);
                const float c = __builtin_amdgcn_exp2f(p[mf][2 * t + 1] - mrun);
                unsigned int pkv;
                asm("v_cvt_pk_bf16_f32 %0, %1, %2" : "=v"(pkv) : "v"(a), "v"(c));
                pk[mf * 2 + t] = pkv;
                ss += a + c;
            }
        }
        ss += __shfl_xor(ss, 16);
        ss += __shfl_xor(ss, 32);
        lrun += ss;
        // P -> per-wave LDS region ALIASED into Ks[cur] (K consumed; protected by barrier#1).
        // Row q=lr: 64 shorts (k=0..63), stride 64; XOR-16B swizzle by lr&7 for bank spread.
        // Write k=16mf+4lh+2t at byte (mf*32+lh*8+4t)^plswz; read pb0/pb1 with same XOR.
        unsigned short* PlW = &Ks[cur][w * 1024];
        const int plswz = (lr & 7) << 4;               // byte XOR within 128B row
#pragma unroll
        for (int mf = 0; mf < 4; mf++)
#pragma unroll
            for (int t = 0; t < 2; t++) {
                const int cb = (mf * 32 + lh * 8 + 4 * t) ^ plswz;
                *reinterpret_cast<unsigned int*>(&PlW[lr * 64 + (cb >> 1)]) = pk[mf * 2 + t];
            }
        bf16x8 pb0 = *reinterpret_cast<const bf16x8*>(&PlW[lr * 64 + (((lh * 16) ^ plswz) >> 1)]);
        bf16x8 pb1 = *reinterpret_cast<const bf16x8*>(&PlW[lr * 64 + (((64 + lh * 16) ^ plswz) >> 1)]);
        // out^T[d][q] += sum_k V^T[d][k] * P[q][k]
        __builtin_amdgcn_s_setprio(1);
#pragma unroll
        for (int df = 0; df < 4; df++) {
            bf16x8 vf0 = *reinterpret_cast<const bf16x8*>(&Vb[(df * 16 + lr) * 64 + colK0]);
            bf16x8 vf1 = *reinterpret_cast<const bf16x8*>(&Vb[(df * 16 + lr) * 64 + colK1]);
            oacc[df] = __builtin_amdgcn_mfma_f32_16x16x32_bf16(vf0, pb0, oacc[df], 0, 0, 0);
            oacc[df] = __builtin_amdgcn_mfma_f32_16x16x32_bf16(vf1, pb1, oacc[df], 0, 0, 0);
        }
        __builtin_amdgcn_s_setprio(0);
        if (mt + 1 < 32) {
            // barrier#2: stage(t+1) landed (vmcnt) + all waves done with Vs[cur]/Pl (lgkm)
            asm volatile("s_waitcnt vmcnt(0) lgkmcnt(0)" ::: "memory");
            __builtin_amdgcn_s_barrier();
            __builtin_amdgcn_sched_barrier(0);
#pragma unroll
            for (int mf = 0; mf < 4; mf++) peR[mf] = peN[mf];
        }
    }
    const float inv = 1.0f / lrun;
    const size_t base = ((size_t)b * 2048 + n0 + 16 * w + lr) * 512 + h * 64;
#pragma unroll
    for (int df = 0; df < 4; df++) {
#pragma unroll
        for (int t = 0; t < 2; t++) {
            const unsigned int ua = f2bfu(oacc[df][2 * t] * inv);
            const unsigned int uc = f2bfu(oacc[df][2 * t + 1] * inv);
            *reinterpret_cast<unsigned int*>(&hbuf[base + 16 * df + 4 * lh + 2 * t]) = ua | (uc << 16);
        }
    }
}

extern "C" void kernel_launch(void* const* d_in, const int* in_sizes, int n_in,
                              void* d_out, int out_size, void* d_ws, size_t ws_size,
                              hipStream_t stream) {
    const float* x       = (const float*)d_in[0];
    const float* pe      = (const float*)d_in[1];
    const float* qkv_w   = (const float*)d_in[2];
    const float* proj_w  = (const float*)d_in[3];
    const float* proj_b  = (const float*)d_in[4];
    const float* conv1_w = (const float*)d_in[5];
    const float* conv1_b = (const float*)d_in[6];
    const float* gn1_g   = (const float*)d_in[7];
    const float* gn1_b   = (const float*)d_in[8];
    const float* conv2_w = (const float*)d_in[9];
    const float* conv2_b = (const float*)d_in[10];
    const float* gn2_g   = (const float*)d_in[11];
    const float* gn2_b   = (const float*)d_in[12];
    float* out = (float*)d_out;

    char* ws = (char*)d_ws;
    size_t off = 0;
    auto alloc = [&](size_t bytes) -> void* {
        void* p = ws + off;
        off += (bytes + 255) & ~(size_t)255;
        return p;
    };
    unsigned short* xb     = (unsigned short*)alloc(8388608);   // x bf16 [B*N, C]
    unsigned short* peb    = (unsigned short*)alloc(8388608);   // pe bf16
    unsigned short* qkvwb  = (unsigned short*)alloc(1572864);   // qkv_w bf16 [1536,512]
    unsigned short* projwb = (unsigned short*)alloc(524288);
    unsigned short* w1b    = (unsigned short*)alloc(524288);
    unsigned short* w2b    = (unsigned short*)alloc(524288);
    unsigned short* c1b    = (unsigned short*)alloc(8388608);   // conv1 out -> p1 (in place GN)
    unsigned short* c2b    = (unsigned short*)alloc(8388608);
    unsigned short* qbuf   = (unsigned short*)alloc(8388608);   // [B,H,N,D] (q pre-scaled)
    unsigned short* kbuf   = (unsigned short*)alloc(8388608);
    unsigned short* vtb    = (unsigned short*)alloc(8388608);   // [B,H,D,N]
    unsigned short* peatt  = (unsigned short*)alloc(33554432);  // pe_attn [B,N(q),N(k)] bf16
    unsigned short* hbuf   = (unsigned short*)alloc(8388608);   // [B,N,C] bf16
    float* part            = (float*)alloc(4096);

    dim3 blk(256);
    cvt2<<<1024, blk, 0, stream>>>(x, xb, pe, peb);
    cvtw<<<512, blk, 0, stream>>>(qkv_w, qkvwb, proj_w, projwb, conv1_w, w1b, conv2_w, w2b);

    // conv1/conv2 (per-position linear over channels), bias, bf16 out [B,N,C]
    gemm_nt<0><<<dim3(4, 64, 1), blk, 0, stream>>>(peb, w1b, c1b, nullptr, nullptr, conv1_b, 512, 0, 0, 0);
    gemm_nt<0><<<dim3(4, 64, 1), blk, 0, stream>>>(peb, w2b, c2b, nullptr, nullptr, conv2_b, 512, 0, 0, 0);
    gn_stats_part<<<256, blk, 0, stream>>>(c1b, c2b, part);
    gn_apply<<<1024, blk, 0, stream>>>(c1b, c2b, part, gn1_g, gn1_b, gn2_g, gn2_b);
    // qkv = x @ qkv_w.T, scattered to q (x0.125*log2e), k [B,H,N,D] and vT [B,H,D,N]
    gemm_nt<1><<<dim3(12, 64, 1), blk, 0, stream>>>(xb, qkvwb, qbuf, kbuf, vtb, nullptr, 512, 0, 0, 0);
    // pe_attn[b][n][m] = sigmoid(sum_k p1[n][k] p2[m][k])  ([q][k] orientation)
    gemm_nt<2><<<dim3(16, 16, 4), blk, 0, stream>>>(c1b, c2b, peatt, nullptr, nullptr, nullptr, 512,
                                                    1048576, 1048576, 4194304);
    attn_fused<<<dim3(1024, 1, 1), blk, 0, stream>>>(qbuf, kbuf, vtb, peatt, hbuf);
    // proj: out = h @ proj_w.T + proj_b (f32)
    gemm_nt<3><<<dim3(4, 64, 1), blk, 0, stream>>>(hbuf, projwb, out, nullptr, nullptr, proj_b, 512, 0, 0, 0);
}

// Round 7
// 232.496 us; speedup vs baseline: 1.4118x; 1.0771x over previous
//
#include <hip/hip_runtime.h>
#include <hip/hip_bf16.h>

// Shapes (fixed): B=4, N=2048, C=512, H=8, D=64, GROUPS=8, C/G=64
typedef __attribute__((ext_vector_type(8))) short bf16x8;
typedef __attribute__((ext_vector_type(4))) float f32x4;

__device__ __forceinline__ float bfu2f(unsigned int u) {
    return __uint_as_float(u << 16);
}
__device__ __forceinline__ unsigned short f2bfu(float f) {
    unsigned int u = __float_as_uint(f);
    u += 0x7fffu + ((u >> 16) & 1u);   // RNE
    return (unsigned short)(u >> 16);
}

// ---------------- fp32 -> bf16 conversion: x and pe in one launch ----------------
__global__ __launch_bounds__(256) void cvt2(const float* __restrict__ s0, unsigned short* __restrict__ d0,
                                            const float* __restrict__ s1, unsigned short* __restrict__ d1) {
    int i = blockIdx.x * 256 + threadIdx.x;
    const int stride = gridDim.x * 256;
    for (; i < 1048576; i += stride) {
        float4 v = reinterpret_cast<const float4*>(s0)[i];
        ushort4 o;
        o.x = f2bfu(v.x); o.y = f2bfu(v.y); o.z = f2bfu(v.z); o.w = f2bfu(v.w);
        reinterpret_cast<ushort4*>(d0)[i] = o;
        float4 u = reinterpret_cast<const float4*>(s1)[i];
        ushort4 p;
        p.x = f2bfu(u.x); p.y = f2bfu(u.y); p.z = f2bfu(u.z); p.w = f2bfu(u.w);
        reinterpret_cast<ushort4*>(d1)[i] = p;
    }
}

// ---------------- all 4 weight tensors in one launch ----------------
__global__ __launch_bounds__(256) void cvtw(const float* __restrict__ s0, unsigned short* __restrict__ d0,
                                            const float* __restrict__ s1, unsigned short* __restrict__ d1,
                                            const float* __restrict__ s2, unsigned short* __restrict__ d2,
                                            const float* __restrict__ s3, unsigned short* __restrict__ d3) {
    int i = blockIdx.x * 256 + threadIdx.x;
    const int stride = gridDim.x * 256;
    for (; i < 393216; i += stride) {
        const float* s; unsigned short* d; int j;
        if (i < 196608)      { s = s0; d = d0; j = i; }
        else if (i < 262144) { s = s1; d = d1; j = i - 196608; }
        else if (i < 327680) { s = s2; d = d2; j = i - 262144; }
        else                 { s = s3; d = d3; j = i - 327680; }
        float4 v = reinterpret_cast<const float4*>(s)[j];
        ushort4 o;
        o.x = f2bfu(v.x); o.y = f2bfu(v.y); o.z = f2bfu(v.z); o.w = f2bfu(v.w);
        reinterpret_cast<ushort4*>(d)[j] = o;
    }
}

// ---------------- generic NT GEMM, bf16 in, MFMA 16x16x32, m97-style staging ----------------
// C[m][n] = sum_k A[m][k] * B[n][k].  128x128 tile, BK=32, 4 waves (2x2 of 64x64).
// Staging: global_load_lds width 16, double-buffered linear LDS [2][128][32],
// source pre-swizzle slot^=(row&3), read col (lh^(lr&3))*8 (same involution both sides).
// EPI: 0 = conv (bf16 out ld512, +bias), 1 = qkv scatter (q*0.125*log2e, k, vT),
//      2 = sigmoid bf16 (ld2048, batched), 3 = proj (f32 out ld512, +bias)
template <int EPI>
__global__ __launch_bounds__(256) void gemm_nt(
    const unsigned short* __restrict__ A, const unsigned short* __restrict__ B,
    void* __restrict__ C0, void* __restrict__ C1, void* __restrict__ C2,
    const float* __restrict__ bias, int K, long sA, long sB, long sC) {
    __shared__ unsigned short As[2][128 * 32];
    __shared__ unsigned short Bs[2][128 * 32];
    const int tid = threadIdx.x;
    const int l = tid & 63, w = tid >> 6;
    const int wr = w >> 1, wc = w & 1, lr = l & 15, lh = l >> 4;
    const int m0 = blockIdx.y * 128, n0 = blockIdx.x * 128;
    A += (size_t)blockIdx.z * sA;
    B += (size_t)blockIdx.z * sB;
    f32x4 acc[4][4] = {};

    // wave w stages rows [w*32, w*32+32): 2 instrs per matrix, lane -> (row=base+l>>2, slot=l&3)
    const int srow = l >> 2, sslot = l & 3;
    auto stage = [&](int bufi, int k0) {
#pragma unroll
        for (int i = 0; i < 2; i++) {
            const int row = w * 32 + i * 16 + srow;
            const int cs = (sslot ^ (row & 3)) * 8;      // pre-swizzled source col (shorts)
            const int ldsoff = (w * 32 + i * 16) * 32;   // linear LDS base (wave-uniform)
            __builtin_amdgcn_global_load_lds(
                (const __attribute__((address_space(1))) void*)(A + (size_t)(m0 + row) * K + k0 + cs),
                (__attribute__((address_space(3))) void*)&As[bufi][ldsoff], 16, 0, 0);
            __builtin_amdgcn_global_load_lds(
                (const __attribute__((address_space(1))) void*)(B + (size_t)(n0 + row) * K + k0 + cs),
                (__attribute__((address_space(3))) void*)&Bs[bufi][ldsoff], 16, 0, 0);
        }
    };

    const int nks = K >> 5;
    stage(0, 0);
    asm volatile("s_waitcnt vmcnt(0)" ::: "memory");
    __builtin_amdgcn_s_barrier();
    __builtin_amdgcn_sched_barrier(0);

    // read col: logical slot lh of row a lives at physical slot lh^(a&3); a&3 == lr&3 for all frags
    const int colA = (lh ^ (lr & 3)) << 3;
    for (int ks = 0; ks < nks; ks++) {
        const int cur = ks & 1;
        if (ks + 1 < nks) stage(cur ^ 1, (ks + 1) << 5);
        bf16x8 af[4], bfr[4];
#pragma unroll
        for (int i = 0; i < 4; i++)
            af[i] = *reinterpret_cast<const bf16x8*>(&As[cur][(wr * 64 + i * 16 + lr) * 32 + colA]);
#pragma unroll
        for (int i = 0; i < 4; i++)
            bfr[i] = *reinterpret_cast<const bf16x8*>(&Bs[cur][(wc * 64 + i * 16 + lr) * 32 + colA]);
        __builtin_amdgcn_s_setprio(1);
#pragma unroll
        for (int mi = 0; mi < 4; mi++)
#pragma unroll
            for (int ni = 0; ni < 4; ni++)
                acc[mi][ni] = __builtin_amdgcn_mfma_f32_16x16x32_bf16(af[mi], bfr[ni], acc[mi][ni], 0, 0, 0);
        __builtin_amdgcn_s_setprio(0);
        if (ks + 1 < nks) {
            // stage(ks+1) landed (vmcnt) + all waves done reading buffer cur (lgkm)
            asm volatile("s_waitcnt vmcnt(0) lgkmcnt(0)" ::: "memory");
            __builtin_amdgcn_s_barrier();
            __builtin_amdgcn_sched_barrier(0);
        }
    }

#pragma unroll
    for (int mi = 0; mi < 4; mi++) {
#pragma unroll
        for (int ni = 0; ni < 4; ni++) {
#pragma unroll
            for (int r = 0; r < 4; r++) {
                const int row = m0 + wr * 64 + mi * 16 + lh * 4 + r;
                const int col = n0 + wc * 64 + ni * 16 + lr;
                float v = acc[mi][ni][r];
                if constexpr (EPI == 0) {
                    v += bias[col];
                    ((unsigned short*)C0)[(size_t)row * 512 + col] = f2bfu(v);
                } else if constexpr (EPI == 1) {
                    // col in [0,1536): j = part*512 + h*64 + d ; row = b*2048 + n
                    const int part = col >> 9, hh = (col >> 6) & 7, d = col & 63;
                    const int b = row >> 11, n = row & 2047;
                    const size_t bh = (size_t)(b * 8 + hh);
                    if (part == 0)
                        ((unsigned short*)C0)[(bh * 2048 + n) * 64 + d] = f2bfu(v * 0.1803368801111244f);
                    else if (part == 1)
                        ((unsigned short*)C1)[(bh * 2048 + n) * 64 + d] = f2bfu(v);
                    else
                        ((unsigned short*)C2)[(bh * 64 + d) * 2048 + n] = f2bfu(v);
                } else if constexpr (EPI == 2) {
                    const float sg = 1.0f / (1.0f + __expf(-v));
                    ((unsigned short*)C0)[(size_t)blockIdx.z * sC + (size_t)row * 2048 + col] = f2bfu(sg);
                } else {
                    ((float*)C0)[(size_t)row * 512 + col] = v + bias[col];
                }
            }
        }
    }
}

// ---------------- GroupNorm partial stats: 256 blocks = (b,g,chunk) ----------------
__global__ __launch_bounds__(256) void gn_stats_part(const unsigned short* __restrict__ c1,
                                                     const unsigned short* __restrict__ c2,
                                                     float* __restrict__ part) {
    const int bgc = blockIdx.x;                 // b*64 + g*8 + ch
    const int b = bgc >> 6, g = (bgc >> 3) & 7, ch = bgc & 7;
    const int tid = threadIdx.x;
    const size_t base = ((size_t)b * 2048 + ch * 256) * 512 + g * 64;
    float s1 = 0.f, q1 = 0.f, s2 = 0.f, q2 = 0.f;
    for (int c = tid; c < 2048; c += 256) {     // 256 rows x 8 vec8 chunks
        const int n = c >> 3, i8 = (c & 7) * 8;
        const size_t off = base + (size_t)n * 512 + i8;
        uint4 v1 = *reinterpret_cast<const uint4*>(c1 + off);
        uint4 v2 = *reinterpret_cast<const uint4*>(c2 + off);
        unsigned int a1[4] = {v1.x, v1.y, v1.z, v1.w};
        unsigned int a2[4] = {v2.x, v2.y, v2.z, v2.w};
#pragma unroll
        for (int j = 0; j < 4; j++) {
            float x0 = bfu2f(a1[j] & 0xffffu), x1 = bfu2f(a1[j] >> 16);
            s1 += x0 + x1; q1 += x0 * x0 + x1 * x1;
            float y0 = bfu2f(a2[j] & 0xffffu), y1 = bfu2f(a2[j] >> 16);
            s2 += y0 + y1; q2 += y0 * y0 + y1 * y1;
        }
    }
#pragma unroll
    for (int off = 32; off >= 1; off >>= 1) {
        s1 += __shfl_down(s1, off); q1 += __shfl_down(q1, off);
        s2 += __shfl_down(s2, off); q2 += __shfl_down(q2, off);
    }
    __shared__ float red[4][4];
    if ((tid & 63) == 0) {
        const int wv = tid >> 6;
        red[0][wv] = s1; red[1][wv] = q1; red[2][wv] = s2; red[3][wv] = q2;
    }
    __syncthreads();
    if (tid == 0) {
        part[bgc * 4 + 0] = red[0][0] + red[0][1] + red[0][2] + red[0][3];
        part[bgc * 4 + 1] = red[1][0] + red[1][1] + red[1][2] + red[1][3];
        part[bgc * 4 + 2] = red[2][0] + red[2][1] + red[2][2] + red[2][3];
        part[bgc * 4 + 3] = red[3][0] + red[3][1] + red[3][2] + red[3][3];
    }
}

// ---------------- GroupNorm apply (in place), finish folded in ----------------
__global__ __launch_bounds__(256) void gn_apply(unsigned short* __restrict__ c1,
                                                unsigned short* __restrict__ c2,
                                                const float* __restrict__ part,
                                                const float* __restrict__ g1, const float* __restrict__ b1,
                                                const float* __restrict__ g2, const float* __restrict__ b2) {
    __shared__ float sst[32][4];
    const int tid = threadIdx.x;
    if (tid < 32) {
        float S1 = 0.f, Q1 = 0.f, S2 = 0.f, Q2 = 0.f;
        for (int ch = 0; ch < 8; ch++) {
            const float* p = part + ((tid << 3) + ch) * 4;
            S1 += p[0]; Q1 += p[1]; S2 += p[2]; Q2 += p[3];
        }
        const float inv = 1.0f / 131072.0f;
        float m1 = S1 * inv, m2 = S2 * inv;
        float v1 = fmaxf(Q1 * inv - m1 * m1, 0.f);
        float v2 = fmaxf(Q2 * inv - m2 * m2, 0.f);
        sst[tid][0] = m1;
        sst[tid][1] = rsqrtf(v1 + 1e-5f);
        sst[tid][2] = m2;
        sst[tid][3] = rsqrtf(v2 + 1e-5f);
    }
    __syncthreads();
    int i = blockIdx.x * 256 + tid;
    const int stride = gridDim.x * 256;
    for (; i < 524288; i += stride) {           // 4*2048*512/8 chunks
        const size_t e = (size_t)i * 8;
        const int b = (int)(e >> 20);           // N*C = 2^20
        const int o = (int)(e & 511);
        const int g = o >> 6;
        const float* st = sst[(b << 3) + g];
        const float m1 = st[0], r1 = st[1], m2 = st[2], r2 = st[3];
        uint4 v1 = *reinterpret_cast<const uint4*>(c1 + e);
        uint4 v2 = *reinterpret_cast<const uint4*>(c2 + e);
        unsigned int a1[4] = {v1.x, v1.y, v1.z, v1.w};
        unsigned int a2[4] = {v2.x, v2.y, v2.z, v2.w};
        unsigned int o1[4], o2[4];
#pragma unroll
        for (int j = 0; j < 4; j++) {
            const int oo = o + j * 2;
            float x0 = (bfu2f(a1[j] & 0xffffu) - m1) * r1 * g1[oo] + b1[oo];
            float x1 = (bfu2f(a1[j] >> 16) - m1) * r1 * g1[oo + 1] + b1[oo + 1];
            o1[j] = (unsigned int)f2bfu(x0) | ((unsigned int)f2bfu(x1) << 16);
            float y0 = (bfu2f(a2[j] & 0xffffu) - m2) * r2 * g2[oo] + b2[oo];
            float y1 = (bfu2f(a2[j] >> 16) - m2) * r2 * g2[oo + 1] + b2[oo + 1];
            o2[j] = (unsigned int)f2bfu(y0) | ((unsigned int)f2bfu(y1) << 16);
        }
        uint4 w1; w1.x = o1[0]; w1.y = o1[1]; w1.z = o1[2]; w1.w = o1[3];
        uint4 w2; w2.x = o2[0]; w2.y = o2[1]; w2.z = o2[2]; w2.w = o2[3];
        *reinterpret_cast<uint4*>(c1 + e) = w1;
        *reinterpret_cast<uint4*>(c2 + e) = w2;
    }
}

// ---------------- fused flash attention, swapped-QK^T, exp2-domain softmax ----------------
// flat grid 1024: h = bid>>7 (same (nt,b) => same bid mod 8 => same XCD for all 8 heads).
// block 256 = 4 waves, wave w owns q-rows [16w,16w+16).  S^T = mfma(K,Q): lane: q=lr, k=16mf+4lh+r.
// K/V^T double-buffered via global_load_lds (XOR-16B-slot swizzle).
// pe held in REGISTERS (4x dwordx2/lane), prefetched one tile ahead.
// Pl: dedicated per-wave buffer (wave-private -> NO barrier between QK^T and PV).
// ONE barrier per iteration (vmcnt+lgkm before buffer swap).  LDS 40960 B -> 4 blocks/CU (160KB exact).
__global__ __launch_bounds__(256, 4) void attn_fused(
    const unsigned short* __restrict__ qb, const unsigned short* __restrict__ kb,
    const unsigned short* __restrict__ vT, const unsigned short* __restrict__ pea,
    unsigned short* __restrict__ hbuf) {
    __shared__ unsigned short Ks[2][64 * 64];
    __shared__ unsigned short Vs[2][64 * 64];
    __shared__ unsigned short Pl[4][16 * 64];
    const int tid = threadIdx.x, l = tid & 63, w = tid >> 6;
    const int lr = l & 15, lh = l >> 4;
    const int bid = blockIdx.x;
    const int h = bid >> 7, rst = bid & 127, nt = rst & 31, b = rst >> 5;
    const size_t bh = (size_t)(b * 8 + h);
    const unsigned short* qp = qb + bh * 2048 * 64;
    const unsigned short* kp = kb + bh * 2048 * 64;
    const unsigned short* vp = vT + bh * 64 * 2048;
    const unsigned short* pep = pea + (size_t)b * 2048 * 2048;   // [q][k] orientation
    const int n0 = nt * 64;

    // Q B-fragments (pre-scaled by 0.125*log2e at QKV epilogue)
    bf16x8 qf[2];
    qf[0] = *reinterpret_cast<const bf16x8*>(qp + (size_t)(n0 + 16 * w + lr) * 64 + lh * 8);
    qf[1] = *reinterpret_cast<const bf16x8*>(qp + (size_t)(n0 + 16 * w + lr) * 64 + 32 + lh * 8);

    // swizzled read columns (shorts) for K/V A-fragments
    const int swz = (lr & 7) << 4;                       // byte XOR
    const int colK0 = ((16 * lh) ^ swz) >> 1;
    const int colK1 = ((64 + 16 * lh) ^ swz) >> 1;

    // pe register path: lane's q-row pointer; per tile 4x 8B loads (k = 16mf+4lh .. +3)
    const unsigned short* perp = pep + (size_t)(n0 + 16 * w + lr) * 2048;
    uint2 peR[4];
#pragma unroll
    for (int mf = 0; mf < 4; mf++)
        peR[mf] = *reinterpret_cast<const uint2*>(perp + 16 * mf + 4 * lh);

    f32x4 oacc[4] = {};
    float mrun = -1e30f, lrun = 0.f;

    // async staging: lane -> (row = base + l>>3, slot = l&7), source col-slot = slot ^ (row&7)
    const int srow = l >> 3, sslot = l & 7;
    auto stage_kv = [&](int bufi, int m0) {
#pragma unroll
        for (int i = 0; i < 2; i++) {
            const int row = w * 16 + i * 8 + srow;
            const int cs = (sslot ^ (row & 7)) * 8;
            const int ldsoff = (w * 16 + i * 8) * 64;
            __builtin_amdgcn_global_load_lds(
                (const __attribute__((address_space(1))) void*)(kp + (size_t)(m0 + row) * 64 + cs),
                (__attribute__((address_space(3))) void*)&Ks[bufi][ldsoff], 16, 0, 0);
            __builtin_amdgcn_global_load_lds(
                (const __attribute__((address_space(1))) void*)(vp + (size_t)row * 2048 + m0 + cs),
                (__attribute__((address_space(3))) void*)&Vs[bufi][ldsoff], 16, 0, 0);
        }
    };

    stage_kv(0, 0);
    asm volatile("s_waitcnt vmcnt(0)" ::: "memory");
    __builtin_amdgcn_s_barrier();
    __builtin_amdgcn_sched_barrier(0);

    for (int mt = 0; mt < 32; mt++) {
        const int cur = mt & 1;
        if (mt + 1 < 32) stage_kv(cur ^ 1, (mt + 1) * 64);
        const unsigned short* Kb = Ks[cur];
        const unsigned short* Vb = Vs[cur];

        // S^T: rows k (4 frags), cols q
        f32x4 st[4] = {};
        __builtin_amdgcn_s_setprio(1);
#pragma unroll
        for (int mf = 0; mf < 4; mf++) {
            bf16x8 kf0 = *reinterpret_cast<const bf16x8*>(&Kb[(mf * 16 + lr) * 64 + colK0]);
            bf16x8 kf1 = *reinterpret_cast<const bf16x8*>(&Kb[(mf * 16 + lr) * 64 + colK1]);
            st[mf] = __builtin_amdgcn_mfma_f32_16x16x32_bf16(kf0, qf[0], st[mf], 0, 0, 0);
            st[mf] = __builtin_amdgcn_mfma_f32_16x16x32_bf16(kf1, qf[1], st[mf], 0, 0, 0);
        }
        __builtin_amdgcn_s_setprio(0);

        // logits (log2-domain): p = S^T * pe   (0.125*log2e folded into Q)
        float p[4][4];
#pragma unroll
        for (int mf = 0; mf < 4; mf++) {
            p[mf][0] = st[mf][0] * bfu2f(peR[mf].x & 0xffffu);
            p[mf][1] = st[mf][1] * bfu2f(peR[mf].x >> 16);
            p[mf][2] = st[mf][2] * bfu2f(peR[mf].y & 0xffffu);
            p[mf][3] = st[mf][3] * bfu2f(peR[mf].y >> 16);
        }
        // prefetch next pe tile into regs (latency hidden under softmax+PV)
        uint2 peN[4];
        if (mt + 1 < 32) {
            const unsigned short* pn = perp + (mt + 1) * 64;
#pragma unroll
            for (int mf = 0; mf < 4; mf++)
                peN[mf] = *reinterpret_cast<const uint2*>(pn + 16 * mf + 4 * lh);
        }
        // row max: lane-local max chain + butterfly across lh groups
        float pm = fmaxf(p[0][0], p[0][1]);
        pm = fmaxf(fmaxf(pm, p[0][2]), p[0][3]);
#pragma unroll
        for (int mf = 1; mf < 4; mf++) {
            pm = fmaxf(fmaxf(pm, p[mf][0]), p[mf][1]);
            pm = fmaxf(fmaxf(pm, p[mf][2]), p[mf][3]);
        }
        pm = fmaxf(pm, __shfl_xor(pm, 16));
        pm = fmaxf(pm, __shfl_xor(pm, 32));
        // defer-max (threshold 8*log2e in log2 domain)
        if (__any(pm > mrun + 11.5416f)) {
            const float mnew = fmaxf(mrun, pm);
            const float fac = __builtin_amdgcn_exp2f(mrun - mnew);
            lrun *= fac;
#pragma unroll
            for (int df = 0; df < 4; df++)
#pragma unroll
                for (int r = 0; r < 4; r++) oacc[df][r] *= fac;
            mrun = mnew;
        }
        // P = exp2(p - mrun); pack pairs with v_cvt_pk_bf16_f32; sum unrounded (bias ~1e-5, ok)
        float ss = 0.f;
        unsigned int pk[8];
#pragma unroll
        for (int mf = 0; mf < 4; mf++) {
#pragma unroll
            for (int t = 0; t < 2; t++) {
                const float a = __builtin_amdgcn_exp2f(p[mf][2 * t] - mrun);
                const float c = __builtin_amdgcn_exp2f(p[mf][2 * t + 1] - mrun);
                unsigned int pkv;
                asm("v_cvt_pk_bf16_f32 %0, %1, %2" : "=v"(pkv) : "v"(a), "v"(c));
                pk[mf * 2 + t] = pkv;
                ss += a + c;
            }
        }
        ss += __shfl_xor(ss, 16);
        ss += __shfl_xor(ss, 32);
        lrun += ss;
        // P -> per-wave Pl (wave-private, no barrier needed).
        // Row q=lr: 64 shorts (k=0..63), stride 64; XOR-16B swizzle by lr&7 for bank spread.
        unsigned short* PlW = Pl[w];
        const int plswz = (lr & 7) << 4;               // byte XOR within 128B row
#pragma unroll
        for (int mf = 0; mf < 4; mf++)
#pragma unroll
            for (int t = 0; t < 2; t++) {
                const int cb = (mf * 32 + lh * 8 + 4 * t) ^ plswz;
                *reinterpret_cast<unsigned int*>(&PlW[lr * 64 + (cb >> 1)]) = pk[mf * 2 + t];
            }
        bf16x8 pb0 = *reinterpret_cast<const bf16x8*>(&PlW[lr * 64 + (((lh * 16) ^ plswz) >> 1)]);
        bf16x8 pb1 = *reinterpret_cast<const bf16x8*>(&PlW[lr * 64 + (((64 + lh * 16) ^ plswz) >> 1)]);
        // out^T[d][q] += sum_k V^T[d][k] * P[q][k]
        __builtin_amdgcn_s_setprio(1);
#pragma unroll
        for (int df = 0; df < 4; df++) {
            bf16x8 vf0 = *reinterpret_cast<const bf16x8*>(&Vb[(df * 16 + lr) * 64 + colK0]);
            bf16x8 vf1 = *reinterpret_cast<const bf16x8*>(&Vb[(df * 16 + lr) * 64 + colK1]);
            oacc[df] = __builtin_amdgcn_mfma_f32_16x16x32_bf16(vf0, pb0, oacc[df], 0, 0, 0);
            oacc[df] = __builtin_amdgcn_mfma_f32_16x16x32_bf16(vf1, pb1, oacc[df], 0, 0, 0);
        }
        __builtin_amdgcn_s_setprio(0);
        if (mt + 1 < 32) {
            // barrier: stage(t+1) landed (vmcnt) + all waves done with Ks/Vs[cur] (lgkm)
            asm volatile("s_waitcnt vmcnt(0) lgkmcnt(0)" ::: "memory");
            __builtin_amdgcn_s_barrier();
            __builtin_amdgcn_sched_barrier(0);
#pragma unroll
            for (int mf = 0; mf < 4; mf++) peR[mf] = peN[mf];
        }
    }
    const float inv = 1.0f / lrun;
    const size_t base = ((size_t)b * 2048 + n0 + 16 * w + lr) * 512 + h * 64;
#pragma unroll
    for (int df = 0; df < 4; df++) {
#pragma unroll
        for (int t = 0; t < 2; t++) {
            const unsigned int ua = f2bfu(oacc[df][2 * t] * inv);
            const unsigned int uc = f2bfu(oacc[df][2 * t + 1] * inv);
            *reinterpret_cast<unsigned int*>(&hbuf[base + 16 * df + 4 * lh + 2 * t]) = ua | (uc << 16);
        }
    }
}

extern "C" void kernel_launch(void* const* d_in, const int* in_sizes, int n_in,
                              void* d_out, int out_size, void* d_ws, size_t ws_size,
                              hipStream_t stream) {
    const float* x       = (const float*)d_in[0];
    const float* pe      = (const float*)d_in[1];
    const float* qkv_w   = (const float*)d_in[2];
    const float* proj_w  = (const float*)d_in[3];
    const float* proj_b  = (const float*)d_in[4];
    const float* conv1_w = (const float*)d_in[5];
    const float* conv1_b = (const float*)d_in[6];
    const float* gn1_g   = (const float*)d_in[7];
    const float* gn1_b   = (const float*)d_in[8];
    const float* conv2_w = (const float*)d_in[9];
    const float* conv2_b = (const float*)d_in[10];
    const float* gn2_g   = (const float*)d_in[11];
    const float* gn2_b   = (const float*)d_in[12];
    float* out = (float*)d_out;

    char* ws = (char*)d_ws;
    size_t off = 0;
    auto alloc = [&](size_t bytes) -> void* {
        void* p = ws + off;
        off += (bytes + 255) & ~(size_t)255;
        return p;
    };
    unsigned short* xb     = (unsigned short*)alloc(8388608);   // x bf16 [B*N, C]
    unsigned short* peb    = (unsigned short*)alloc(8388608);   // pe bf16
    unsigned short* qkvwb  = (unsigned short*)alloc(1572864);   // qkv_w bf16 [1536,512]
    unsigned short* projwb = (unsigned short*)alloc(524288);
    unsigned short* w1b    = (unsigned short*)alloc(524288);
    unsigned short* w2b    = (unsigned short*)alloc(524288);
    unsigned short* c1b    = (unsigned short*)alloc(8388608);   // conv1 out -> p1 (in place GN)
    unsigned short* c2b    = (unsigned short*)alloc(8388608);
    unsigned short* qbuf   = (unsigned short*)alloc(8388608);   // [B,H,N,D] (q pre-scaled)
    unsigned short* kbuf   = (unsigned short*)alloc(8388608);
    unsigned short* vtb    = (unsigned short*)alloc(8388608);   // [B,H,D,N]
    unsigned short* peatt  = (unsigned short*)alloc(33554432);  // pe_attn [B,N(q),N(k)] bf16
    unsigned short* hbuf   = (unsigned short*)alloc(8388608);   // [B,N,C] bf16
    float* part            = (float*)alloc(4096);

    dim3 blk(256);
    cvt2<<<1024, blk, 0, stream>>>(x, xb, pe, peb);
    cvtw<<<512, blk, 0, stream>>>(qkv_w, qkvwb, proj_w, projwb, conv1_w, w1b, conv2_w, w2b);

    // conv1/conv2 (per-position linear over channels), bias, bf16 out [B,N,C]
    gemm_nt<0><<<dim3(4, 64, 1), blk, 0, stream>>>(peb, w1b, c1b, nullptr, nullptr, conv1_b, 512, 0, 0, 0);
    gemm_nt<0><<<dim3(4, 64, 1), blk, 0, stream>>>(peb, w2b, c2b, nullptr, nullptr, conv2_b, 512, 0, 0, 0);
    gn_stats_part<<<256, blk, 0, stream>>>(c1b, c2b, part);
    gn_apply<<<1024, blk, 0, stream>>>(c1b, c2b, part, gn1_g, gn1_b, gn2_g, gn2_b);
    // qkv = x @ qkv_w.T, scattered to q (x0.125*log2e), k [B,H,N,D] and vT [B,H,D,N]
    gemm_nt<1><<<dim3(12, 64, 1), blk, 0, stream>>>(xb, qkvwb, qbuf, kbuf, vtb, nullptr, 512, 0, 0, 0);
    // pe_attn[b][n][m] = sigmoid(sum_k p1[n][k] p2[m][k])  ([q][k] orientation)
    gemm_nt<2><<<dim3(16, 16, 4), blk, 0, stream>>>(c1b, c2b, peatt, nullptr, nullptr, nullptr, 512,
                                                    1048576, 1048576, 4194304);
    attn_fused<<<dim3(1024, 1, 1), blk, 0, stream>>>(qbuf, kbuf, vtb, peatt, hbuf);
    // proj: out = h @ proj_w.T + proj_b (f32)
    gemm_nt<3><<<dim3(4, 64, 1), blk, 0, stream>>>(hbuf, projwb, out, nullptr, nullptr, proj_b, 512, 0, 0, 0);
}

// Round 9
// 228.606 us; speedup vs baseline: 1.4358x; 1.0170x over previous
//
#include <hip/hip_runtime.h>
#include <hip/hip_bf16.h>

// Shapes (fixed): B=4, N=2048, C=512, H=8, D=64, GROUPS=8, C/G=64
typedef __attribute__((ext_vector_type(8))) short bf16x8;
typedef __attribute__((ext_vector_type(4))) float f32x4;

__device__ __forceinline__ float bfu2f(unsigned int u) {
    return __uint_as_float(u << 16);
}
__device__ __forceinline__ unsigned short f2bfu(float f) {
    unsigned int u = __float_as_uint(f);
    u += 0x7fffu + ((u >> 16) & 1u);   // RNE
    return (unsigned short)(u >> 16);
}

// ---------------- all fp32->bf16 conversions + bias gather, one launch ----------------
__global__ __launch_bounds__(256) void cvt_all(
    const float* __restrict__ x, unsigned short* __restrict__ xb,
    const float* __restrict__ pe, unsigned short* __restrict__ peb,
    const float* __restrict__ w0, unsigned short* __restrict__ d0,
    const float* __restrict__ w1, unsigned short* __restrict__ d1,
    const float* __restrict__ w2, unsigned short* __restrict__ d2,
    const float* __restrict__ w3, unsigned short* __restrict__ d3,
    const float* __restrict__ c1bias, const float* __restrict__ c2bias,
    float* __restrict__ biasws) {
    const int tid = threadIdx.x;
    if (blockIdx.x == 0) {
        if (tid < 128) ((float4*)biasws)[tid] = ((const float4*)c1bias)[tid];
        else ((float4*)biasws)[tid] = ((const float4*)c2bias)[tid - 128];
    }
    int i = blockIdx.x * 256 + tid;
    const int stride = gridDim.x * 256;
    for (; i < 1441792; i += stride) {
        if (i < 1048576) {
            float4 v = reinterpret_cast<const float4*>(x)[i];
            ushort4 o;
            o.x = f2bfu(v.x); o.y = f2bfu(v.y); o.z = f2bfu(v.z); o.w = f2bfu(v.w);
            reinterpret_cast<ushort4*>(xb)[i] = o;
            float4 u = reinterpret_cast<const float4*>(pe)[i];
            ushort4 p;
            p.x = f2bfu(u.x); p.y = f2bfu(u.y); p.z = f2bfu(u.z); p.w = f2bfu(u.w);
            reinterpret_cast<ushort4*>(peb)[i] = p;
        } else {
            int j = i - 1048576;
            const float* s; unsigned short* d;
            if (j < 196608)      { s = w0; d = d0; }
            else if (j < 262144) { s = w1; d = d1; j -= 196608; }
            else if (j < 327680) { s = w2; d = d2; j -= 262144; }
            else                 { s = w3; d = d3; j -= 327680; }
            float4 v = reinterpret_cast<const float4*>(s)[j];
            ushort4 o;
            o.x = f2bfu(v.x); o.y = f2bfu(v.y); o.z = f2bfu(v.z); o.w = f2bfu(v.w);
            reinterpret_cast<ushort4*>(d)[j] = o;
        }
    }
}

// ---------------- generic NT GEMM, bf16 in, MFMA 16x16x32, m97-style staging ----------------
// C[m][n] = sum_k A[m][k] * B[n][k].  128x128 tile, BK=32, 4 waves (2x2 of 64x64).
// Staging: global_load_lds width 16, double-buffered linear LDS [2][128][32],
// source pre-swizzle slot^=(row&3), read col (lh^(lr&3))*8 (same involution both sides).
// EPI: 0 = conv pair z=2 (bf16 out ld512, +bias from biasws, fused GN stats atomics via C1),
//      1 = qkv scatter (q*0.125*log2e, k, vT), 2 = sigmoid bf16 (ld2048, batched),
//      3 = proj (f32 out ld512, +bias)
template <int EPI>
__global__ __launch_bounds__(256) void gemm_nt(
    const unsigned short* __restrict__ A, const unsigned short* __restrict__ B,
    void* __restrict__ C0, void* __restrict__ C1, void* __restrict__ C2,
    const float* __restrict__ bias, int K, long sA, long sB, long sC) {
    __shared__ unsigned short As[2][128 * 32];
    __shared__ unsigned short Bs[2][128 * 32];
    const int tid = threadIdx.x;
    const int l = tid & 63, w = tid >> 6;
    const int wr = w >> 1, wc = w & 1, lr = l & 15, lh = l >> 4;
    const int m0 = blockIdx.y * 128, n0 = blockIdx.x * 128;
    A += (size_t)blockIdx.z * sA;
    B += (size_t)blockIdx.z * sB;
    f32x4 acc[4][4] = {};

    // wave w stages rows [w*32, w*32+32): 2 instrs per matrix, lane -> (row=base+l>>2, slot=l&3)
    const int srow = l >> 2, sslot = l & 3;
    auto stage = [&](int bufi, int k0) {
#pragma unroll
        for (int i = 0; i < 2; i++) {
            const int row = w * 32 + i * 16 + srow;
            const int cs = (sslot ^ (row & 3)) * 8;      // pre-swizzled source col (shorts)
            const int ldsoff = (w * 32 + i * 16) * 32;   // linear LDS base (wave-uniform)
            __builtin_amdgcn_global_load_lds(
                (const __attribute__((address_space(1))) void*)(A + (size_t)(m0 + row) * K + k0 + cs),
                (__attribute__((address_space(3))) void*)&As[bufi][ldsoff], 16, 0, 0);
            __builtin_amdgcn_global_load_lds(
                (const __attribute__((address_space(1))) void*)(B + (size_t)(n0 + row) * K + k0 + cs),
                (__attribute__((address_space(3))) void*)&Bs[bufi][ldsoff], 16, 0, 0);
        }
    };

    const int nks = K >> 5;
    stage(0, 0);
    asm volatile("s_waitcnt vmcnt(0)" ::: "memory");
    __builtin_amdgcn_s_barrier();
    __builtin_amdgcn_sched_barrier(0);

    // read col: logical slot lh of row a lives at physical slot lh^(a&3); a&3 == lr&3 for all frags
    const int colA = (lh ^ (lr & 3)) << 3;
    for (int ks = 0; ks < nks; ks++) {
        const int cur = ks & 1;
        if (ks + 1 < nks) stage(cur ^ 1, (ks + 1) << 5);
        bf16x8 af[4], bfr[4];
#pragma unroll
        for (int i = 0; i < 4; i++)
            af[i] = *reinterpret_cast<const bf16x8*>(&As[cur][(wr * 64 + i * 16 + lr) * 32 + colA]);
#pragma unroll
        for (int i = 0; i < 4; i++)
            bfr[i] = *reinterpret_cast<const bf16x8*>(&Bs[cur][(wc * 64 + i * 16 + lr) * 32 + colA]);
        __builtin_amdgcn_s_setprio(1);
#pragma unroll
        for (int mi = 0; mi < 4; mi++)
#pragma unroll
            for (int ni = 0; ni < 4; ni++)
                acc[mi][ni] = __builtin_amdgcn_mfma_f32_16x16x32_bf16(af[mi], bfr[ni], acc[mi][ni], 0, 0, 0);
        __builtin_amdgcn_s_setprio(0);
        if (ks + 1 < nks) {
            // stage(ks+1) landed (vmcnt) + all waves done reading buffer cur (lgkm)
            asm volatile("s_waitcnt vmcnt(0) lgkmcnt(0)" ::: "memory");
            __builtin_amdgcn_s_barrier();
            __builtin_amdgcn_sched_barrier(0);
        }
    }

    float sgn = 0.f, qgn = 0.f;   // fused GN partial stats (EPI==0)
#pragma unroll
    for (int mi = 0; mi < 4; mi++) {
#pragma unroll
        for (int ni = 0; ni < 4; ni++) {
#pragma unroll
            for (int r = 0; r < 4; r++) {
                const int row = m0 + wr * 64 + mi * 16 + lh * 4 + r;
                const int col = n0 + wc * 64 + ni * 16 + lr;
                float v = acc[mi][ni][r];
                if constexpr (EPI == 0) {
                    v += bias[blockIdx.z * 512 + col];
                    sgn += v; qgn += v * v;
                    ((unsigned short*)C0)[(size_t)blockIdx.z * sC + (size_t)row * 512 + col] = f2bfu(v);
                } else if constexpr (EPI == 1) {
                    // col in [0,1536): j = part*512 + h*64 + d ; row = b*2048 + n
                    const int part = col >> 9, hh = (col >> 6) & 7, d = col & 63;
                    const int b = row >> 11, n = row & 2047;
                    const size_t bh = (size_t)(b * 8 + hh);
                    if (part == 0)
                        ((unsigned short*)C0)[(bh * 2048 + n) * 64 + d] = f2bfu(v * 0.1803368801111244f);
                    else if (part == 1)
                        ((unsigned short*)C1)[(bh * 2048 + n) * 64 + d] = f2bfu(v);
                    else
                        ((unsigned short*)C2)[(bh * 64 + d) * 2048 + n] = f2bfu(v);
                } else if constexpr (EPI == 2) {
                    const float sg = 1.0f / (1.0f + __expf(-v));
                    ((unsigned short*)C0)[(size_t)blockIdx.z * sC + (size_t)row * 2048 + col] = f2bfu(sg);
                } else {
                    ((float*)C0)[(size_t)row * 512 + col] = v + bias[col];
                }
            }
        }
    }
    if constexpr (EPI == 0) {
        // wave holds one (b,g): b = blockIdx.y>>4, g = blockIdx.x*2+wc
#pragma unroll
        for (int s = 1; s < 64; s <<= 1) {
            sgn += __shfl_xor(sgn, s);
            qgn += __shfl_xor(qgn, s);
        }
        if (l == 0) {
            const int bg = ((blockIdx.y >> 4) << 3) + blockIdx.x * 2 + wc;
            float* part = (float*)C1;
            atomicAdd(&part[(blockIdx.z * 32 + bg) * 2 + 0], sgn);
            atomicAdd(&part[(blockIdx.z * 32 + bg) * 2 + 1], qgn);
        }
    }
}

// ---------------- GroupNorm apply (in place), stats finish folded in ----------------
__global__ __launch_bounds__(256) void gn_apply(unsigned short* __restrict__ c1,
                                                unsigned short* __restrict__ c2,
                                                const float* __restrict__ part,
                                                const float* __restrict__ g1, const float* __restrict__ b1,
                                                const float* __restrict__ g2, const float* __restrict__ b2) {
    __shared__ float sst[2][32][2];
    const int tid = threadIdx.x;
    if (tid < 64) {
        const int z = tid >> 5, bg = tid & 31;
        const float S = part[(z * 32 + bg) * 2 + 0];
        const float Q = part[(z * 32 + bg) * 2 + 1];
        const float inv = 1.0f / 131072.0f;
        const float m = S * inv;
        const float v = fmaxf(Q * inv - m * m, 0.f);
        sst[z][bg][0] = m;
        sst[z][bg][1] = rsqrtf(v + 1e-5f);
    }
    __syncthreads();
    int i = blockIdx.x * 256 + tid;
    const int stride = gridDim.x * 256;
    for (; i < 524288; i += stride) {           // 4*2048*512/8 chunks
        const size_t e = (size_t)i * 8;
        const int b = (int)(e >> 20);           // N*C = 2^20
        const int o = (int)(e & 511);
        const int g = o >> 6;
        const int bg = (b << 3) + g;
        const float m1 = sst[0][bg][0], r1 = sst[0][bg][1];
        const float m2 = sst[1][bg][0], r2 = sst[1][bg][1];
        uint4 v1 = *reinterpret_cast<const uint4*>(c1 + e);
        uint4 v2 = *reinterpret_cast<const uint4*>(c2 + e);
        unsigned int a1[4] = {v1.x, v1.y, v1.z, v1.w};
        unsigned int a2[4] = {v2.x, v2.y, v2.z, v2.w};
        unsigned int o1[4], o2[4];
#pragma unroll
        for (int j = 0; j < 4; j++) {
            const int oo = o + j * 2;
            float x0 = (bfu2f(a1[j] & 0xffffu) - m1) * r1 * g1[oo] + b1[oo];
            float x1 = (bfu2f(a1[j] >> 16) - m1) * r1 * g1[oo + 1] + b1[oo + 1];
            o1[j] = (unsigned int)f2bfu(x0) | ((unsigned int)f2bfu(x1) << 16);
            float y0 = (bfu2f(a2[j] & 0xffffu) - m2) * r2 * g2[oo] + b2[oo];
            float y1 = (bfu2f(a2[j] >> 16) - m2) * r2 * g2[oo + 1] + b2[oo + 1];
            o2[j] = (unsigned int)f2bfu(y0) | ((unsigned int)f2bfu(y1) << 16);
        }
        uint4 w1; w1.x = o1[0]; w1.y = o1[1]; w1.z = o1[2]; w1.w = o1[3];
        uint4 w2; w2.x = o2[0]; w2.y = o2[1]; w2.z = o2[2]; w2.w = o2[3];
        *reinterpret_cast<uint4*>(c1 + e) = w1;
        *reinterpret_cast<uint4*>(c2 + e) = w2;
    }
}

// ---------------- fused flash attention (R7-verified version, verbatim) ----------------
// flat grid 1024: h = bid>>7.  block 256 = 4 waves, wave w owns q-rows [16w,16w+16).
// S^T = mfma(K,Q): lane: q=lr, k=16mf+4lh+r.  K/V^T double-buffered via global_load_lds.
// pe in registers.  Pl dedicated per-wave buffer.  One barrier per iteration.
__global__ __launch_bounds__(256, 4) void attn_fused(
    const unsigned short* __restrict__ qb, const unsigned short* __restrict__ kb,
    const unsigned short* __restrict__ vT, const unsigned short* __restrict__ pea,
    unsigned short* __restrict__ hbuf) {
    __shared__ unsigned short Ks[2][64 * 64];
    __shared__ unsigned short Vs[2][64 * 64];
    __shared__ unsigned short Pl[4][16 * 64];
    const int tid = threadIdx.x, l = tid & 63, w = tid >> 6;
    const int lr = l & 15, lh = l >> 4;
    const int bid = blockIdx.x;
    const int h = bid >> 7, rst = bid & 127, nt = rst & 31, b = rst >> 5;
    const size_t bh = (size_t)(b * 8 + h);
    const unsigned short* qp = qb + bh * 2048 * 64;
    const unsigned short* kp = kb + bh * 2048 * 64;
    const unsigned short* vp = vT + bh * 64 * 2048;
    const unsigned short* pep = pea + (size_t)b * 2048 * 2048;   // [q][k] orientation
    const int n0 = nt * 64;

    // Q B-fragments (pre-scaled by 0.125*log2e at QKV epilogue)
    bf16x8 qf[2];
    qf[0] = *reinterpret_cast<const bf16x8*>(qp + (size_t)(n0 + 16 * w + lr) * 64 + lh * 8);
    qf[1] = *reinterpret_cast<const bf16x8*>(qp + (size_t)(n0 + 16 * w + lr) * 64 + 32 + lh * 8);

    // swizzled read columns (shorts) for K/V A-fragments
    const int swz = (lr & 7) << 4;                       // byte XOR
    const int colK0 = ((16 * lh) ^ swz) >> 1;
    const int colK1 = ((64 + 16 * lh) ^ swz) >> 1;

    // pe register path: lane's q-row pointer; per tile 4x 8B loads (k = 16mf+4lh .. +3)
    const unsigned short* perp = pep + (size_t)(n0 + 16 * w + lr) * 2048;
    uint2 peR[4];
#pragma unroll
    for (int mf = 0; mf < 4; mf++)
        peR[mf] = *reinterpret_cast<const uint2*>(perp + 16 * mf + 4 * lh);

    f32x4 oacc[4] = {};
    float mrun = -1e30f, lrun = 0.f;

    // async staging: lane -> (row = base + l>>3, slot = l&7), source col-slot = slot ^ (row&7)
    const int srow = l >> 3, sslot = l & 7;
    auto stage_kv = [&](int bufi, int m0) {
#pragma unroll
        for (int i = 0; i < 2; i++) {
            const int row = w * 16 + i * 8 + srow;
            const int cs = (sslot ^ (row & 7)) * 8;
            const int ldsoff = (w * 16 + i * 8) * 64;
            __builtin_amdgcn_global_load_lds(
                (const __attribute__((address_space(1))) void*)(kp + (size_t)(m0 + row) * 64 + cs),
                (__attribute__((address_space(3))) void*)&Ks[bufi][ldsoff], 16, 0, 0);
            __builtin_amdgcn_global_load_lds(
                (const __attribute__((address_space(1))) void*)(vp + (size_t)row * 2048 + m0 + cs),
                (__attribute__((address_space(3))) void*)&Vs[bufi][ldsoff], 16, 0, 0);
        }
    };

    stage_kv(0, 0);
    asm volatile("s_waitcnt vmcnt(0)" ::: "memory");
    __builtin_amdgcn_s_barrier();
    __builtin_amdgcn_sched_barrier(0);

    for (int mt = 0; mt < 32; mt++) {
        const int cur = mt & 1;
        if (mt + 1 < 32) stage_kv(cur ^ 1, (mt + 1) * 64);
        const unsigned short* Kb = Ks[cur];
        const unsigned short* Vb = Vs[cur];

        // S^T: rows k (4 frags), cols q
        f32x4 st[4] = {};
        __builtin_amdgcn_s_setprio(1);
#pragma unroll
        for (int mf = 0; mf < 4; mf++) {
            bf16x8 kf0 = *reinterpret_cast<const bf16x8*>(&Kb[(mf * 16 + lr) * 64 + colK0]);
            bf16x8 kf1 = *reinterpret_cast<const bf16x8*>(&Kb[(mf * 16 + lr) * 64 + colK1]);
            st[mf] = __builtin_amdgcn_mfma_f32_16x16x32_bf16(kf0, qf[0], st[mf], 0, 0, 0);
            st[mf] = __builtin_amdgcn_mfma_f32_16x16x32_bf16(kf1, qf[1], st[mf], 0, 0, 0);
        }
        __builtin_amdgcn_s_setprio(0);

        // logits (log2-domain): p = S^T * pe   (0.125*log2e folded into Q)
        float p[4][4];
#pragma unroll
        for (int mf = 0; mf < 4; mf++) {
            p[mf][0] = st[mf][0] * bfu2f(peR[mf].x & 0xffffu);
            p[mf][1] = st[mf][1] * bfu2f(peR[mf].x >> 16);
            p[mf][2] = st[mf][2] * bfu2f(peR[mf].y & 0xffffu);
            p[mf][3] = st[mf][3] * bfu2f(peR[mf].y >> 16);
        }
        // prefetch next pe tile into regs (latency hidden under softmax+PV)
        uint2 peN[4];
        if (mt + 1 < 32) {
            const unsigned short* pn = perp + (mt + 1) * 64;
#pragma unroll
            for (int mf = 0; mf < 4; mf++)
                peN[mf] = *reinterpret_cast<const uint2*>(pn + 16 * mf + 4 * lh);
        }
        // row max: lane-local max chain + butterfly across lh groups
        float pm = fmaxf(p[0][0], p[0][1]);
        pm = fmaxf(fmaxf(pm, p[0][2]), p[0][3]);
#pragma unroll
        for (int mf = 1; mf < 4; mf++) {
            pm = fmaxf(fmaxf(pm, p[mf][0]), p[mf][1]);
            pm = fmaxf(fmaxf(pm, p[mf][2]), p[mf][3]);
        }
        pm = fmaxf(pm, __shfl_xor(pm, 16));
        pm = fmaxf(pm, __shfl_xor(pm, 32));
        // defer-max (threshold 8*log2e in log2 domain)
        if (__any(pm > mrun + 11.5416f)) {
            const float mnew = fmaxf(mrun, pm);
            const float fac = __builtin_amdgcn_exp2f(mrun - mnew);
            lrun *= fac;
#pragma unroll
            for (int df = 0; df < 4; df++)
#pragma unroll
                for (int r = 0; r < 4; r++) oacc[df][r] *= fac;
            mrun = mnew;
        }
        // P = exp2(p - mrun); pack pairs with v_cvt_pk_bf16_f32; sum unrounded (bias ~1e-5, ok)
        float ss = 0.f;
        unsigned int pk[8];
#pragma unroll
        for (int mf = 0; mf < 4; mf++) {
#pragma unroll
            for (int t = 0; t < 2; t++) {
                const float a = __builtin_amdgcn_exp2f(p[mf][2 * t] - mrun);
                const float c = __builtin_amdgcn_exp2f(p[mf][2 * t + 1] - mrun);
                unsigned int pkv;
                asm("v_cvt_pk_bf16_f32 %0, %1, %2" : "=v"(pkv) : "v"(a), "v"(c));
                pk[mf * 2 + t] = pkv;
                ss += a + c;
            }
        }
        ss += __shfl_xor(ss, 16);
        ss += __shfl_xor(ss, 32);
        lrun += ss;
        // P -> per-wave Pl (wave-private, no barrier needed).
        // Row q=lr: 64 shorts (k=0..63), stride 64; XOR-16B swizzle by lr&7 for bank spread.
        unsigned short* PlW = Pl[w];
        const int plswz = (lr & 7) << 4;               // byte XOR within 128B row
#pragma unroll
        for (int mf = 0; mf < 4; mf++)
#pragma unroll
            for (int t = 0; t < 2; t++) {
                const int cb = (mf * 32 + lh * 8 + 4 * t) ^ plswz;
                *reinterpret_cast<unsigned int*>(&PlW[lr * 64 + (cb >> 1)]) = pk[mf * 2 + t];
            }
        bf16x8 pb0 = *reinterpret_cast<const bf16x8*>(&PlW[lr * 64 + (((lh * 16) ^ plswz) >> 1)]);
        bf16x8 pb1 = *reinterpret_cast<const bf16x8*>(&PlW[lr * 64 + (((64 + lh * 16) ^ plswz) >> 1)]);
        // out^T[d][q] += sum_k V^T[d][k] * P[q][k]
        __builtin_amdgcn_s_setprio(1);
#pragma unroll
        for (int df = 0; df < 4; df++) {
            bf16x8 vf0 = *reinterpret_cast<const bf16x8*>(&Vb[(df * 16 + lr) * 64 + colK0]);
            bf16x8 vf1 = *reinterpret_cast<const bf16x8*>(&Vb[(df * 16 + lr) * 64 + colK1]);
            oacc[df] = __builtin_amdgcn_mfma_f32_16x16x32_bf16(vf0, pb0, oacc[df], 0, 0, 0);
            oacc[df] = __builtin_amdgcn_mfma_f32_16x16x32_bf16(vf1, pb1, oacc[df], 0, 0, 0);
        }
        __builtin_amdgcn_s_setprio(0);
        if (mt + 1 < 32) {
            // barrier: stage(t+1) landed (vmcnt) + all waves done with Ks/Vs[cur] (lgkm)
            asm volatile("s_waitcnt vmcnt(0) lgkmcnt(0)" ::: "memory");
            __builtin_amdgcn_s_barrier();
            __builtin_amdgcn_sched_barrier(0);
#pragma unroll
            for (int mf = 0; mf < 4; mf++) peR[mf] = peN[mf];
        }
    }
    const float inv = 1.0f / lrun;
    const size_t base = ((size_t)b * 2048 + n0 + 16 * w + lr) * 512 + h * 64;
#pragma unroll
    for (int df = 0; df < 4; df++) {
#pragma unroll
        for (int t = 0; t < 2; t++) {
            const unsigned int ua = f2bfu(oacc[df][2 * t] * inv);
            const unsigned int uc = f2bfu(oacc[df][2 * t + 1] * inv);
            *reinterpret_cast<unsigned int*>(&hbuf[base + 16 * df + 4 * lh + 2 * t]) = ua | (uc << 16);
        }
    }
}

extern "C" void kernel_launch(void* const* d_in, const int* in_sizes, int n_in,
                              void* d_out, int out_size, void* d_ws, size_t ws_size,
                              hipStream_t stream) {
    const float* x       = (const float*)d_in[0];
    const float* pe      = (const float*)d_in[1];
    const float* qkv_w   = (const float*)d_in[2];
    const float* proj_w  = (const float*)d_in[3];
    const float* proj_b  = (const float*)d_in[4];
    const float* conv1_w = (const float*)d_in[5];
    const float* conv1_b = (const float*)d_in[6];
    const float* gn1_g   = (const float*)d_in[7];
    const float* gn1_b   = (const float*)d_in[8];
    const float* conv2_w = (const float*)d_in[9];
    const float* conv2_b = (const float*)d_in[10];
    const float* gn2_g   = (const float*)d_in[11];
    const float* gn2_b   = (const float*)d_in[12];
    float* out = (float*)d_out;

    char* ws = (char*)d_ws;
    size_t off = 0;
    auto alloc = [&](size_t bytes) -> void* {
        void* p = ws + off;
        off += (bytes + 255) & ~(size_t)255;
        return p;
    };
    unsigned short* xb     = (unsigned short*)alloc(8388608);   // x bf16 [B*N, C]
    unsigned short* peb    = (unsigned short*)alloc(8388608);   // pe bf16
    unsigned short* qkvwb  = (unsigned short*)alloc(1572864);   // qkv_w bf16 [1536,512]
    unsigned short* projwb = (unsigned short*)alloc(524288);
    unsigned short* w1b    = (unsigned short*)alloc(524288);    // w1b/w2b contiguous (sB=262144)
    unsigned short* w2b    = (unsigned short*)alloc(524288);
    unsigned short* c1b    = (unsigned short*)alloc(8388608);   // c1b/c2b contiguous (sC=4194304)
    unsigned short* c2b    = (unsigned short*)alloc(8388608);
    unsigned short* qbuf   = (unsigned short*)alloc(8388608);   // [B,H,N,D] (q pre-scaled)
    unsigned short* kbuf   = (unsigned short*)alloc(8388608);
    unsigned short* vtb    = (unsigned short*)alloc(8388608);   // [B,H,D,N]
    unsigned short* peatt  = (unsigned short*)alloc(33554432);  // pe_attn [B,N(q),N(k)] bf16
    unsigned short* hbuf   = (unsigned short*)alloc(8388608);   // [B,N,C] bf16
    float* part            = (float*)alloc(512);                // GN stats [2][32][2]
    float* biasws          = (float*)alloc(4096);               // conv biases [2][512]

    dim3 blk(256);
    hipMemsetAsync(part, 0, 512, stream);
    cvt_all<<<2048, blk, 0, stream>>>(x, xb, pe, peb, qkv_w, qkvwb, proj_w, projwb,
                                      conv1_w, w1b, conv2_w, w2b, conv1_b, conv2_b, biasws);

    // conv1+conv2 in one launch (z selects weights/bias/output); GN stats fused via atomics
    gemm_nt<0><<<dim3(4, 64, 2), blk, 0, stream>>>(peb, w1b, c1b, part, nullptr, biasws,
                                                   512, 0, 262144, 4194304);
    gn_apply<<<1024, blk, 0, stream>>>(c1b, c2b, part, gn1_g, gn1_b, gn2_g, gn2_b);
    // qkv = x @ qkv_w.T, scattered to q (x0.125*log2e), k [B,H,N,D] and vT [B,H,D,N]
    gemm_nt<1><<<dim3(12, 64, 1), blk, 0, stream>>>(xb, qkvwb, qbuf, kbuf, vtb, nullptr, 512, 0, 0, 0);
    // pe_attn[b][n][m] = sigmoid(sum_k p1[n][k] p2[m][k])  ([q][k] orientation)
    gemm_nt<2><<<dim3(16, 16, 4), blk, 0, stream>>>(c1b, c2b, peatt, nullptr, nullptr, nullptr, 512,
                                                    1048576, 1048576, 4194304);
    attn_fused<<<dim3(1024, 1, 1), blk, 0, stream>>>(qbuf, kbuf, vtb, peatt, hbuf);
    // proj: out = h @ proj_w.T + proj_b (f32)
    gemm_nt<3><<<dim3(4, 64, 1), blk, 0, stream>>>(hbuf, projwb, out, nullptr, nullptr, proj_b, 512, 0, 0, 0);
}

// Round 11
// 226.262 us; speedup vs baseline: 1.4507x; 1.0104x over previous
//
#include <hip/hip_runtime.h>
#include <hip/hip_bf16.h>

// Shapes (fixed): B=4, N=2048, C=512, H=8, D=64, GROUPS=8, C/G=64
typedef __attribute__((ext_vector_type(8))) short bf16x8;
typedef __attribute__((ext_vector_type(4))) float f32x4;

__device__ __forceinline__ float bfu2f(unsigned int u) {
    return __uint_as_float(u << 16);
}
__device__ __forceinline__ unsigned short f2bfu(float f) {
    unsigned int u = __float_as_uint(f);
    u += 0x7fffu + ((u >> 16) & 1u);   // RNE
    return (unsigned short)(u >> 16);
}

// ---------------- all fp32->bf16 conversions + bias gather, one launch ----------------
__global__ __launch_bounds__(256) void cvt_all(
    const float* __restrict__ x, unsigned short* __restrict__ xb,
    const float* __restrict__ pe, unsigned short* __restrict__ peb,
    const float* __restrict__ w0, unsigned short* __restrict__ d0,
    const float* __restrict__ w1, unsigned short* __restrict__ d1,
    const float* __restrict__ w2, unsigned short* __restrict__ d2,
    const float* __restrict__ w3, unsigned short* __restrict__ d3,
    const float* __restrict__ c1bias, const float* __restrict__ c2bias,
    float* __restrict__ biasws) {
    const int tid = threadIdx.x;
    if (blockIdx.x == 0) {
        if (tid < 128) ((float4*)biasws)[tid] = ((const float4*)c1bias)[tid];
        else ((float4*)biasws)[tid] = ((const float4*)c2bias)[tid - 128];
    }
    int i = blockIdx.x * 256 + tid;
    const int stride = gridDim.x * 256;
    for (; i < 1441792; i += stride) {
        if (i < 1048576) {
            float4 v = reinterpret_cast<const float4*>(x)[i];
            ushort4 o;
            o.x = f2bfu(v.x); o.y = f2bfu(v.y); o.z = f2bfu(v.z); o.w = f2bfu(v.w);
            reinterpret_cast<ushort4*>(xb)[i] = o;
            float4 u = reinterpret_cast<const float4*>(pe)[i];
            ushort4 p;
            p.x = f2bfu(u.x); p.y = f2bfu(u.y); p.z = f2bfu(u.z); p.w = f2bfu(u.w);
            reinterpret_cast<ushort4*>(peb)[i] = p;
        } else {
            int j = i - 1048576;
            const float* s; unsigned short* d;
            if (j < 196608)      { s = w0; d = d0; }
            else if (j < 262144) { s = w1; d = d1; j -= 196608; }
            else if (j < 327680) { s = w2; d = d2; j -= 262144; }
            else                 { s = w3; d = d3; j -= 327680; }
            float4 v = reinterpret_cast<const float4*>(s)[j];
            ushort4 o;
            o.x = f2bfu(v.x); o.y = f2bfu(v.y); o.z = f2bfu(v.z); o.w = f2bfu(v.w);
            reinterpret_cast<ushort4*>(d)[j] = o;
        }
    }
}

// ---------------- generic NT GEMM, flat grid + bijective XCD swizzle ----------------
// C[m][n] = sum_k A[m][k] * B[n][k].  128x128 tile, BK=32, 4 waves (2x2 of 64x64).
// Staging: global_load_lds width 16, double-buffered linear LDS [2][128][32],
// source pre-swizzle slot^=(row&3), read col (lh^(lr&3))*8 (same involution both sides).
// EPI: 0 = conv pair (bf16 out ld512, +bias from biasws, GN stats atomics via C1) [R9-verified],
//      1 = qkv scatter (q*0.125*log2e, k, vT), 2 = sigmoid bf16 (ld2048, batched),
//      3 = proj (f32 out ld512, +bias)
template <int EPI>
__global__ __launch_bounds__(256) void gemm_nt(
    const unsigned short* __restrict__ A, const unsigned short* __restrict__ B,
    void* __restrict__ C0, void* __restrict__ C1, void* __restrict__ C2,
    const float* __restrict__ bias, int K, long sA, long sB, long sC,
    int nx, int ny) {
    __shared__ unsigned short As[2][128 * 32];
    __shared__ unsigned short Bs[2][128 * 32];
    int lin = blockIdx.x;
    const int qsw = gridDim.x >> 3;
    lin = (lin & 7) * qsw + (lin >> 3);          // bijective XCD swizzle (grid % 8 == 0)
    const int bx = lin % nx;
    const int t2 = lin / nx;
    const int by = t2 % ny;
    const int bz = t2 / ny;
    const int tid = threadIdx.x;
    const int l = tid & 63, w = tid >> 6;
    const int wr = w >> 1, wc = w & 1, lr = l & 15, lh = l >> 4;
    const int m0 = by * 128, n0 = bx * 128;
    A += (size_t)bz * sA;
    B += (size_t)bz * sB;
    f32x4 acc[4][4] = {};

    const int srow = l >> 2, sslot = l & 3;
    auto stage = [&](int bufi, int k0) {
#pragma unroll
        for (int i = 0; i < 2; i++) {
            const int row = w * 32 + i * 16 + srow;
            const int cs = (sslot ^ (row & 3)) * 8;
            const int ldsoff = (w * 32 + i * 16) * 32;
            __builtin_amdgcn_global_load_lds(
                (const __attribute__((address_space(1))) void*)(A + (size_t)(m0 + row) * K + k0 + cs),
                (__attribute__((address_space(3))) void*)&As[bufi][ldsoff], 16, 0, 0);
            __builtin_amdgcn_global_load_lds(
                (const __attribute__((address_space(1))) void*)(B + (size_t)(n0 + row) * K + k0 + cs),
                (__attribute__((address_space(3))) void*)&Bs[bufi][ldsoff], 16, 0, 0);
        }
    };

    const int nks = K >> 5;
    stage(0, 0);
    asm volatile("s_waitcnt vmcnt(0)" ::: "memory");
    __builtin_amdgcn_s_barrier();
    __builtin_amdgcn_sched_barrier(0);

    const int colA = (lh ^ (lr & 3)) << 3;
    for (int ks = 0; ks < nks; ks++) {
        const int cur = ks & 1;
        if (ks + 1 < nks) stage(cur ^ 1, (ks + 1) << 5);
        bf16x8 af[4], bfr[4];
#pragma unroll
        for (int i = 0; i < 4; i++)
            af[i] = *reinterpret_cast<const bf16x8*>(&As[cur][(wr * 64 + i * 16 + lr) * 32 + colA]);
#pragma unroll
        for (int i = 0; i < 4; i++)
            bfr[i] = *reinterpret_cast<const bf16x8*>(&Bs[cur][(wc * 64 + i * 16 + lr) * 32 + colA]);
        __builtin_amdgcn_s_setprio(1);
#pragma unroll
        for (int mi = 0; mi < 4; mi++)
#pragma unroll
            for (int ni = 0; ni < 4; ni++)
                acc[mi][ni] = __builtin_amdgcn_mfma_f32_16x16x32_bf16(af[mi], bfr[ni], acc[mi][ni], 0, 0, 0);
        __builtin_amdgcn_s_setprio(0);
        if (ks + 1 < nks) {
            asm volatile("s_waitcnt vmcnt(0) lgkmcnt(0)" ::: "memory");
            __builtin_amdgcn_s_barrier();
            __builtin_amdgcn_sched_barrier(0);
        }
    }

    float sgn = 0.f, qgn = 0.f;   // fused GN partial stats (EPI==0)
#pragma unroll
    for (int mi = 0; mi < 4; mi++) {
#pragma unroll
        for (int ni = 0; ni < 4; ni++) {
#pragma unroll
            for (int r = 0; r < 4; r++) {
                const int row = m0 + wr * 64 + mi * 16 + lh * 4 + r;
                const int col = n0 + wc * 64 + ni * 16 + lr;
                float v = acc[mi][ni][r];
                if constexpr (EPI == 0) {
                    v += bias[bz * 512 + col];
                    sgn += v; qgn += v * v;
                    ((unsigned short*)C0)[(size_t)bz * sC + (size_t)row * 512 + col] = f2bfu(v);
                } else if constexpr (EPI == 1) {
                    // col in [0,1536): j = part*512 + h*64 + d ; row = b*2048 + n
                    const int part = col >> 9, hh = (col >> 6) & 7, d = col & 63;
                    const int b = row >> 11, n = row & 2047;
                    const size_t bh = (size_t)(b * 8 + hh);
                    if (part == 0)
                        ((unsigned short*)C0)[(bh * 2048 + n) * 64 + d] = f2bfu(v * 0.1803368801111244f);
                    else if (part == 1)
                        ((unsigned short*)C1)[(bh * 2048 + n) * 64 + d] = f2bfu(v);
                    else
                        ((unsigned short*)C2)[(bh * 64 + d) * 2048 + n] = f2bfu(v);
                } else if constexpr (EPI == 2) {
                    const float sg = 1.0f / (1.0f + __expf(-v));
                    ((unsigned short*)C0)[(size_t)bz * sC + (size_t)row * 2048 + col] = f2bfu(sg);
                } else {
                    ((float*)C0)[(size_t)row * 512 + col] = v + bias[col];
                }
            }
        }
    }
    if constexpr (EPI == 0) {
        // wave holds one (b,g): b = by>>4, g = bx*2+wc
#pragma unroll
        for (int s = 1; s < 64; s <<= 1) {
            sgn += __shfl_xor(sgn, s);
            qgn += __shfl_xor(qgn, s);
        }
        if (l == 0) {
            const int bg = ((by >> 4) << 3) + bx * 2 + wc;
            float* part = (float*)C1;
            atomicAdd(&part[(bz * 32 + bg) * 2 + 0], sgn);
            atomicAdd(&part[(bz * 32 + bg) * 2 + 1], qgn);
        }
    }
}

// ---------------- GroupNorm apply (in place), stats finish folded in [R9-verified] ------
__global__ __launch_bounds__(256) void gn_apply(unsigned short* __restrict__ c1,
                                                unsigned short* __restrict__ c2,
                                                const float* __restrict__ part,
                                                const float* __restrict__ g1, const float* __restrict__ b1,
                                                const float* __restrict__ g2, const float* __restrict__ b2) {
    __shared__ float sst[2][32][2];
    const int tid = threadIdx.x;
    if (tid < 64) {
        const int z = tid >> 5, bg = tid & 31;
        const float S = part[(z * 32 + bg) * 2 + 0];
        const float Q = part[(z * 32 + bg) * 2 + 1];
        const float inv = 1.0f / 131072.0f;
        const float m = S * inv;
        const float v = fmaxf(Q * inv - m * m, 0.f);
        sst[z][bg][0] = m;
        sst[z][bg][1] = rsqrtf(v + 1e-5f);
    }
    __syncthreads();
    int i = blockIdx.x * 256 + tid;
    const int stride = gridDim.x * 256;
    for (; i < 524288; i += stride) {           // 4*2048*512/8 chunks
        const size_t e = (size_t)i * 8;
        const int b = (int)(e >> 20);           // N*C = 2^20
        const int o = (int)(e & 511);
        const int g = o >> 6;
        const int bg = (b << 3) + g;
        const float m1 = sst[0][bg][0], r1 = sst[0][bg][1];
        const float m2 = sst[1][bg][0], r2 = sst[1][bg][1];
        uint4 v1 = *reinterpret_cast<const uint4*>(c1 + e);
        uint4 v2 = *reinterpret_cast<const uint4*>(c2 + e);
        unsigned int a1[4] = {v1.x, v1.y, v1.z, v1.w};
        unsigned int a2[4] = {v2.x, v2.y, v2.z, v2.w};
        unsigned int o1[4], o2[4];
#pragma unroll
        for (int j = 0; j < 4; j++) {
            const int oo = o + j * 2;
            float x0 = (bfu2f(a1[j] & 0xffffu) - m1) * r1 * g1[oo] + b1[oo];
            float x1 = (bfu2f(a1[j] >> 16) - m1) * r1 * g1[oo + 1] + b1[oo + 1];
            o1[j] = (unsigned int)f2bfu(x0) | ((unsigned int)f2bfu(x1) << 16);
            float y0 = (bfu2f(a2[j] & 0xffffu) - m2) * r2 * g2[oo] + b2[oo];
            float y1 = (bfu2f(a2[j] >> 16) - m2) * r2 * g2[oo + 1] + b2[oo + 1];
            o2[j] = (unsigned int)f2bfu(y0) | ((unsigned int)f2bfu(y1) << 16);
        }
        uint4 w1; w1.x = o1[0]; w1.y = o1[1]; w1.z = o1[2]; w1.w = o1[3];
        uint4 w2; w2.x = o2[0]; w2.y = o2[1]; w2.z = o2[2]; w2.w = o2[3];
        *reinterpret_cast<uint4*>(c1 + e) = w1;
        *reinterpret_cast<uint4*>(c2 + e) = w2;
    }
}

// ---------------- fused flash attention (R7-verified version, verbatim) ----------------
// flat grid 1024: h = bid>>7.  block 256 = 4 waves, wave w owns q-rows [16w,16w+16).
// S^T = mfma(K,Q): lane: q=lr, k=16mf+4lh+r.  K/V^T double-buffered via global_load_lds.
// pe in registers.  Pl dedicated per-wave buffer.  One barrier per iteration.
__global__ __launch_bounds__(256, 4) void attn_fused(
    const unsigned short* __restrict__ qb, const unsigned short* __restrict__ kb,
    const unsigned short* __restrict__ vT, const unsigned short* __restrict__ pea,
    unsigned short* __restrict__ hbuf) {
    __shared__ unsigned short Ks[2][64 * 64];
    __shared__ unsigned short Vs[2][64 * 64];
    __shared__ unsigned short Pl[4][16 * 64];
    const int tid = threadIdx.x, l = tid & 63, w = tid >> 6;
    const int lr = l & 15, lh = l >> 4;
    const int bid = blockIdx.x;
    const int h = bid >> 7, rst = bid & 127, nt = rst & 31, b = rst >> 5;
    const size_t bh = (size_t)(b * 8 + h);
    const unsigned short* qp = qb + bh * 2048 * 64;
    const unsigned short* kp = kb + bh * 2048 * 64;
    const unsigned short* vp = vT + bh * 64 * 2048;
    const unsigned short* pep = pea + (size_t)b * 2048 * 2048;   // [q][k] orientation
    const int n0 = nt * 64;

    bf16x8 qf[2];
    qf[0] = *reinterpret_cast<const bf16x8*>(qp + (size_t)(n0 + 16 * w + lr) * 64 + lh * 8);
    qf[1] = *reinterpret_cast<const bf16x8*>(qp + (size_t)(n0 + 16 * w + lr) * 64 + 32 + lh * 8);

    const int swz = (lr & 7) << 4;                       // byte XOR
    const int colK0 = ((16 * lh) ^ swz) >> 1;
    const int colK1 = ((64 + 16 * lh) ^ swz) >> 1;

    const unsigned short* perp = pep + (size_t)(n0 + 16 * w + lr) * 2048;
    uint2 peR[4];
#pragma unroll
    for (int mf = 0; mf < 4; mf++)
        peR[mf] = *reinterpret_cast<const uint2*>(perp + 16 * mf + 4 * lh);

    f32x4 oacc[4] = {};
    float mrun = -1e30f, lrun = 0.f;

    const int srow = l >> 3, sslot = l & 7;
    auto stage_kv = [&](int bufi, int m0) {
#pragma unroll
        for (int i = 0; i < 2; i++) {
            const int row = w * 16 + i * 8 + srow;
            const int cs = (sslot ^ (row & 7)) * 8;
            const int ldsoff = (w * 16 + i * 8) * 64;
            __builtin_amdgcn_global_load_lds(
                (const __attribute__((address_space(1))) void*)(kp + (size_t)(m0 + row) * 64 + cs),
                (__attribute__((address_space(3))) void*)&Ks[bufi][ldsoff], 16, 0, 0);
            __builtin_amdgcn_global_load_lds(
                (const __attribute__((address_space(1))) void*)(vp + (size_t)row * 2048 + m0 + cs),
                (__attribute__((address_space(3))) void*)&Vs[bufi][ldsoff], 16, 0, 0);
        }
    };

    stage_kv(0, 0);
    asm volatile("s_waitcnt vmcnt(0)" ::: "memory");
    __builtin_amdgcn_s_barrier();
    __builtin_amdgcn_sched_barrier(0);

    for (int mt = 0; mt < 32; mt++) {
        const int cur = mt & 1;
        if (mt + 1 < 32) stage_kv(cur ^ 1, (mt + 1) * 64);
        const unsigned short* Kb = Ks[cur];
        const unsigned short* Vb = Vs[cur];

        f32x4 st[4] = {};
        __builtin_amdgcn_s_setprio(1);
#pragma unroll
        for (int mf = 0; mf < 4; mf++) {
            bf16x8 kf0 = *reinterpret_cast<const bf16x8*>(&Kb[(mf * 16 + lr) * 64 + colK0]);
            bf16x8 kf1 = *reinterpret_cast<const bf16x8*>(&Kb[(mf * 16 + lr) * 64 + colK1]);
            st[mf] = __builtin_amdgcn_mfma_f32_16x16x32_bf16(kf0, qf[0], st[mf], 0, 0, 0);
            st[mf] = __builtin_amdgcn_mfma_f32_16x16x32_bf16(kf1, qf[1], st[mf], 0, 0, 0);
        }
        __builtin_amdgcn_s_setprio(0);

        float p[4][4];
#pragma unroll
        for (int mf = 0; mf < 4; mf++) {
            p[mf][0] = st[mf][0] * bfu2f(peR[mf].x & 0xffffu);
            p[mf][1] = st[mf][1] * bfu2f(peR[mf].x >> 16);
            p[mf][2] = st[mf][2] * bfu2f(peR[mf].y & 0xffffu);
            p[mf][3] = st[mf][3] * bfu2f(peR[mf].y >> 16);
        }
        uint2 peN[4];
        if (mt + 1 < 32) {
            const unsigned short* pn = perp + (mt + 1) * 64;
#pragma unroll
            for (int mf = 0; mf < 4; mf++)
                peN[mf] = *reinterpret_cast<const uint2*>(pn + 16 * mf + 4 * lh);
        }
        float pm = fmaxf(p[0][0], p[0][1]);
        pm = fmaxf(fmaxf(pm, p[0][2]), p[0][3]);
#pragma unroll
        for (int mf = 1; mf < 4; mf++) {
            pm = fmaxf(fmaxf(pm, p[mf][0]), p[mf][1]);
            pm = fmaxf(fmaxf(pm, p[mf][2]), p[mf][3]);
        }
        pm = fmaxf(pm, __shfl_xor(pm, 16));
        pm = fmaxf(pm, __shfl_xor(pm, 32));
        if (__any(pm > mrun + 11.5416f)) {
            const float mnew = fmaxf(mrun, pm);
            const float fac = __builtin_amdgcn_exp2f(mrun - mnew);
            lrun *= fac;
#pragma unroll
            for (int df = 0; df < 4; df++)
#pragma unroll
                for (int r = 0; r < 4; r++) oacc[df][r] *= fac;
            mrun = mnew;
        }
        float ss = 0.f;
        unsigned int pk[8];
#pragma unroll
        for (int mf = 0; mf < 4; mf++) {
#pragma unroll
            for (int t = 0; t < 2; t++) {
                const float a = __builtin_amdgcn_exp2f(p[mf][2 * t] - mrun);
                const float c = __builtin_amdgcn_exp2f(p[mf][2 * t + 1] - mrun);
                unsigned int pkv;
                asm("v_cvt_pk_bf16_f32 %0, %1, %2" : "=v"(pkv) : "v"(a), "v"(c));
                pk[mf * 2 + t] = pkv;
                ss += a + c;
            }
        }
        ss += __shfl_xor(ss, 16);
        ss += __shfl_xor(ss, 32);
        lrun += ss;
        unsigned short* PlW = Pl[w];
        const int plswz = (lr & 7) << 4;               // byte XOR within 128B row
#pragma unroll
        for (int mf = 0; mf < 4; mf++)
#pragma unroll
            for (int t = 0; t < 2; t++) {
                const int cb = (mf * 32 + lh * 8 + 4 * t) ^ plswz;
                *reinterpret_cast<unsigned int*>(&PlW[lr * 64 + (cb >> 1)]) = pk[mf * 2 + t];
            }
        bf16x8 pb0 = *reinterpret_cast<const bf16x8*>(&PlW[lr * 64 + (((lh * 16) ^ plswz) >> 1)]);
        bf16x8 pb1 = *reinterpret_cast<const bf16x8*>(&PlW[lr * 64 + (((64 + lh * 16) ^ plswz) >> 1)]);
        __builtin_amdgcn_s_setprio(1);
#pragma unroll
        for (int df = 0; df < 4; df++) {
            bf16x8 vf0 = *reinterpret_cast<const bf16x8*>(&Vb[(df * 16 + lr) * 64 + colK0]);
            bf16x8 vf1 = *reinterpret_cast<const bf16x8*>(&Vb[(df * 16 + lr) * 64 + colK1]);
            oacc[df] = __builtin_amdgcn_mfma_f32_16x16x32_bf16(vf0, pb0, oacc[df], 0, 0, 0);
            oacc[df] = __builtin_amdgcn_mfma_f32_16x16x32_bf16(vf1, pb1, oacc[df], 0, 0, 0);
        }
        __builtin_amdgcn_s_setprio(0);
        if (mt + 1 < 32) {
            asm volatile("s_waitcnt vmcnt(0) lgkmcnt(0)" ::: "memory");
            __builtin_amdgcn_s_barrier();
            __builtin_amdgcn_sched_barrier(0);
#pragma unroll
            for (int mf = 0; mf < 4; mf++) peR[mf] = peN[mf];
        }
    }
    const float inv = 1.0f / lrun;
    const size_t base = ((size_t)b * 2048 + n0 + 16 * w + lr) * 512 + h * 64;
#pragma unroll
    for (int df = 0; df < 4; df++) {
#pragma unroll
        for (int t = 0; t < 2; t++) {
            const unsigned int ua = f2bfu(oacc[df][2 * t] * inv);
            const unsigned int uc = f2bfu(oacc[df][2 * t + 1] * inv);
            *reinterpret_cast<unsigned int*>(&hbuf[base + 16 * df + 4 * lh + 2 * t]) = ua | (uc << 16);
        }
    }
}

extern "C" void kernel_launch(void* const* d_in, const int* in_sizes, int n_in,
                              void* d_out, int out_size, void* d_ws, size_t ws_size,
                              hipStream_t stream) {
    const float* x       = (const float*)d_in[0];
    const float* pe      = (const float*)d_in[1];
    const float* qkv_w   = (const float*)d_in[2];
    const float* proj_w  = (const float*)d_in[3];
    const float* proj_b  = (const float*)d_in[4];
    const float* conv1_w = (const float*)d_in[5];
    const float* conv1_b = (const float*)d_in[6];
    const float* gn1_g   = (const float*)d_in[7];
    const float* gn1_b   = (const float*)d_in[8];
    const float* conv2_w = (const float*)d_in[9];
    const float* conv2_b = (const float*)d_in[10];
    const float* gn2_g   = (const float*)d_in[11];
    const float* gn2_b   = (const float*)d_in[12];
    float* out = (float*)d_out;

    char* ws = (char*)d_ws;
    size_t off = 0;
    auto alloc = [&](size_t bytes) -> void* {
        void* p = ws + off;
        off += (bytes + 255) & ~(size_t)255;
        return p;
    };
    unsigned short* xb     = (unsigned short*)alloc(8388608);   // x bf16 [B*N, C]
    unsigned short* peb    = (unsigned short*)alloc(8388608);   // pe bf16
    unsigned short* qkvwb  = (unsigned short*)alloc(1572864);   // qkv_w bf16 [1536,512]
    unsigned short* projwb = (unsigned short*)alloc(524288);
    unsigned short* w1b    = (unsigned short*)alloc(524288);    // w1b/w2b contiguous (sB=262144)
    unsigned short* w2b    = (unsigned short*)alloc(524288);
    unsigned short* c1b    = (unsigned short*)alloc(8388608);   // c1b/c2b contiguous (sC=4194304)
    unsigned short* c2b    = (unsigned short*)alloc(8388608);
    unsigned short* qbuf   = (unsigned short*)alloc(8388608);   // [B,H,N,D] (q pre-scaled)
    unsigned short* kbuf   = (unsigned short*)alloc(8388608);
    unsigned short* vtb    = (unsigned short*)alloc(8388608);   // [B,H,D,N]
    unsigned short* peatt  = (unsigned short*)alloc(33554432);  // pe_attn [B,N(q),N(k)] bf16
    unsigned short* hbuf   = (unsigned short*)alloc(8388608);   // [B,N,C] bf16
    float* part            = (float*)alloc(512);                // GN stats [2][32][2]
    float* biasws          = (float*)alloc(4096);               // conv biases [2][512]

    dim3 blk(256);
    hipMemsetAsync(part, 0, 512, stream);
    cvt_all<<<2048, blk, 0, stream>>>(x, xb, pe, peb, qkv_w, qkvwb, proj_w, projwb,
                                      conv1_w, w1b, conv2_w, w2b, conv1_b, conv2_b, biasws);

    // conv1+conv2 in one launch (bz selects weights/bias/output); GN stats via atomics
    gemm_nt<0><<<dim3(512), blk, 0, stream>>>(peb, w1b, c1b, part, nullptr, biasws,
                                              512, 0, 262144, 4194304, 4, 64);
    gn_apply<<<1024, blk, 0, stream>>>(c1b, c2b, part, gn1_g, gn1_b, gn2_g, gn2_b);
    // qkv = x @ qkv_w.T, scattered to q (x0.125*log2e), k [B,H,N,D] and vT [B,H,D,N]
    gemm_nt<1><<<dim3(768), blk, 0, stream>>>(xb, qkvwb, qbuf, kbuf, vtb, nullptr,
                                              512, 0, 0, 0, 12, 64);
    // pe_attn[b][n][m] = sigmoid(sum_k p1[n][k] p2[m][k])  ([q][k] orientation)
    gemm_nt<2><<<dim3(1024), blk, 0, stream>>>(c1b, c2b, peatt, nullptr, nullptr, nullptr,
                                               512, 1048576, 1048576, 4194304, 16, 16);
    attn_fused<<<dim3(1024), blk, 0, stream>>>(qbuf, kbuf, vtb, peatt, hbuf);
    // proj: out = h @ proj_w.T + proj_b (f32)
    gemm_nt<3><<<dim3(256), blk, 0, stream>>>(hbuf, projwb, out, nullptr, nullptr, proj_b,
                                              512, 0, 0, 0, 4, 64);
}

// Round 12
// 226.167 us; speedup vs baseline: 1.4513x; 1.0004x over previous
//
#include <hip/hip_runtime.h>
#include <hip/hip_bf16.h>

// Shapes (fixed): B=4, N=2048, C=512, H=8, D=64, GROUPS=8, C/G=64
typedef __attribute__((ext_vector_type(8))) short bf16x8;
typedef __attribute__((ext_vector_type(4))) float f32x4;

__device__ __forceinline__ float bfu2f(unsigned int u) {
    return __uint_as_float(u << 16);
}
__device__ __forceinline__ unsigned short f2bfu(float f) {
    unsigned int u = __float_as_uint(f);
    u += 0x7fffu + ((u >> 16) & 1u);   // RNE
    return (unsigned short)(u >> 16);
}

// ---------------- all fp32->bf16 conversions + bias gather, one launch ----------------
__global__ __launch_bounds__(256) void cvt_all(
    const float* __restrict__ x, unsigned short* __restrict__ xb,
    const float* __restrict__ pe, unsigned short* __restrict__ peb,
    const float* __restrict__ w0, unsigned short* __restrict__ d0,
    const float* __restrict__ w1, unsigned short* __restrict__ d1,
    const float* __restrict__ w2, unsigned short* __restrict__ d2,
    const float* __restrict__ w3, unsigned short* __restrict__ d3,
    const float* __restrict__ c1bias, const float* __restrict__ c2bias,
    float* __restrict__ biasws) {
    const int tid = threadIdx.x;
    if (blockIdx.x == 0) {
        if (tid < 128) ((float4*)biasws)[tid] = ((const float4*)c1bias)[tid];
        else ((float4*)biasws)[tid] = ((const float4*)c2bias)[tid - 128];
    }
    int i = blockIdx.x * 256 + tid;
    const int stride = gridDim.x * 256;
    for (; i < 1441792; i += stride) {
        if (i < 1048576) {
            float4 v = reinterpret_cast<const float4*>(x)[i];
            ushort4 o;
            o.x = f2bfu(v.x); o.y = f2bfu(v.y); o.z = f2bfu(v.z); o.w = f2bfu(v.w);
            reinterpret_cast<ushort4*>(xb)[i] = o;
            float4 u = reinterpret_cast<const float4*>(pe)[i];
            ushort4 p;
            p.x = f2bfu(u.x); p.y = f2bfu(u.y); p.z = f2bfu(u.z); p.w = f2bfu(u.w);
            reinterpret_cast<ushort4*>(peb)[i] = p;
        } else {
            int j = i - 1048576;
            const float* s; unsigned short* d;
            if (j < 196608)      { s = w0; d = d0; }
            else if (j < 262144) { s = w1; d = d1; j -= 196608; }
            else if (j < 327680) { s = w2; d = d2; j -= 262144; }
            else                 { s = w3; d = d3; j -= 327680; }
            float4 v = reinterpret_cast<const float4*>(s)[j];
            ushort4 o;
            o.x = f2bfu(v.x); o.y = f2bfu(v.y); o.z = f2bfu(v.z); o.w = f2bfu(v.w);
            reinterpret_cast<ushort4*>(d)[j] = o;
        }
    }
}

// ---------------- merged conv-pair + qkv GEMM (one launch, 1280 blocks) ----------------
// blocks [0,512): conv z-pair (EPI0: bias + GN stats atomics); blocks [512,1280): qkv (EPI1).
// Same 128x128/BK=32 core, global_load_lds staging, bijective XCD swizzle per range.
__global__ __launch_bounds__(256) void gemm_cq(
    const unsigned short* __restrict__ peb, const unsigned short* __restrict__ wcb,
    unsigned short* __restrict__ c1b, float* __restrict__ part, const float* __restrict__ biasws,
    const unsigned short* __restrict__ xb, const unsigned short* __restrict__ qkvwb,
    unsigned short* __restrict__ qbuf, unsigned short* __restrict__ kbuf,
    unsigned short* __restrict__ vtb) {
    __shared__ unsigned short As[2][128 * 32];
    __shared__ unsigned short Bs[2][128 * 32];
    const int bid = blockIdx.x;
    const bool isconv = bid < 512;
    int bx, by, bz;
    const unsigned short* A;
    const unsigned short* B;
    if (isconv) {
        int lin = ((bid & 7) << 6) + (bid >> 3);          // 512 = 8*64
        bx = lin & 3; by = (lin >> 2) & 63; bz = lin >> 8;
        A = peb; B = wcb + (size_t)bz * 262144;
    } else {
        int l2 = bid - 512;
        int lin = (l2 & 7) * 96 + (l2 >> 3);              // 768 = 8*96
        bx = lin % 12; by = lin / 12; bz = 0;
        A = xb; B = qkvwb;
    }
    const int tid = threadIdx.x;
    const int l = tid & 63, w = tid >> 6;
    const int wr = w >> 1, wc = w & 1, lr = l & 15, lh = l >> 4;
    const int m0 = by * 128, n0 = bx * 128;
    f32x4 acc[4][4] = {};

    const int srow = l >> 2, sslot = l & 3;
    auto stage = [&](int bufi, int k0) {
#pragma unroll
        for (int i = 0; i < 2; i++) {
            const int row = w * 32 + i * 16 + srow;
            const int cs = (sslot ^ (row & 3)) * 8;
            const int ldsoff = (w * 32 + i * 16) * 32;
            __builtin_amdgcn_global_load_lds(
                (const __attribute__((address_space(1))) void*)(A + (size_t)(m0 + row) * 512 + k0 + cs),
                (__attribute__((address_space(3))) void*)&As[bufi][ldsoff], 16, 0, 0);
            __builtin_amdgcn_global_load_lds(
                (const __attribute__((address_space(1))) void*)(B + (size_t)(n0 + row) * 512 + k0 + cs),
                (__attribute__((address_space(3))) void*)&Bs[bufi][ldsoff], 16, 0, 0);
        }
    };

    stage(0, 0);
    asm volatile("s_waitcnt vmcnt(0)" ::: "memory");
    __builtin_amdgcn_s_barrier();
    __builtin_amdgcn_sched_barrier(0);

    const int colA = (lh ^ (lr & 3)) << 3;
    for (int ks = 0; ks < 16; ks++) {
        const int cur = ks & 1;
        if (ks + 1 < 16) stage(cur ^ 1, (ks + 1) << 5);
        bf16x8 af[4], bfr[4];
#pragma unroll
        for (int i = 0; i < 4; i++)
            af[i] = *reinterpret_cast<const bf16x8*>(&As[cur][(wr * 64 + i * 16 + lr) * 32 + colA]);
#pragma unroll
        for (int i = 0; i < 4; i++)
            bfr[i] = *reinterpret_cast<const bf16x8*>(&Bs[cur][(wc * 64 + i * 16 + lr) * 32 + colA]);
        __builtin_amdgcn_s_setprio(1);
#pragma unroll
        for (int mi = 0; mi < 4; mi++)
#pragma unroll
            for (int ni = 0; ni < 4; ni++)
                acc[mi][ni] = __builtin_amdgcn_mfma_f32_16x16x32_bf16(af[mi], bfr[ni], acc[mi][ni], 0, 0, 0);
        __builtin_amdgcn_s_setprio(0);
        if (ks + 1 < 16) {
            asm volatile("s_waitcnt vmcnt(0) lgkmcnt(0)" ::: "memory");
            __builtin_amdgcn_s_barrier();
            __builtin_amdgcn_sched_barrier(0);
        }
    }

    if (isconv) {
        float sgn = 0.f, qgn = 0.f;
#pragma unroll
        for (int mi = 0; mi < 4; mi++)
#pragma unroll
            for (int ni = 0; ni < 4; ni++)
#pragma unroll
                for (int r = 0; r < 4; r++) {
                    const int row = m0 + wr * 64 + mi * 16 + lh * 4 + r;
                    const int col = n0 + wc * 64 + ni * 16 + lr;
                    float v = acc[mi][ni][r] + biasws[bz * 512 + col];
                    sgn += v; qgn += v * v;
                    c1b[(size_t)bz * 4194304 + (size_t)row * 512 + col] = f2bfu(v);
                }
#pragma unroll
        for (int s = 1; s < 64; s <<= 1) {
            sgn += __shfl_xor(sgn, s);
            qgn += __shfl_xor(qgn, s);
        }
        if (l == 0) {
            const int bg = ((by >> 4) << 3) + bx * 2 + wc;
            atomicAdd(&part[(bz * 32 + bg) * 2 + 0], sgn);
            atomicAdd(&part[(bz * 32 + bg) * 2 + 1], qgn);
        }
    } else {
#pragma unroll
        for (int mi = 0; mi < 4; mi++)
#pragma unroll
            for (int ni = 0; ni < 4; ni++)
#pragma unroll
                for (int r = 0; r < 4; r++) {
                    const int row = m0 + wr * 64 + mi * 16 + lh * 4 + r;
                    const int col = n0 + wc * 64 + ni * 16 + lr;
                    const float v = acc[mi][ni][r];
                    const int part_ = col >> 9, hh = (col >> 6) & 7, d = col & 63;
                    const int b = row >> 11, n = row & 2047;
                    const size_t bh = (size_t)(b * 8 + hh);
                    if (part_ == 0)
                        qbuf[(bh * 2048 + n) * 64 + d] = f2bfu(v * 0.1803368801111244f);
                    else if (part_ == 1)
                        kbuf[(bh * 2048 + n) * 64 + d] = f2bfu(v);
                    else
                        vtb[(bh * 64 + d) * 2048 + n] = f2bfu(v);
                }
    }
}

// ---------------- generic NT GEMM (EPI 2 = pe sigmoid, EPI 3 = proj) ----------------
template <int EPI>
__global__ __launch_bounds__(256) void gemm_nt(
    const unsigned short* __restrict__ A, const unsigned short* __restrict__ B,
    void* __restrict__ C0, const float* __restrict__ bias,
    int K, long sA, long sB, long sC, int nx, int ny) {
    __shared__ unsigned short As[2][128 * 32];
    __shared__ unsigned short Bs[2][128 * 32];
    int lin = blockIdx.x;
    const int qsw = gridDim.x >> 3;
    lin = (lin & 7) * qsw + (lin >> 3);
    const int bx = lin % nx;
    const int t2 = lin / nx;
    const int by = t2 % ny;
    const int bz = t2 / ny;
    const int tid = threadIdx.x;
    const int l = tid & 63, w = tid >> 6;
    const int wr = w >> 1, wc = w & 1, lr = l & 15, lh = l >> 4;
    const int m0 = by * 128, n0 = bx * 128;
    A += (size_t)bz * sA;
    B += (size_t)bz * sB;
    f32x4 acc[4][4] = {};

    const int srow = l >> 2, sslot = l & 3;
    auto stage = [&](int bufi, int k0) {
#pragma unroll
        for (int i = 0; i < 2; i++) {
            const int row = w * 32 + i * 16 + srow;
            const int cs = (sslot ^ (row & 3)) * 8;
            const int ldsoff = (w * 32 + i * 16) * 32;
            __builtin_amdgcn_global_load_lds(
                (const __attribute__((address_space(1))) void*)(A + (size_t)(m0 + row) * K + k0 + cs),
                (__attribute__((address_space(3))) void*)&As[bufi][ldsoff], 16, 0, 0);
            __builtin_amdgcn_global_load_lds(
                (const __attribute__((address_space(1))) void*)(B + (size_t)(n0 + row) * K + k0 + cs),
                (__attribute__((address_space(3))) void*)&Bs[bufi][ldsoff], 16, 0, 0);
        }
    };

    const int nks = K >> 5;
    stage(0, 0);
    asm volatile("s_waitcnt vmcnt(0)" ::: "memory");
    __builtin_amdgcn_s_barrier();
    __builtin_amdgcn_sched_barrier(0);

    const int colA = (lh ^ (lr & 3)) << 3;
    for (int ks = 0; ks < nks; ks++) {
        const int cur = ks & 1;
        if (ks + 1 < nks) stage(cur ^ 1, (ks + 1) << 5);
        bf16x8 af[4], bfr[4];
#pragma unroll
        for (int i = 0; i < 4; i++)
            af[i] = *reinterpret_cast<const bf16x8*>(&As[cur][(wr * 64 + i * 16 + lr) * 32 + colA]);
#pragma unroll
        for (int i = 0; i < 4; i++)
            bfr[i] = *reinterpret_cast<const bf16x8*>(&Bs[cur][(wc * 64 + i * 16 + lr) * 32 + colA]);
        __builtin_amdgcn_s_setprio(1);
#pragma unroll
        for (int mi = 0; mi < 4; mi++)
#pragma unroll
            for (int ni = 0; ni < 4; ni++)
                acc[mi][ni] = __builtin_amdgcn_mfma_f32_16x16x32_bf16(af[mi], bfr[ni], acc[mi][ni], 0, 0, 0);
        __builtin_amdgcn_s_setprio(0);
        if (ks + 1 < nks) {
            asm volatile("s_waitcnt vmcnt(0) lgkmcnt(0)" ::: "memory");
            __builtin_amdgcn_s_barrier();
            __builtin_amdgcn_sched_barrier(0);
        }
    }

#pragma unroll
    for (int mi = 0; mi < 4; mi++) {
#pragma unroll
        for (int ni = 0; ni < 4; ni++) {
#pragma unroll
            for (int r = 0; r < 4; r++) {
                const int row = m0 + wr * 64 + mi * 16 + lh * 4 + r;
                const int col = n0 + wc * 64 + ni * 16 + lr;
                float v = acc[mi][ni][r];
                if constexpr (EPI == 2) {
                    const float sg = 1.0f / (1.0f + __expf(-v));
                    ((unsigned short*)C0)[(size_t)bz * sC + (size_t)row * 2048 + col] = f2bfu(sg);
                } else {
                    ((float*)C0)[(size_t)row * 512 + col] = v + bias[col];
                }
            }
        }
    }
}

// ---------------- GroupNorm apply (in place), stats finish folded in [R9-verified] ------
__global__ __launch_bounds__(256) void gn_apply(unsigned short* __restrict__ c1,
                                                unsigned short* __restrict__ c2,
                                                const float* __restrict__ part,
                                                const float* __restrict__ g1, const float* __restrict__ b1,
                                                const float* __restrict__ g2, const float* __restrict__ b2) {
    __shared__ float sst[2][32][2];
    const int tid = threadIdx.x;
    if (tid < 64) {
        const int z = tid >> 5, bg = tid & 31;
        const float S = part[(z * 32 + bg) * 2 + 0];
        const float Q = part[(z * 32 + bg) * 2 + 1];
        const float inv = 1.0f / 131072.0f;
        const float m = S * inv;
        const float v = fmaxf(Q * inv - m * m, 0.f);
        sst[z][bg][0] = m;
        sst[z][bg][1] = rsqrtf(v + 1e-5f);
    }
    __syncthreads();
    int i = blockIdx.x * 256 + tid;
    const int stride = gridDim.x * 256;
    for (; i < 524288; i += stride) {
        const size_t e = (size_t)i * 8;
        const int b = (int)(e >> 20);
        const int o = (int)(e & 511);
        const int g = o >> 6;
        const int bg = (b << 3) + g;
        const float m1 = sst[0][bg][0], r1 = sst[0][bg][1];
        const float m2 = sst[1][bg][0], r2 = sst[1][bg][1];
        uint4 v1 = *reinterpret_cast<const uint4*>(c1 + e);
        uint4 v2 = *reinterpret_cast<const uint4*>(c2 + e);
        unsigned int a1[4] = {v1.x, v1.y, v1.z, v1.w};
        unsigned int a2[4] = {v2.x, v2.y, v2.z, v2.w};
        unsigned int o1[4], o2[4];
#pragma unroll
        for (int j = 0; j < 4; j++) {
            const int oo = o + j * 2;
            float x0 = (bfu2f(a1[j] & 0xffffu) - m1) * r1 * g1[oo] + b1[oo];
            float x1 = (bfu2f(a1[j] >> 16) - m1) * r1 * g1[oo + 1] + b1[oo + 1];
            o1[j] = (unsigned int)f2bfu(x0) | ((unsigned int)f2bfu(x1) << 16);
            float y0 = (bfu2f(a2[j] & 0xffffu) - m2) * r2 * g2[oo] + b2[oo];
            float y1 = (bfu2f(a2[j] >> 16) - m2) * r2 * g2[oo + 1] + b2[oo + 1];
            o2[j] = (unsigned int)f2bfu(y0) | ((unsigned int)f2bfu(y1) << 16);
        }
        uint4 w1; w1.x = o1[0]; w1.y = o1[1]; w1.z = o1[2]; w1.w = o1[3];
        uint4 w2; w2.x = o2[0]; w2.y = o2[1]; w2.z = o2[2]; w2.w = o2[3];
        *reinterpret_cast<uint4*>(c1 + e) = w1;
        *reinterpret_cast<uint4*>(c2 + e) = w2;
    }
}

// ---------------- fused flash attention, 8-wave blocks (per-wave math = R7-verified) ----
// grid 512: h = bid>>6, nt = bid&15, b = (bid>>4)&3.  block 512 = 8 waves;
// wave w owns q-rows [nt*128 + 16w, +16).  K/V^T tiles (64 keys) shared by all 8 waves,
// staged via global_load_lds (1 instr pair per wave: rows [8w,8w+8)).  S^T = mfma(K,Q).
// pe in registers.  Pl per-wave.  One barrier per iteration.  LDS 48KB.
__global__ __launch_bounds__(512, 4) void attn_fused(
    const unsigned short* __restrict__ qb, const unsigned short* __restrict__ kb,
    const unsigned short* __restrict__ vT, const unsigned short* __restrict__ pea,
    unsigned short* __restrict__ hbuf) {
    __shared__ unsigned short Ks[2][64 * 64];
    __shared__ unsigned short Vs[2][64 * 64];
    __shared__ unsigned short Pl[8][16 * 64];
    const int tid = threadIdx.x, l = tid & 63, w = tid >> 6;
    const int lr = l & 15, lh = l >> 4;
    const int bid = blockIdx.x;
    const int h = bid >> 6, rst = bid & 63, nt = rst & 15, b = rst >> 4;
    const size_t bh = (size_t)(b * 8 + h);
    const unsigned short* qp = qb + bh * 2048 * 64;
    const unsigned short* kp = kb + bh * 2048 * 64;
    const unsigned short* vp = vT + bh * 64 * 2048;
    const unsigned short* pep = pea + (size_t)b * 2048 * 2048;   // [q][k] orientation
    const int qrow = nt * 128 + 16 * w + lr;                     // this lane's q-row

    bf16x8 qf[2];
    qf[0] = *reinterpret_cast<const bf16x8*>(qp + (size_t)qrow * 64 + lh * 8);
    qf[1] = *reinterpret_cast<const bf16x8*>(qp + (size_t)qrow * 64 + 32 + lh * 8);

    const int swz = (lr & 7) << 4;                       // byte XOR
    const int colK0 = ((16 * lh) ^ swz) >> 1;
    const int colK1 = ((64 + 16 * lh) ^ swz) >> 1;

    const unsigned short* perp = pep + (size_t)qrow * 2048;
    uint2 peR[4];
#pragma unroll
    for (int mf = 0; mf < 4; mf++)
        peR[mf] = *reinterpret_cast<const uint2*>(perp + 16 * mf + 4 * lh);

    f32x4 oacc[4] = {};
    float mrun = -1e30f, lrun = 0.f;

    // staging: wave w covers K/V rows [8w, 8w+8); lane l -> row 8w+(l>>3), slot l&7
    const int srow = l >> 3, sslot = l & 7;
    auto stage_kv = [&](int bufi, int m0) {
        const int row = w * 8 + srow;
        const int cs = (sslot ^ srow) * 8;               // row&7 == srow
        const int ldsoff = w * 512;                      // wave-uniform base (shorts)
        __builtin_amdgcn_global_load_lds(
            (const __attribute__((address_space(1))) void*)(kp + (size_t)(m0 + row) * 64 + cs),
            (__attribute__((address_space(3))) void*)&Ks[bufi][ldsoff], 16, 0, 0);
        __builtin_amdgcn_global_load_lds(
            (const __attribute__((address_space(1))) void*)(vp + (size_t)row * 2048 + m0 + cs),
            (__attribute__((address_space(3))) void*)&Vs[bufi][ldsoff], 16, 0, 0);
    };

    stage_kv(0, 0);
    asm volatile("s_waitcnt vmcnt(0)" ::: "memory");
    __builtin_amdgcn_s_barrier();
    __builtin_amdgcn_sched_barrier(0);

    for (int mt = 0; mt < 32; mt++) {
        const int cur = mt & 1;
        if (mt + 1 < 32) stage_kv(cur ^ 1, (mt + 1) * 64);
        const unsigned short* Kb = Ks[cur];
        const unsigned short* Vb = Vs[cur];

        f32x4 st[4] = {};
        __builtin_amdgcn_s_setprio(1);
#pragma unroll
        for (int mf = 0; mf < 4; mf++) {
            bf16x8 kf0 = *reinterpret_cast<const bf16x8*>(&Kb[(mf * 16 + lr) * 64 + colK0]);
            bf16x8 kf1 = *reinterpret_cast<const bf16x8*>(&Kb[(mf * 16 + lr) * 64 + colK1]);
            st[mf] = __builtin_amdgcn_mfma_f32_16x16x32_bf16(kf0, qf[0], st[mf], 0, 0, 0);
            st[mf] = __builtin_amdgcn_mfma_f32_16x16x32_bf16(kf1, qf[1], st[mf], 0, 0, 0);
        }
        __builtin_amdgcn_s_setprio(0);

        float p[4][4];
#pragma unroll
        for (int mf = 0; mf < 4; mf++) {
            p[mf][0] = st[mf][0] * bfu2f(peR[mf].x & 0xffffu);
            p[mf][1] = st[mf][1] * bfu2f(peR[mf].x >> 16);
            p[mf][2] = st[mf][2] * bfu2f(peR[mf].y & 0xffffu);
            p[mf][3] = st[mf][3] * bfu2f(peR[mf].y >> 16);
        }
        uint2 peN[4];
        if (mt + 1 < 32) {
            const unsigned short* pn = perp + (mt + 1) * 64;
#pragma unroll
            for (int mf = 0; mf < 4; mf++)
                peN[mf] = *reinterpret_cast<const uint2*>(pn + 16 * mf + 4 * lh);
        }
        float pm = fmaxf(p[0][0], p[0][1]);
        pm = fmaxf(fmaxf(pm, p[0][2]), p[0][3]);
#pragma unroll
        for (int mf = 1; mf < 4; mf++) {
            pm = fmaxf(fmaxf(pm, p[mf][0]), p[mf][1]);
            pm = fmaxf(fmaxf(pm, p[mf][2]), p[mf][3]);
        }
        pm = fmaxf(pm, __shfl_xor(pm, 16));
        pm = fmaxf(pm, __shfl_xor(pm, 32));
        if (__any(pm > mrun + 11.5416f)) {
            const float mnew = fmaxf(mrun, pm);
            const float fac = __builtin_amdgcn_exp2f(mrun - mnew);
            lrun *= fac;
#pragma unroll
            for (int df = 0; df < 4; df++)
#pragma unroll
                for (int r = 0; r < 4; r++) oacc[df][r] *= fac;
            mrun = mnew;
        }
        float ss = 0.f;
        unsigned int pk[8];
#pragma unroll
        for (int mf = 0; mf < 4; mf++) {
#pragma unroll
            for (int t = 0; t < 2; t++) {
                const float a = __builtin_amdgcn_exp2f(p[mf][2 * t] - mrun);
                const float c = __builtin_amdgcn_exp2f(p[mf][2 * t + 1] - mrun);
                unsigned int pkv;
                asm("v_cvt_pk_bf16_f32 %0, %1, %2" : "=v"(pkv) : "v"(a), "v"(c));
                pk[mf * 2 + t] = pkv;
                ss += a + c;
            }
        }
        ss += __shfl_xor(ss, 16);
        ss += __shfl_xor(ss, 32);
        lrun += ss;
        unsigned short* PlW = Pl[w];
        const int plswz = (lr & 7) << 4;               // byte XOR within 128B row
#pragma unroll
        for (int mf = 0; mf < 4; mf++)
#pragma unroll
            for (int t = 0; t < 2; t++) {
                const int cb = (mf * 32 + lh * 8 + 4 * t) ^ plswz;
                *reinterpret_cast<unsigned int*>(&PlW[lr * 64 + (cb >> 1)]) = pk[mf * 2 + t];
            }
        bf16x8 pb0 = *reinterpret_cast<const bf16x8*>(&PlW[lr * 64 + (((lh * 16) ^ plswz) >> 1)]);
        bf16x8 pb1 = *reinterpret_cast<const bf16x8*>(&PlW[lr * 64 + (((64 + lh * 16) ^ plswz) >> 1)]);
        __builtin_amdgcn_s_setprio(1);
#pragma unroll
        for (int df = 0; df < 4; df++) {
            bf16x8 vf0 = *reinterpret_cast<const bf16x8*>(&Vb[(df * 16 + lr) * 64 + colK0]);
            bf16x8 vf1 = *reinterpret_cast<const bf16x8*>(&Vb[(df * 16 + lr) * 64 + colK1]);
            oacc[df] = __builtin_amdgcn_mfma_f32_16x16x32_bf16(vf0, pb0, oacc[df], 0, 0, 0);
            oacc[df] = __builtin_amdgcn_mfma_f32_16x16x32_bf16(vf1, pb1, oacc[df], 0, 0, 0);
        }
        __builtin_amdgcn_s_setprio(0);
        if (mt + 1 < 32) {
            asm volatile("s_waitcnt vmcnt(0) lgkmcnt(0)" ::: "memory");
            __builtin_amdgcn_s_barrier();
            __builtin_amdgcn_sched_barrier(0);
#pragma unroll
            for (int mf = 0; mf < 4; mf++) peR[mf] = peN[mf];
        }
    }
    const float inv = 1.0f / lrun;
    const size_t base = ((size_t)b * 2048 + qrow) * 512 + h * 64;
#pragma unroll
    for (int df = 0; df < 4; df++) {
#pragma unroll
        for (int t = 0; t < 2; t++) {
            const unsigned int ua = f2bfu(oacc[df][2 * t] * inv);
            const unsigned int uc = f2bfu(oacc[df][2 * t + 1] * inv);
            *reinterpret_cast<unsigned int*>(&hbuf[base + 16 * df + 4 * lh + 2 * t]) = ua | (uc << 16);
        }
    }
}

extern "C" void kernel_launch(void* const* d_in, const int* in_sizes, int n_in,
                              void* d_out, int out_size, void* d_ws, size_t ws_size,
                              hipStream_t stream) {
    const float* x       = (const float*)d_in[0];
    const float* pe      = (const float*)d_in[1];
    const float* qkv_w   = (const float*)d_in[2];
    const float* proj_w  = (const float*)d_in[3];
    const float* proj_b  = (const float*)d_in[4];
    const float* conv1_w = (const float*)d_in[5];
    const float* conv1_b = (const float*)d_in[6];
    const float* gn1_g   = (const float*)d_in[7];
    const float* gn1_b   = (const float*)d_in[8];
    const float* conv2_w = (const float*)d_in[9];
    const float* conv2_b = (const float*)d_in[10];
    const float* gn2_g   = (const float*)d_in[11];
    const float* gn2_b   = (const float*)d_in[12];
    float* out = (float*)d_out;

    char* ws = (char*)d_ws;
    size_t off = 0;
    auto alloc = [&](size_t bytes) -> void* {
        void* p = ws + off;
        off += (bytes + 255) & ~(size_t)255;
        return p;
    };
    unsigned short* xb     = (unsigned short*)alloc(8388608);   // x bf16 [B*N, C]
    unsigned short* peb    = (unsigned short*)alloc(8388608);   // pe bf16
    unsigned short* qkvwb  = (unsigned short*)alloc(1572864);   // qkv_w bf16 [1536,512]
    unsigned short* projwb = (unsigned short*)alloc(524288);
    unsigned short* w1b    = (unsigned short*)alloc(524288);    // w1b/w2b contiguous
    unsigned short* w2b    = (unsigned short*)alloc(524288);
    unsigned short* c1b    = (unsigned short*)alloc(8388608);   // c1b/c2b contiguous
    unsigned short* c2b    = (unsigned short*)alloc(8388608);
    unsigned short* qbuf   = (unsigned short*)alloc(8388608);   // [B,H,N,D] (q pre-scaled)
    unsigned short* kbuf   = (unsigned short*)alloc(8388608);
    unsigned short* vtb    = (unsigned short*)alloc(8388608);   // [B,H,D,N]
    unsigned short* peatt  = (unsigned short*)alloc(33554432);  // pe_attn [B,N(q),N(k)] bf16
    unsigned short* hbuf   = (unsigned short*)alloc(8388608);   // [B,N,C] bf16
    float* part            = (float*)alloc(512);                // GN stats [2][32][2]
    float* biasws          = (float*)alloc(4096);               // conv biases [2][512]

    dim3 blk(256);
    hipMemsetAsync(part, 0, 512, stream);
    cvt_all<<<2048, blk, 0, stream>>>(x, xb, pe, peb, qkv_w, qkvwb, proj_w, projwb,
                                      conv1_w, w1b, conv2_w, w2b, conv1_b, conv2_b, biasws);

    // conv pair + qkv in ONE launch (1280 blocks; block range selects path)
    gemm_cq<<<dim3(1280), blk, 0, stream>>>(peb, w1b, c1b, part, biasws,
                                            xb, qkvwb, qbuf, kbuf, vtb);
    gn_apply<<<1024, blk, 0, stream>>>(c1b, c2b, part, gn1_g, gn1_b, gn2_g, gn2_b);
    // pe_attn[b][n][m] = sigmoid(sum_k p1[n][k] p2[m][k])  ([q][k] orientation)
    gemm_nt<2><<<dim3(1024), blk, 0, stream>>>(c1b, c2b, peatt, nullptr,
                                               512, 1048576, 1048576, 4194304, 16, 16);
    attn_fused<<<dim3(512), dim3(512), 0, stream>>>(qbuf, kbuf, vtb, peatt, hbuf);
    // proj: out = h @ proj_w.T + proj_b (f32)
    gemm_nt<3><<<dim3(256), blk, 0, stream>>>(hbuf, projwb, out, proj_b,
                                              512, 0, 0, 0, 4, 64);
}

// Round 13
// 221.984 us; speedup vs baseline: 1.4787x; 1.0188x over previous
//
#include <hip/hip_runtime.h>
#include <hip/hip_bf16.h>

// Shapes (fixed): B=4, N=2048, C=512, H=8, D=64, GROUPS=8, C/G=64
typedef __attribute__((ext_vector_type(8))) short bf16x8;
typedef __attribute__((ext_vector_type(4))) float f32x4;

__device__ __forceinline__ float bfu2f(unsigned int u) {
    return __uint_as_float(u << 16);
}
__device__ __forceinline__ unsigned short f2bfu(float f) {
    unsigned int u = __float_as_uint(f);
    u += 0x7fffu + ((u >> 16) & 1u);   // RNE
    return (unsigned short)(u >> 16);
}

// ---------------- all fp32->bf16 conversions + bias gather, one launch ----------------
__global__ __launch_bounds__(256) void cvt_all(
    const float* __restrict__ x, unsigned short* __restrict__ xb,
    const float* __restrict__ pe, unsigned short* __restrict__ peb,
    const float* __restrict__ w0, unsigned short* __restrict__ d0,
    const float* __restrict__ w1, unsigned short* __restrict__ d1,
    const float* __restrict__ w2, unsigned short* __restrict__ d2,
    const float* __restrict__ w3, unsigned short* __restrict__ d3,
    const float* __restrict__ c1bias, const float* __restrict__ c2bias,
    float* __restrict__ biasws) {
    const int tid = threadIdx.x;
    if (blockIdx.x == 0) {
        if (tid < 128) ((float4*)biasws)[tid] = ((const float4*)c1bias)[tid];
        else ((float4*)biasws)[tid] = ((const float4*)c2bias)[tid - 128];
    }
    int i = blockIdx.x * 256 + tid;
    const int stride = gridDim.x * 256;
    for (; i < 1441792; i += stride) {
        if (i < 1048576) {
            float4 v = reinterpret_cast<const float4*>(x)[i];
            ushort4 o;
            o.x = f2bfu(v.x); o.y = f2bfu(v.y); o.z = f2bfu(v.z); o.w = f2bfu(v.w);
            reinterpret_cast<ushort4*>(xb)[i] = o;
            float4 u = reinterpret_cast<const float4*>(pe)[i];
            ushort4 p;
            p.x = f2bfu(u.x); p.y = f2bfu(u.y); p.z = f2bfu(u.z); p.w = f2bfu(u.w);
            reinterpret_cast<ushort4*>(peb)[i] = p;
        } else {
            int j = i - 1048576;
            const float* s; unsigned short* d;
            if (j < 196608)      { s = w0; d = d0; }
            else if (j < 262144) { s = w1; d = d1; j -= 196608; }
            else if (j < 327680) { s = w2; d = d2; j -= 262144; }
            else                 { s = w3; d = d3; j -= 327680; }
            float4 v = reinterpret_cast<const float4*>(s)[j];
            ushort4 o;
            o.x = f2bfu(v.x); o.y = f2bfu(v.y); o.z = f2bfu(v.z); o.w = f2bfu(v.w);
            reinterpret_cast<ushort4*>(d)[j] = o;
        }
    }
}

// ---------------- generic NT GEMM, flat grid + bijective XCD swizzle [R11-verified] -----
// C[m][n] = sum_k A[m][k] * B[n][k].  128x128 tile, BK=32, 4 waves (2x2 of 64x64).
// Staging: global_load_lds width 16, double-buffered linear LDS [2][128][32],
// source pre-swizzle slot^=(row&3), read col (lh^(lr&3))*8 (same involution both sides).
// EPI: 0 = conv pair (bf16 out ld512, +bias from biasws, GN stats atomics via C1),
//      1 = qkv scatter (q*0.125*log2e, k, vT), 2 = sigmoid bf16 (ld2048, batched),
//      3 = proj (f32 out ld512, +bias)
template <int EPI>
__global__ __launch_bounds__(256) void gemm_nt(
    const unsigned short* __restrict__ A, const unsigned short* __restrict__ B,
    void* __restrict__ C0, void* __restrict__ C1, void* __restrict__ C2,
    const float* __restrict__ bias, int K, long sA, long sB, long sC,
    int nx, int ny) {
    __shared__ unsigned short As[2][128 * 32];
    __shared__ unsigned short Bs[2][128 * 32];
    int lin = blockIdx.x;
    const int qsw = gridDim.x >> 3;
    lin = (lin & 7) * qsw + (lin >> 3);          // bijective XCD swizzle (grid % 8 == 0)
    const int bx = lin % nx;
    const int t2 = lin / nx;
    const int by = t2 % ny;
    const int bz = t2 / ny;
    const int tid = threadIdx.x;
    const int l = tid & 63, w = tid >> 6;
    const int wr = w >> 1, wc = w & 1, lr = l & 15, lh = l >> 4;
    const int m0 = by * 128, n0 = bx * 128;
    A += (size_t)bz * sA;
    B += (size_t)bz * sB;
    f32x4 acc[4][4] = {};

    const int srow = l >> 2, sslot = l & 3;
    auto stage = [&](int bufi, int k0) {
#pragma unroll
        for (int i = 0; i < 2; i++) {
            const int row = w * 32 + i * 16 + srow;
            const int cs = (sslot ^ (row & 3)) * 8;
            const int ldsoff = (w * 32 + i * 16) * 32;
            __builtin_amdgcn_global_load_lds(
                (const __attribute__((address_space(1))) void*)(A + (size_t)(m0 + row) * K + k0 + cs),
                (__attribute__((address_space(3))) void*)&As[bufi][ldsoff], 16, 0, 0);
            __builtin_amdgcn_global_load_lds(
                (const __attribute__((address_space(1))) void*)(B + (size_t)(n0 + row) * K + k0 + cs),
                (__attribute__((address_space(3))) void*)&Bs[bufi][ldsoff], 16, 0, 0);
        }
    };

    const int nks = K >> 5;
    stage(0, 0);
    asm volatile("s_waitcnt vmcnt(0)" ::: "memory");
    __builtin_amdgcn_s_barrier();
    __builtin_amdgcn_sched_barrier(0);

    const int colA = (lh ^ (lr & 3)) << 3;
    for (int ks = 0; ks < nks; ks++) {
        const int cur = ks & 1;
        if (ks + 1 < nks) stage(cur ^ 1, (ks + 1) << 5);
        bf16x8 af[4], bfr[4];
#pragma unroll
        for (int i = 0; i < 4; i++)
            af[i] = *reinterpret_cast<const bf16x8*>(&As[cur][(wr * 64 + i * 16 + lr) * 32 + colA]);
#pragma unroll
        for (int i = 0; i < 4; i++)
            bfr[i] = *reinterpret_cast<const bf16x8*>(&Bs[cur][(wc * 64 + i * 16 + lr) * 32 + colA]);
        __builtin_amdgcn_s_setprio(1);
#pragma unroll
        for (int mi = 0; mi < 4; mi++)
#pragma unroll
            for (int ni = 0; ni < 4; ni++)
                acc[mi][ni] = __builtin_amdgcn_mfma_f32_16x16x32_bf16(af[mi], bfr[ni], acc[mi][ni], 0, 0, 0);
        __builtin_amdgcn_s_setprio(0);
        if (ks + 1 < nks) {
            asm volatile("s_waitcnt vmcnt(0) lgkmcnt(0)" ::: "memory");
            __builtin_amdgcn_s_barrier();
            __builtin_amdgcn_sched_barrier(0);
        }
    }

    float sgn = 0.f, qgn = 0.f;   // fused GN partial stats (EPI==0)
#pragma unroll
    for (int mi = 0; mi < 4; mi++) {
#pragma unroll
        for (int ni = 0; ni < 4; ni++) {
#pragma unroll
            for (int r = 0; r < 4; r++) {
                const int row = m0 + wr * 64 + mi * 16 + lh * 4 + r;
                const int col = n0 + wc * 64 + ni * 16 + lr;
                float v = acc[mi][ni][r];
                if constexpr (EPI == 0) {
                    v += bias[bz * 512 + col];
                    sgn += v; qgn += v * v;
                    ((unsigned short*)C0)[(size_t)bz * sC + (size_t)row * 512 + col] = f2bfu(v);
                } else if constexpr (EPI == 1) {
                    // col in [0,1536): j = part*512 + h*64 + d ; row = b*2048 + n
                    const int part = col >> 9, hh = (col >> 6) & 7, d = col & 63;
                    const int b = row >> 11, n = row & 2047;
                    const size_t bh = (size_t)(b * 8 + hh);
                    if (part == 0)
                        ((unsigned short*)C0)[(bh * 2048 + n) * 64 + d] = f2bfu(v * 0.1803368801111244f);
                    else if (part == 1)
                        ((unsigned short*)C1)[(bh * 2048 + n) * 64 + d] = f2bfu(v);
                    else
                        ((unsigned short*)C2)[(bh * 64 + d) * 2048 + n] = f2bfu(v);
                } else if constexpr (EPI == 2) {
                    const float sg = 1.0f / (1.0f + __expf(-v));
                    ((unsigned short*)C0)[(size_t)bz * sC + (size_t)row * 2048 + col] = f2bfu(sg);
                } else {
                    ((float*)C0)[(size_t)row * 512 + col] = v + bias[col];
                }
            }
        }
    }
    if constexpr (EPI == 0) {
        // wave holds one (b,g): b = by>>4, g = bx*2+wc
#pragma unroll
        for (int s = 1; s < 64; s <<= 1) {
            sgn += __shfl_xor(sgn, s);
            qgn += __shfl_xor(qgn, s);
        }
        if (l == 0) {
            const int bg = ((by >> 4) << 3) + bx * 2 + wc;
            float* part = (float*)C1;
            atomicAdd(&part[(bz * 32 + bg) * 2 + 0], sgn);
            atomicAdd(&part[(bz * 32 + bg) * 2 + 1], qgn);
        }
    }
}

// ---------------- GroupNorm apply (in place), stats finish folded in [R9-verified] ------
__global__ __launch_bounds__(256) void gn_apply(unsigned short* __restrict__ c1,
                                                unsigned short* __restrict__ c2,
                                                const float* __restrict__ part,
                                                const float* __restrict__ g1, const float* __restrict__ b1,
                                                const float* __restrict__ g2, const float* __restrict__ b2) {
    __shared__ float sst[2][32][2];
    const int tid = threadIdx.x;
    if (tid < 64) {
        const int z = tid >> 5, bg = tid & 31;
        const float S = part[(z * 32 + bg) * 2 + 0];
        const float Q = part[(z * 32 + bg) * 2 + 1];
        const float inv = 1.0f / 131072.0f;
        const float m = S * inv;
        const float v = fmaxf(Q * inv - m * m, 0.f);
        sst[z][bg][0] = m;
        sst[z][bg][1] = rsqrtf(v + 1e-5f);
    }
    __syncthreads();
    int i = blockIdx.x * 256 + tid;
    const int stride = gridDim.x * 256;
    for (; i < 524288; i += stride) {
        const size_t e = (size_t)i * 8;
        const int b = (int)(e >> 20);
        const int o = (int)(e & 511);
        const int g = o >> 6;
        const int bg = (b << 3) + g;
        const float m1 = sst[0][bg][0], r1 = sst[0][bg][1];
        const float m2 = sst[1][bg][0], r2 = sst[1][bg][1];
        uint4 v1 = *reinterpret_cast<const uint4*>(c1 + e);
        uint4 v2 = *reinterpret_cast<const uint4*>(c2 + e);
        unsigned int a1[4] = {v1.x, v1.y, v1.z, v1.w};
        unsigned int a2[4] = {v2.x, v2.y, v2.z, v2.w};
        unsigned int o1[4], o2[4];
#pragma unroll
        for (int j = 0; j < 4; j++) {
            const int oo = o + j * 2;
            float x0 = (bfu2f(a1[j] & 0xffffu) - m1) * r1 * g1[oo] + b1[oo];
            float x1 = (bfu2f(a1[j] >> 16) - m1) * r1 * g1[oo + 1] + b1[oo + 1];
            o1[j] = (unsigned int)f2bfu(x0) | ((unsigned int)f2bfu(x1) << 16);
            float y0 = (bfu2f(a2[j] & 0xffffu) - m2) * r2 * g2[oo] + b2[oo];
            float y1 = (bfu2f(a2[j] >> 16) - m2) * r2 * g2[oo + 1] + b2[oo + 1];
            o2[j] = (unsigned int)f2bfu(y0) | ((unsigned int)f2bfu(y1) << 16);
        }
        uint4 w1; w1.x = o1[0]; w1.y = o1[1]; w1.z = o1[2]; w1.w = o1[3];
        uint4 w2; w2.x = o2[0]; w2.y = o2[1]; w2.z = o2[2]; w2.w = o2[3];
        *reinterpret_cast<uint4*>(c1 + e) = w1;
        *reinterpret_cast<uint4*>(c2 + e) = w2;
    }
}

// ---------------- fused flash attention, 8-wave blocks [R12-verified, verbatim] ---------
// grid 512: h = bid>>6, nt = bid&15, b = (bid>>4)&3.  block 512 = 8 waves;
// wave w owns q-rows [nt*128 + 16w, +16).  K/V^T tiles (64 keys) shared by all 8 waves.
__global__ __launch_bounds__(512, 4) void attn_fused(
    const unsigned short* __restrict__ qb, const unsigned short* __restrict__ kb,
    const unsigned short* __restrict__ vT, const unsigned short* __restrict__ pea,
    unsigned short* __restrict__ hbuf) {
    __shared__ unsigned short Ks[2][64 * 64];
    __shared__ unsigned short Vs[2][64 * 64];
    __shared__ unsigned short Pl[8][16 * 64];
    const int tid = threadIdx.x, l = tid & 63, w = tid >> 6;
    const int lr = l & 15, lh = l >> 4;
    const int bid = blockIdx.x;
    const int h = bid >> 6, rst = bid & 63, nt = rst & 15, b = rst >> 4;
    const size_t bh = (size_t)(b * 8 + h);
    const unsigned short* qp = qb + bh * 2048 * 64;
    const unsigned short* kp = kb + bh * 2048 * 64;
    const unsigned short* vp = vT + bh * 64 * 2048;
    const unsigned short* pep = pea + (size_t)b * 2048 * 2048;   // [q][k] orientation
    const int qrow = nt * 128 + 16 * w + lr;                     // this lane's q-row

    bf16x8 qf[2];
    qf[0] = *reinterpret_cast<const bf16x8*>(qp + (size_t)qrow * 64 + lh * 8);
    qf[1] = *reinterpret_cast<const bf16x8*>(qp + (size_t)qrow * 64 + 32 + lh * 8);

    const int swz = (lr & 7) << 4;                       // byte XOR
    const int colK0 = ((16 * lh) ^ swz) >> 1;
    const int colK1 = ((64 + 16 * lh) ^ swz) >> 1;

    const unsigned short* perp = pep + (size_t)qrow * 2048;
    uint2 peR[4];
#pragma unroll
    for (int mf = 0; mf < 4; mf++)
        peR[mf] = *reinterpret_cast<const uint2*>(perp + 16 * mf + 4 * lh);

    f32x4 oacc[4] = {};
    float mrun = -1e30f, lrun = 0.f;

    // staging: wave w covers K/V rows [8w, 8w+8); lane l -> row 8w+(l>>3), slot l&7
    const int srow = l >> 3, sslot = l & 7;
    auto stage_kv = [&](int bufi, int m0) {
        const int row = w * 8 + srow;
        const int cs = (sslot ^ srow) * 8;               // row&7 == srow
        const int ldsoff = w * 512;                      // wave-uniform base (shorts)
        __builtin_amdgcn_global_load_lds(
            (const __attribute__((address_space(1))) void*)(kp + (size_t)(m0 + row) * 64 + cs),
            (__attribute__((address_space(3))) void*)&Ks[bufi][ldsoff], 16, 0, 0);
        __builtin_amdgcn_global_load_lds(
            (const __attribute__((address_space(1))) void*)(vp + (size_t)row * 2048 + m0 + cs),
            (__attribute__((address_space(3))) void*)&Vs[bufi][ldsoff], 16, 0, 0);
    };

    stage_kv(0, 0);
    asm volatile("s_waitcnt vmcnt(0)" ::: "memory");
    __builtin_amdgcn_s_barrier();
    __builtin_amdgcn_sched_barrier(0);

    for (int mt = 0; mt < 32; mt++) {
        const int cur = mt & 1;
        if (mt + 1 < 32) stage_kv(cur ^ 1, (mt + 1) * 64);
        const unsigned short* Kb = Ks[cur];
        const unsigned short* Vb = Vs[cur];

        f32x4 st[4] = {};
        __builtin_amdgcn_s_setprio(1);
#pragma unroll
        for (int mf = 0; mf < 4; mf++) {
            bf16x8 kf0 = *reinterpret_cast<const bf16x8*>(&Kb[(mf * 16 + lr) * 64 + colK0]);
            bf16x8 kf1 = *reinterpret_cast<const bf16x8*>(&Kb[(mf * 16 + lr) * 64 + colK1]);
            st[mf] = __builtin_amdgcn_mfma_f32_16x16x32_bf16(kf0, qf[0], st[mf], 0, 0, 0);
            st[mf] = __builtin_amdgcn_mfma_f32_16x16x32_bf16(kf1, qf[1], st[mf], 0, 0, 0);
        }
        __builtin_amdgcn_s_setprio(0);

        float p[4][4];
#pragma unroll
        for (int mf = 0; mf < 4; mf++) {
            p[mf][0] = st[mf][0] * bfu2f(peR[mf].x & 0xffffu);
            p[mf][1] = st[mf][1] * bfu2f(peR[mf].x >> 16);
            p[mf][2] = st[mf][2] * bfu2f(peR[mf].y & 0xffffu);
            p[mf][3] = st[mf][3] * bfu2f(peR[mf].y >> 16);
        }
        uint2 peN[4];
        if (mt + 1 < 32) {
            const unsigned short* pn = perp + (mt + 1) * 64;
#pragma unroll
            for (int mf = 0; mf < 4; mf++)
                peN[mf] = *reinterpret_cast<const uint2*>(pn + 16 * mf + 4 * lh);
        }
        float pm = fmaxf(p[0][0], p[0][1]);
        pm = fmaxf(fmaxf(pm, p[0][2]), p[0][3]);
#pragma unroll
        for (int mf = 1; mf < 4; mf++) {
            pm = fmaxf(fmaxf(pm, p[mf][0]), p[mf][1]);
            pm = fmaxf(fmaxf(pm, p[mf][2]), p[mf][3]);
        }
        pm = fmaxf(pm, __shfl_xor(pm, 16));
        pm = fmaxf(pm, __shfl_xor(pm, 32));
        if (__any(pm > mrun + 11.5416f)) {
            const float mnew = fmaxf(mrun, pm);
            const float fac = __builtin_amdgcn_exp2f(mrun - mnew);
            lrun *= fac;
#pragma unroll
            for (int df = 0; df < 4; df++)
#pragma unroll
                for (int r = 0; r < 4; r++) oacc[df][r] *= fac;
            mrun = mnew;
        }
        float ss = 0.f;
        unsigned int pk[8];
#pragma unroll
        for (int mf = 0; mf < 4; mf++) {
#pragma unroll
            for (int t = 0; t < 2; t++) {
                const float a = __builtin_amdgcn_exp2f(p[mf][2 * t] - mrun);
                const float c = __builtin_amdgcn_exp2f(p[mf][2 * t + 1] - mrun);
                unsigned int pkv;
                asm("v_cvt_pk_bf16_f32 %0, %1, %2" : "=v"(pkv) : "v"(a), "v"(c));
                pk[mf * 2 + t] = pkv;
                ss += a + c;
            }
        }
        ss += __shfl_xor(ss, 16);
        ss += __shfl_xor(ss, 32);
        lrun += ss;
        unsigned short* PlW = Pl[w];
        const int plswz = (lr & 7) << 4;               // byte XOR within 128B row
#pragma unroll
        for (int mf = 0; mf < 4; mf++)
#pragma unroll
            for (int t = 0; t < 2; t++) {
                const int cb = (mf * 32 + lh * 8 + 4 * t) ^ plswz;
                *reinterpret_cast<unsigned int*>(&PlW[lr * 64 + (cb >> 1)]) = pk[mf * 2 + t];
            }
        bf16x8 pb0 = *reinterpret_cast<const bf16x8*>(&PlW[lr * 64 + (((lh * 16) ^ plswz) >> 1)]);
        bf16x8 pb1 = *reinterpret_cast<const bf16x8*>(&PlW[lr * 64 + (((64 + lh * 16) ^ plswz) >> 1)]);
        __builtin_amdgcn_s_setprio(1);
#pragma unroll
        for (int df = 0; df < 4; df++) {
            bf16x8 vf0 = *reinterpret_cast<const bf16x8*>(&Vb[(df * 16 + lr) * 64 + colK0]);
            bf16x8 vf1 = *reinterpret_cast<const bf16x8*>(&Vb[(df * 16 + lr) * 64 + colK1]);
            oacc[df] = __builtin_amdgcn_mfma_f32_16x16x32_bf16(vf0, pb0, oacc[df], 0, 0, 0);
            oacc[df] = __builtin_amdgcn_mfma_f32_16x16x32_bf16(vf1, pb1, oacc[df], 0, 0, 0);
        }
        __builtin_amdgcn_s_setprio(0);
        if (mt + 1 < 32) {
            asm volatile("s_waitcnt vmcnt(0) lgkmcnt(0)" ::: "memory");
            __builtin_amdgcn_s_barrier();
            __builtin_amdgcn_sched_barrier(0);
#pragma unroll
            for (int mf = 0; mf < 4; mf++) peR[mf] = peN[mf];
        }
    }
    const float inv = 1.0f / lrun;
    const size_t base = ((size_t)b * 2048 + qrow) * 512 + h * 64;
#pragma unroll
    for (int df = 0; df < 4; df++) {
#pragma unroll
        for (int t = 0; t < 2; t++) {
            const unsigned int ua = f2bfu(oacc[df][2 * t] * inv);
            const unsigned int uc = f2bfu(oacc[df][2 * t + 1] * inv);
            *reinterpret_cast<unsigned int*>(&hbuf[base + 16 * df + 4 * lh + 2 * t]) = ua | (uc << 16);
        }
    }
}

extern "C" void kernel_launch(void* const* d_in, const int* in_sizes, int n_in,
                              void* d_out, int out_size, void* d_ws, size_t ws_size,
                              hipStream_t stream) {
    const float* x       = (const float*)d_in[0];
    const float* pe      = (const float*)d_in[1];
    const float* qkv_w   = (const float*)d_in[2];
    const float* proj_w  = (const float*)d_in[3];
    const float* proj_b  = (const float*)d_in[4];
    const float* conv1_w = (const float*)d_in[5];
    const float* conv1_b = (const float*)d_in[6];
    const float* gn1_g   = (const float*)d_in[7];
    const float* gn1_b   = (const float*)d_in[8];
    const float* conv2_w = (const float*)d_in[9];
    const float* conv2_b = (const float*)d_in[10];
    const float* gn2_g   = (const float*)d_in[11];
    const float* gn2_b   = (const float*)d_in[12];
    float* out = (float*)d_out;

    char* ws = (char*)d_ws;
    size_t off = 0;
    auto alloc = [&](size_t bytes) -> void* {
        void* p = ws + off;
        off += (bytes + 255) & ~(size_t)255;
        return p;
    };
    unsigned short* xb     = (unsigned short*)alloc(8388608);   // x bf16 [B*N, C]
    unsigned short* peb    = (unsigned short*)alloc(8388608);   // pe bf16
    unsigned short* qkvwb  = (unsigned short*)alloc(1572864);   // qkv_w bf16 [1536,512]
    unsigned short* projwb = (unsigned short*)alloc(524288);
    unsigned short* w1b    = (unsigned short*)alloc(524288);    // w1b/w2b contiguous (sB=262144)
    unsigned short* w2b    = (unsigned short*)alloc(524288);
    unsigned short* c1b    = (unsigned short*)alloc(8388608);   // c1b/c2b contiguous (sC=4194304)
    unsigned short* c2b    = (unsigned short*)alloc(8388608);
    unsigned short* qbuf   = (unsigned short*)alloc(8388608);   // [B,H,N,D] (q pre-scaled)
    unsigned short* kbuf   = (unsigned short*)alloc(8388608);
    unsigned short* vtb    = (unsigned short*)alloc(8388608);   // [B,H,D,N]
    unsigned short* peatt  = (unsigned short*)alloc(33554432);  // pe_attn [B,N(q),N(k)] bf16
    unsigned short* hbuf   = (unsigned short*)alloc(8388608);   // [B,N,C] bf16
    float* part            = (float*)alloc(512);                // GN stats [2][32][2]
    float* biasws          = (float*)alloc(4096);               // conv biases [2][512]

    dim3 blk(256);
    hipMemsetAsync(part, 0, 512, stream);
    cvt_all<<<2048, blk, 0, stream>>>(x, xb, pe, peb, qkv_w, qkvwb, proj_w, projwb,
                                      conv1_w, w1b, conv2_w, w2b, conv1_b, conv2_b, biasws);

    // conv1+conv2 in one launch (bz selects weights/bias/output); GN stats via atomics
    gemm_nt<0><<<dim3(512), blk, 0, stream>>>(peb, w1b, c1b, part, nullptr, biasws,
                                              512, 0, 262144, 4194304, 4, 64);
    gn_apply<<<1024, blk, 0, stream>>>(c1b, c2b, part, gn1_g, gn1_b, gn2_g, gn2_b);
    // qkv = x @ qkv_w.T, scattered to q (x0.125*log2e), k [B,H,N,D] and vT [B,H,D,N]
    gemm_nt<1><<<dim3(768), blk, 0, stream>>>(xb, qkvwb, qbuf, kbuf, vtb, nullptr,
                                              512, 0, 0, 0, 12, 64);
    // pe_attn[b][n][m] = sigmoid(sum_k p1[n][k] p2[m][k])  ([q][k] orientation)
    gemm_nt<2><<<dim3(1024), blk, 0, stream>>>(c1b, c2b, peatt, nullptr, nullptr, nullptr,
                                               512, 1048576, 1048576, 4194304, 16, 16);
    attn_fused<<<dim3(512), dim3(512), 0, stream>>>(qbuf, kbuf, vtb, peatt, hbuf);
    // proj: out = h @ proj_w.T + proj_b (f32)
    gemm_nt<3><<<dim3(256), blk, 0, stream>>>(hbuf, projwb, out, nullptr, nullptr, proj_b,
                                              512, 0, 0, 0, 4, 64);
}

// Round 14
// 221.659 us; speedup vs baseline: 1.4808x; 1.0015x over previous
//
#include <hip/hip_runtime.h>
#include <hip/hip_bf16.h>

// Shapes (fixed): B=4, N=2048, C=512, H=8, D=64, GROUPS=8, C/G=64
typedef __attribute__((ext_vector_type(8))) short bf16x8;
typedef __attribute__((ext_vector_type(4))) float f32x4;

__device__ __forceinline__ float bfu2f(unsigned int u) {
    return __uint_as_float(u << 16);
}
__device__ __forceinline__ unsigned short f2bfu(float f) {
    unsigned int u = __float_as_uint(f);
    u += 0x7fffu + ((u >> 16) & 1u);   // RNE
    return (unsigned short)(u >> 16);
}

// ---------------- all fp32->bf16 conversions + bias gather, one launch ----------------
__global__ __launch_bounds__(256) void cvt_all(
    const float* __restrict__ x, unsigned short* __restrict__ xb,
    const float* __restrict__ pe, unsigned short* __restrict__ peb,
    const float* __restrict__ w0, unsigned short* __restrict__ d0,
    const float* __restrict__ w1, unsigned short* __restrict__ d1,
    const float* __restrict__ w2, unsigned short* __restrict__ d2,
    const float* __restrict__ w3, unsigned short* __restrict__ d3,
    const float* __restrict__ c1bias, const float* __restrict__ c2bias,
    float* __restrict__ biasws) {
    const int tid = threadIdx.x;
    if (blockIdx.x == 0) {
        if (tid < 128) ((float4*)biasws)[tid] = ((const float4*)c1bias)[tid];
        else ((float4*)biasws)[tid] = ((const float4*)c2bias)[tid - 128];
    }
    int i = blockIdx.x * 256 + tid;
    const int stride = gridDim.x * 256;
    for (; i < 1441792; i += stride) {
        if (i < 1048576) {
            float4 v = reinterpret_cast<const float4*>(x)[i];
            ushort4 o;
            o.x = f2bfu(v.x); o.y = f2bfu(v.y); o.z = f2bfu(v.z); o.w = f2bfu(v.w);
            reinterpret_cast<ushort4*>(xb)[i] = o;
            float4 u = reinterpret_cast<const float4*>(pe)[i];
            ushort4 p;
            p.x = f2bfu(u.x); p.y = f2bfu(u.y); p.z = f2bfu(u.z); p.w = f2bfu(u.w);
            reinterpret_cast<ushort4*>(peb)[i] = p;
        } else {
            int j = i - 1048576;
            const float* s; unsigned short* d;
            if (j < 196608)      { s = w0; d = d0; }
            else if (j < 262144) { s = w1; d = d1; j -= 196608; }
            else if (j < 327680) { s = w2; d = d2; j -= 262144; }
            else                 { s = w3; d = d3; j -= 327680; }
            float4 v = reinterpret_cast<const float4*>(s)[j];
            ushort4 o;
            o.x = f2bfu(v.x); o.y = f2bfu(v.y); o.z = f2bfu(v.z); o.w = f2bfu(v.w);
            reinterpret_cast<ushort4*>(d)[j] = o;
        }
    }
}

// ---------------- generic NT GEMM, flat grid + bijective XCD swizzle [R11-verified] -----
// EPI: 0 = conv pair (bf16 out ld512, +bias from biasws, GN stats atomics via C1),
//      1 = qkv scatter (q*0.125*log2e, k, vT), 2 = sigmoid bf16 (ld2048, batched),
//      3 = proj (f32 out ld512, +bias)
template <int EPI>
__global__ __launch_bounds__(256) void gemm_nt(
    const unsigned short* __restrict__ A, const unsigned short* __restrict__ B,
    void* __restrict__ C0, void* __restrict__ C1, void* __restrict__ C2,
    const float* __restrict__ bias, int K, long sA, long sB, long sC,
    int nx, int ny) {
    __shared__ unsigned short As[2][128 * 32];
    __shared__ unsigned short Bs[2][128 * 32];
    int lin = blockIdx.x;
    const int qsw = gridDim.x >> 3;
    lin = (lin & 7) * qsw + (lin >> 3);          // bijective XCD swizzle (grid % 8 == 0)
    const int bx = lin % nx;
    const int t2 = lin / nx;
    const int by = t2 % ny;
    const int bz = t2 / ny;
    const int tid = threadIdx.x;
    const int l = tid & 63, w = tid >> 6;
    const int wr = w >> 1, wc = w & 1, lr = l & 15, lh = l >> 4;
    const int m0 = by * 128, n0 = bx * 128;
    A += (size_t)bz * sA;
    B += (size_t)bz * sB;
    f32x4 acc[4][4] = {};

    const int srow = l >> 2, sslot = l & 3;
    auto stage = [&](int bufi, int k0) {
#pragma unroll
        for (int i = 0; i < 2; i++) {
            const int row = w * 32 + i * 16 + srow;
            const int cs = (sslot ^ (row & 3)) * 8;
            const int ldsoff = (w * 32 + i * 16) * 32;
            __builtin_amdgcn_global_load_lds(
                (const __attribute__((address_space(1))) void*)(A + (size_t)(m0 + row) * K + k0 + cs),
                (__attribute__((address_space(3))) void*)&As[bufi][ldsoff], 16, 0, 0);
            __builtin_amdgcn_global_load_lds(
                (const __attribute__((address_space(1))) void*)(B + (size_t)(n0 + row) * K + k0 + cs),
                (__attribute__((address_space(3))) void*)&Bs[bufi][ldsoff], 16, 0, 0);
        }
    };

    const int nks = K >> 5;
    stage(0, 0);
    asm volatile("s_waitcnt vmcnt(0)" ::: "memory");
    __builtin_amdgcn_s_barrier();
    __builtin_amdgcn_sched_barrier(0);

    const int colA = (lh ^ (lr & 3)) << 3;
    for (int ks = 0; ks < nks; ks++) {
        const int cur = ks & 1;
        if (ks + 1 < nks) stage(cur ^ 1, (ks + 1) << 5);
        bf16x8 af[4], bfr[4];
#pragma unroll
        for (int i = 0; i < 4; i++)
            af[i] = *reinterpret_cast<const bf16x8*>(&As[cur][(wr * 64 + i * 16 + lr) * 32 + colA]);
#pragma unroll
        for (int i = 0; i < 4; i++)
            bfr[i] = *reinterpret_cast<const bf16x8*>(&Bs[cur][(wc * 64 + i * 16 + lr) * 32 + colA]);
        __builtin_amdgcn_s_setprio(1);
#pragma unroll
        for (int mi = 0; mi < 4; mi++)
#pragma unroll
            for (int ni = 0; ni < 4; ni++)
                acc[mi][ni] = __builtin_amdgcn_mfma_f32_16x16x32_bf16(af[mi], bfr[ni], acc[mi][ni], 0, 0, 0);
        __builtin_amdgcn_s_setprio(0);
        if (ks + 1 < nks) {
            asm volatile("s_waitcnt vmcnt(0) lgkmcnt(0)" ::: "memory");
            __builtin_amdgcn_s_barrier();
            __builtin_amdgcn_sched_barrier(0);
        }
    }

    float sgn = 0.f, qgn = 0.f;   // fused GN partial stats (EPI==0)
#pragma unroll
    for (int mi = 0; mi < 4; mi++) {
#pragma unroll
        for (int ni = 0; ni < 4; ni++) {
#pragma unroll
            for (int r = 0; r < 4; r++) {
                const int row = m0 + wr * 64 + mi * 16 + lh * 4 + r;
                const int col = n0 + wc * 64 + ni * 16 + lr;
                float v = acc[mi][ni][r];
                if constexpr (EPI == 0) {
                    v += bias[bz * 512 + col];
                    sgn += v; qgn += v * v;
                    ((unsigned short*)C0)[(size_t)bz * sC + (size_t)row * 512 + col] = f2bfu(v);
                } else if constexpr (EPI == 1) {
                    // col in [0,1536): j = part*512 + h*64 + d ; row = b*2048 + n
                    const int part = col >> 9, hh = (col >> 6) & 7, d = col & 63;
                    const int b = row >> 11, n = row & 2047;
                    const size_t bh = (size_t)(b * 8 + hh);
                    if (part == 0)
                        ((unsigned short*)C0)[(bh * 2048 + n) * 64 + d] = f2bfu(v * 0.1803368801111244f);
                    else if (part == 1)
                        ((unsigned short*)C1)[(bh * 2048 + n) * 64 + d] = f2bfu(v);
                    else
                        ((unsigned short*)C2)[(bh * 64 + d) * 2048 + n] = f2bfu(v);
                } else if constexpr (EPI == 2) {
                    const float sg = 1.0f / (1.0f + __expf(-v));
                    ((unsigned short*)C0)[(size_t)bz * sC + (size_t)row * 2048 + col] = f2bfu(sg);
                } else {
                    ((float*)C0)[(size_t)row * 512 + col] = v + bias[col];
                }
            }
        }
    }
    if constexpr (EPI == 0) {
        // wave holds one (b,g): b = by>>4, g = bx*2+wc
#pragma unroll
        for (int s = 1; s < 64; s <<= 1) {
            sgn += __shfl_xor(sgn, s);
            qgn += __shfl_xor(qgn, s);
        }
        if (l == 0) {
            const int bg = ((by >> 4) << 3) + bx * 2 + wc;
            float* part = (float*)C1;
            atomicAdd(&part[(bz * 32 + bg) * 2 + 0], sgn);
            atomicAdd(&part[(bz * 32 + bg) * 2 + 1], qgn);
        }
    }
}

// ---------------- GroupNorm apply (in place), stats finish folded in [R9-verified] ------
__global__ __launch_bounds__(256) void gn_apply(unsigned short* __restrict__ c1,
                                                unsigned short* __restrict__ c2,
                                                const float* __restrict__ part,
                                                const float* __restrict__ g1, const float* __restrict__ b1,
                                                const float* __restrict__ g2, const float* __restrict__ b2) {
    __shared__ float sst[2][32][2];
    const int tid = threadIdx.x;
    if (tid < 64) {
        const int z = tid >> 5, bg = tid & 31;
        const float S = part[(z * 32 + bg) * 2 + 0];
        const float Q = part[(z * 32 + bg) * 2 + 1];
        const float inv = 1.0f / 131072.0f;
        const float m = S * inv;
        const float v = fmaxf(Q * inv - m * m, 0.f);
        sst[z][bg][0] = m;
        sst[z][bg][1] = rsqrtf(v + 1e-5f);
    }
    __syncthreads();
    int i = blockIdx.x * 256 + tid;
    const int stride = gridDim.x * 256;
    for (; i < 524288; i += stride) {
        const size_t e = (size_t)i * 8;
        const int b = (int)(e >> 20);
        const int o = (int)(e & 511);
        const int g = o >> 6;
        const int bg = (b << 3) + g;
        const float m1 = sst[0][bg][0], r1 = sst[0][bg][1];
        const float m2 = sst[1][bg][0], r2 = sst[1][bg][1];
        uint4 v1 = *reinterpret_cast<const uint4*>(c1 + e);
        uint4 v2 = *reinterpret_cast<const uint4*>(c2 + e);
        unsigned int a1[4] = {v1.x, v1.y, v1.z, v1.w};
        unsigned int a2[4] = {v2.x, v2.y, v2.z, v2.w};
        unsigned int o1[4], o2[4];
#pragma unroll
        for (int j = 0; j < 4; j++) {
            const int oo = o + j * 2;
            float x0 = (bfu2f(a1[j] & 0xffffu) - m1) * r1 * g1[oo] + b1[oo];
            float x1 = (bfu2f(a1[j] >> 16) - m1) * r1 * g1[oo + 1] + b1[oo + 1];
            o1[j] = (unsigned int)f2bfu(x0) | ((unsigned int)f2bfu(x1) << 16);
            float y0 = (bfu2f(a2[j] & 0xffffu) - m2) * r2 * g2[oo] + b2[oo];
            float y1 = (bfu2f(a2[j] >> 16) - m2) * r2 * g2[oo + 1] + b2[oo + 1];
            o2[j] = (unsigned int)f2bfu(y0) | ((unsigned int)f2bfu(y1) << 16);
        }
        uint4 w1; w1.x = o1[0]; w1.y = o1[1]; w1.z = o1[2]; w1.w = o1[3];
        uint4 w2; w2.x = o2[0]; w2.y = o2[1]; w2.z = o2[2]; w2.w = o2[3];
        *reinterpret_cast<uint4*>(c1 + e) = w1;
        *reinterpret_cast<uint4*>(c2 + e) = w2;
    }
}

// ---------------- fused flash attention, 8-wave blocks, KVBLK=128 ----------------
// grid 512: h = bid>>6, nt = bid&15, b = (bid>>4)&3.  block 512 = 8 waves;
// wave w owns q-rows [nt*128 + 16w, +16).  Per iter: 128 keys (16 iters, 16 barriers).
// Ks [2][128 k][64 d]; Vs [2][64 d][128 k]; Pl [8][16 q][64 k] reused in 2 PV phases.
// LDS 80KB -> 2 blocks/CU.  Per-wave softmax math identical to R12 (just 8 frags/iter).
__global__ __launch_bounds__(512, 4) void attn_fused(
    const unsigned short* __restrict__ qb, const unsigned short* __restrict__ kb,
    const unsigned short* __restrict__ vT, const unsigned short* __restrict__ pea,
    unsigned short* __restrict__ hbuf) {
    __shared__ unsigned short Ks[2][128 * 64];
    __shared__ unsigned short Vs[2][64 * 128];
    __shared__ unsigned short Pl[8][16 * 64];
    const int tid = threadIdx.x, l = tid & 63, w = tid >> 6;
    const int lr = l & 15, lh = l >> 4;
    const int bid = blockIdx.x;
    const int h = bid >> 6, rst = bid & 63, nt = rst & 15, b = rst >> 4;
    const size_t bh = (size_t)(b * 8 + h);
    const unsigned short* qp = qb + bh * 2048 * 64;
    const unsigned short* kp = kb + bh * 2048 * 64;
    const unsigned short* vp = vT + bh * 64 * 2048;
    const unsigned short* pep = pea + (size_t)b * 2048 * 2048;   // [q][k] orientation
    const int qrow = nt * 128 + 16 * w + lr;                     // this lane's q-row

    bf16x8 qf[2];
    qf[0] = *reinterpret_cast<const bf16x8*>(qp + (size_t)qrow * 64 + lh * 8);
    qf[1] = *reinterpret_cast<const bf16x8*>(qp + (size_t)qrow * 64 + 32 + lh * 8);

    const int swz = (lr & 7) << 4;                       // byte XOR (row&7 == lr&7 for frag rows)
    const int colK0 = ((16 * lh) ^ swz) >> 1;            // Ks row stride 64 shorts
    const int colK1 = ((64 + 16 * lh) ^ swz) >> 1;
    int colV[4];                                          // Vs row stride 128 shorts; chunk c k=32c..
#pragma unroll
    for (int c = 0; c < 4; c++) colV[c] = ((64 * c + 16 * lh) ^ swz) >> 1;

    const unsigned short* perp = pep + (size_t)qrow * 2048;
    uint2 peR[8];
#pragma unroll
    for (int mf = 0; mf < 8; mf++)
        peR[mf] = *reinterpret_cast<const uint2*>(perp + 16 * mf + 4 * lh);

    f32x4 oacc[4] = {};
    float mrun = -1e30f, lrun = 0.f;

    // staging per wave: K = 2 instrs (rows 16w..16w+16, 8 slots/row);
    //                   V = 2 instrs (rows 8w..8w+8, 16 slots/row). chunk = 16B.
    auto stage_kv = [&](int bufi, int m0) {
#pragma unroll
        for (int i = 0; i < 2; i++) {
            const int kc = w * 128 + i * 64 + l;          // K chunk id
            const int krow = kc >> 3, kslot = kc & 7;
            const int kcs = (kslot ^ (krow & 7)) * 8;
            __builtin_amdgcn_global_load_lds(
                (const __attribute__((address_space(1))) void*)(kp + (size_t)(m0 + krow) * 64 + kcs),
                (__attribute__((address_space(3))) void*)&Ks[bufi][(w * 128 + i * 64) * 8], 16, 0, 0);
            const int vrow = kc >> 4, vslot = kc & 15;
            const int vcs = (vslot ^ (vrow & 7)) * 8;
            __builtin_amdgcn_global_load_lds(
                (const __attribute__((address_space(1))) void*)(vp + (size_t)vrow * 2048 + m0 + vcs),
                (__attribute__((address_space(3))) void*)&Vs[bufi][(w * 128 + i * 64) * 8], 16, 0, 0);
        }
    };

    stage_kv(0, 0);
    asm volatile("s_waitcnt vmcnt(0)" ::: "memory");
    __builtin_amdgcn_s_barrier();
    __builtin_amdgcn_sched_barrier(0);

    for (int mt = 0; mt < 16; mt++) {
        const int cur = mt & 1;
        if (mt + 1 < 16) stage_kv(cur ^ 1, (mt + 1) * 128);
        const unsigned short* Kb = Ks[cur];
        const unsigned short* Vb = Vs[cur];

        // S^T over 128 keys: 8 k-frags
        f32x4 st[8];
        __builtin_amdgcn_s_setprio(1);
#pragma unroll
        for (int mf = 0; mf < 8; mf++) {
            f32x4 z = {};
            bf16x8 kf0 = *reinterpret_cast<const bf16x8*>(&Kb[(mf * 16 + lr) * 64 + colK0]);
            bf16x8 kf1 = *reinterpret_cast<const bf16x8*>(&Kb[(mf * 16 + lr) * 64 + colK1]);
            z = __builtin_amdgcn_mfma_f32_16x16x32_bf16(kf0, qf[0], z, 0, 0, 0);
            st[mf] = __builtin_amdgcn_mfma_f32_16x16x32_bf16(kf1, qf[1], z, 0, 0, 0);
        }
        __builtin_amdgcn_s_setprio(0);

        float p[8][4];
#pragma unroll
        for (int mf = 0; mf < 8; mf++) {
            p[mf][0] = st[mf][0] * bfu2f(peR[mf].x & 0xffffu);
            p[mf][1] = st[mf][1] * bfu2f(peR[mf].x >> 16);
            p[mf][2] = st[mf][2] * bfu2f(peR[mf].y & 0xffffu);
            p[mf][3] = st[mf][3] * bfu2f(peR[mf].y >> 16);
        }
        uint2 peN[8];
        if (mt + 1 < 16) {
            const unsigned short* pn = perp + (mt + 1) * 128;
#pragma unroll
            for (int mf = 0; mf < 8; mf++)
                peN[mf] = *reinterpret_cast<const uint2*>(pn + 16 * mf + 4 * lh);
        }
        float pm = fmaxf(p[0][0], p[0][1]);
        pm = fmaxf(fmaxf(pm, p[0][2]), p[0][3]);
#pragma unroll
        for (int mf = 1; mf < 8; mf++) {
            pm = fmaxf(fmaxf(pm, p[mf][0]), p[mf][1]);
            pm = fmaxf(fmaxf(pm, p[mf][2]), p[mf][3]);
        }
        pm = fmaxf(pm, __shfl_xor(pm, 16));
        pm = fmaxf(pm, __shfl_xor(pm, 32));
        if (__any(pm > mrun + 11.5416f)) {
            const float mnew = fmaxf(mrun, pm);
            const float fac = __builtin_amdgcn_exp2f(mrun - mnew);
            lrun *= fac;
#pragma unroll
            for (int df = 0; df < 4; df++)
#pragma unroll
                for (int r = 0; r < 4; r++) oacc[df][r] *= fac;
            mrun = mnew;
        }
        float ss = 0.f;
        unsigned int pk[16];
#pragma unroll
        for (int mf = 0; mf < 8; mf++) {
#pragma unroll
            for (int t = 0; t < 2; t++) {
                const float a = __builtin_amdgcn_exp2f(p[mf][2 * t] - mrun);
                const float c = __builtin_amdgcn_exp2f(p[mf][2 * t + 1] - mrun);
                unsigned int pkv;
                asm("v_cvt_pk_bf16_f32 %0, %1, %2" : "=v"(pkv) : "v"(a), "v"(c));
                pk[mf * 2 + t] = pkv;
                ss += a + c;
            }
        }
        ss += __shfl_xor(ss, 16);
        ss += __shfl_xor(ss, 32);
        lrun += ss;
        // PV in two phases over the 128-key tile; Pl (wave-private) reused.
        unsigned short* PlW = Pl[w];
        const int plswz = (lr & 7) << 4;               // byte XOR within 128B row
#pragma unroll
        for (int kh = 0; kh < 2; kh++) {
#pragma unroll
            for (int mq = 0; mq < 4; mq++)
#pragma unroll
                for (int t = 0; t < 2; t++) {
                    const int cb = (mq * 32 + lh * 8 + 4 * t) ^ plswz;
                    *reinterpret_cast<unsigned int*>(&PlW[lr * 64 + (cb >> 1)]) = pk[(kh * 4 + mq) * 2 + t];
                }
            bf16x8 pb0 = *reinterpret_cast<const bf16x8*>(&PlW[lr * 64 + (((lh * 16) ^ plswz) >> 1)]);
            bf16x8 pb1 = *reinterpret_cast<const bf16x8*>(&PlW[lr * 64 + (((64 + lh * 16) ^ plswz) >> 1)]);
            __builtin_amdgcn_s_setprio(1);
#pragma unroll
            for (int df = 0; df < 4; df++) {
                bf16x8 vf0 = *reinterpret_cast<const bf16x8*>(&Vb[(df * 16 + lr) * 128 + colV[kh * 2]]);
                bf16x8 vf1 = *reinterpret_cast<const bf16x8*>(&Vb[(df * 16 + lr) * 128 + colV[kh * 2 + 1]]);
                oacc[df] = __builtin_amdgcn_mfma_f32_16x16x32_bf16(vf0, pb0, oacc[df], 0, 0, 0);
                oacc[df] = __builtin_amdgcn_mfma_f32_16x16x32_bf16(vf1, pb1, oacc[df], 0, 0, 0);
            }
            __builtin_amdgcn_s_setprio(0);
        }
        if (mt + 1 < 16) {
            asm volatile("s_waitcnt vmcnt(0) lgkmcnt(0)" ::: "memory");
            __builtin_amdgcn_s_barrier();
            __builtin_amdgcn_sched_barrier(0);
#pragma unroll
            for (int mf = 0; mf < 8; mf++) peR[mf] = peN[mf];
        }
    }
    const float inv = 1.0f / lrun;
    const size_t base = ((size_t)b * 2048 + qrow) * 512 + h * 64;
#pragma unroll
    for (int df = 0; df < 4; df++) {
#pragma unroll
        for (int t = 0; t < 2; t++) {
            const unsigned int ua = f2bfu(oacc[df][2 * t] * inv);
            const unsigned int uc = f2bfu(oacc[df][2 * t + 1] * inv);
            *reinterpret_cast<unsigned int*>(&hbuf[base + 16 * df + 4 * lh + 2 * t]) = ua | (uc << 16);
        }
    }
}

extern "C" void kernel_launch(void* const* d_in, const int* in_sizes, int n_in,
                              void* d_out, int out_size, void* d_ws, size_t ws_size,
                              hipStream_t stream) {
    const float* x       = (const float*)d_in[0];
    const float* pe      = (const float*)d_in[1];
    const float* qkv_w   = (const float*)d_in[2];
    const float* proj_w  = (const float*)d_in[3];
    const float* proj_b  = (const float*)d_in[4];
    const float* conv1_w = (const float*)d_in[5];
    const float* conv1_b = (const float*)d_in[6];
    const float* gn1_g   = (const float*)d_in[7];
    const float* gn1_b   = (const float*)d_in[8];
    const float* conv2_w = (const float*)d_in[9];
    const float* conv2_b = (const float*)d_in[10];
    const float* gn2_g   = (const float*)d_in[11];
    const float* gn2_b   = (const float*)d_in[12];
    float* out = (float*)d_out;

    char* ws = (char*)d_ws;
    size_t off = 0;
    auto alloc = [&](size_t bytes) -> void* {
        void* p = ws + off;
        off += (bytes + 255) & ~(size_t)255;
        return p;
    };
    unsigned short* xb     = (unsigned short*)alloc(8388608);   // x bf16 [B*N, C]
    unsigned short* peb    = (unsigned short*)alloc(8388608);   // pe bf16
    unsigned short* qkvwb  = (unsigned short*)alloc(1572864);   // qkv_w bf16 [1536,512]
    unsigned short* projwb = (unsigned short*)alloc(524288);
    unsigned short* w1b    = (unsigned short*)alloc(524288);    // w1b/w2b contiguous (sB=262144)
    unsigned short* w2b    = (unsigned short*)alloc(524288);
    unsigned short* c1b    = (unsigned short*)alloc(8388608);   // c1b/c2b contiguous (sC=4194304)
    unsigned short* c2b    = (unsigned short*)alloc(8388608);
    unsigned short* qbuf   = (unsigned short*)alloc(8388608);   // [B,H,N,D] (q pre-scaled)
    unsigned short* kbuf   = (unsigned short*)alloc(8388608);
    unsigned short* vtb    = (unsigned short*)alloc(8388608);   // [B,H,D,N]
    unsigned short* peatt  = (unsigned short*)alloc(33554432);  // pe_attn [B,N(q),N(k)] bf16
    unsigned short* hbuf   = (unsigned short*)alloc(8388608);   // [B,N,C] bf16
    float* part            = (float*)alloc(512);                // GN stats [2][32][2]
    float* biasws          = (float*)alloc(4096);               // conv biases [2][512]

    dim3 blk(256);
    hipMemsetAsync(part, 0, 512, stream);
    cvt_all<<<2048, blk, 0, stream>>>(x, xb, pe, peb, qkv_w, qkvwb, proj_w, projwb,
                                      conv1_w, w1b, conv2_w, w2b, conv1_b, conv2_b, biasws);

    // conv1+conv2 in one launch (bz selects weights/bias/output); GN stats via atomics
    gemm_nt<0><<<dim3(512), blk, 0, stream>>>(peb, w1b, c1b, part, nullptr, biasws,
                                              512, 0, 262144, 4194304, 4, 64);
    gn_apply<<<1024, blk, 0, stream>>>(c1b, c2b, part, gn1_g, gn1_b, gn2_g, gn2_b);
    // qkv = x @ qkv_w.T, scattered to q (x0.125*log2e), k [B,H,N,D] and vT [B,H,D,N]
    gemm_nt<1><<<dim3(768), blk, 0, stream>>>(xb, qkvwb, qbuf, kbuf, vtb, nullptr,
                                              512, 0, 0, 0, 12, 64);
    // pe_attn[b][n][m] = sigmoid(sum_k p1[n][k] p2[m][k])  ([q][k] orientation)
    gemm_nt<2><<<dim3(1024), blk, 0, stream>>>(c1b, c2b, peatt, nullptr, nullptr, nullptr,
                                               512, 1048576, 1048576, 4194304, 16, 16);
    attn_fused<<<dim3(512), dim3(512), 0, stream>>>(qbuf, kbuf, vtb, peatt, hbuf);
    // proj: out = h @ proj_w.T + proj_b (f32)
    gemm_nt<3><<<dim3(256), blk, 0, stream>>>(hbuf, projwb, out, nullptr, nullptr, proj_b,
                                              512, 0, 0, 0, 4, 64);
}

// Round 15
// 216.244 us; speedup vs baseline: 1.5179x; 1.0250x over previous
//
#include <hip/hip_runtime.h>
#include <hip/hip_bf16.h>

// Shapes (fixed): B=4, N=2048, C=512, H=8, D=64, GROUPS=8, C/G=64
typedef __attribute__((ext_vector_type(8))) short bf16x8;
typedef __attribute__((ext_vector_type(4))) float f32x4;

__device__ __forceinline__ float bfu2f(unsigned int u) {
    return __uint_as_float(u << 16);
}
__device__ __forceinline__ unsigned short f2bfu(float f) {
    unsigned int u = __float_as_uint(f);
    u += 0x7fffu + ((u >> 16) & 1u);   // RNE
    return (unsigned short)(u >> 16);
}

// ---------------- all fp32->bf16 conversions + bias gather, one launch ----------------
__global__ __launch_bounds__(256) void cvt_all(
    const float* __restrict__ x, unsigned short* __restrict__ xb,
    const float* __restrict__ pe, unsigned short* __restrict__ peb,
    const float* __restrict__ w0, unsigned short* __restrict__ d0,
    const float* __restrict__ w1, unsigned short* __restrict__ d1,
    const float* __restrict__ w2, unsigned short* __restrict__ d2,
    const float* __restrict__ w3, unsigned short* __restrict__ d3,
    const float* __restrict__ c1bias, const float* __restrict__ c2bias,
    float* __restrict__ biasws) {
    const int tid = threadIdx.x;
    if (blockIdx.x == 0) {
        if (tid < 128) ((float4*)biasws)[tid] = ((const float4*)c1bias)[tid];
        else ((float4*)biasws)[tid] = ((const float4*)c2bias)[tid - 128];
    }
    int i = blockIdx.x * 256 + tid;
    const int stride = gridDim.x * 256;
    for (; i < 1441792; i += stride) {
        if (i < 1048576) {
            float4 v = reinterpret_cast<const float4*>(x)[i];
            ushort4 o;
            o.x = f2bfu(v.x); o.y = f2bfu(v.y); o.z = f2bfu(v.z); o.w = f2bfu(v.w);
            reinterpret_cast<ushort4*>(xb)[i] = o;
            float4 u = reinterpret_cast<const float4*>(pe)[i];
            ushort4 p;
            p.x = f2bfu(u.x); p.y = f2bfu(u.y); p.z = f2bfu(u.z); p.w = f2bfu(u.w);
            reinterpret_cast<ushort4*>(peb)[i] = p;
        } else {
            int j = i - 1048576;
            const float* s; unsigned short* d;
            if (j < 196608)      { s = w0; d = d0; }
            else if (j < 262144) { s = w1; d = d1; j -= 196608; }
            else if (j < 327680) { s = w2; d = d2; j -= 262144; }
            else                 { s = w3; d = d3; j -= 327680; }
            float4 v = reinterpret_cast<const float4*>(s)[j];
            ushort4 o;
            o.x = f2bfu(v.x); o.y = f2bfu(v.y); o.z = f2bfu(v.z); o.w = f2bfu(v.w);
            reinterpret_cast<ushort4*>(d)[j] = o;
        }
    }
}

// ---------------- generic NT GEMM, 3-buffer rotation + counted vmcnt (T3/T4) ----------
// C[m][n] = sum_k A[m][k] * B[n][k].  128x128 tile, BK=32, 4 waves (2x2 of 64x64).
// Staging: global_load_lds width 16 into [3][128][32] rotation; per iter: wait OWN stage(t)
// done (vmcnt(4): one later stage stays IN FLIGHT across the barrier) + lgkm drain, barrier,
// then issue stage(t+2).  Last iter waits vmcnt(0).  Hazards: RAW via barrier-in; WAR via
// lgkmcnt(0) at the same barrier (readers of the overwritten buffer drained).
// EPI: 0 = conv pair (bf16 out, +bias, GN stats atomics via C1), 1 = qkv scatter,
//      2 = sigmoid bf16 (ld2048, batched), 3 = proj (f32 out, +bias)
template <int EPI>
__global__ __launch_bounds__(256) void gemm_nt(
    const unsigned short* __restrict__ A, const unsigned short* __restrict__ B,
    void* __restrict__ C0, void* __restrict__ C1, void* __restrict__ C2,
    const float* __restrict__ bias, int K, long sA, long sB, long sC,
    int nx, int ny) {
    __shared__ unsigned short As[3][128 * 32];
    __shared__ unsigned short Bs[3][128 * 32];
    int lin = blockIdx.x;
    const int qsw = gridDim.x >> 3;
    lin = (lin & 7) * qsw + (lin >> 3);          // bijective XCD swizzle (grid % 8 == 0)
    const int bx = lin % nx;
    const int t2 = lin / nx;
    const int by = t2 % ny;
    const int bz = t2 / ny;
    const int tid = threadIdx.x;
    const int l = tid & 63, w = tid >> 6;
    const int wr = w >> 1, wc = w & 1, lr = l & 15, lh = l >> 4;
    const int m0 = by * 128, n0 = bx * 128;
    A += (size_t)bz * sA;
    B += (size_t)bz * sB;
    f32x4 acc[4][4] = {};

    const int srow = l >> 2, sslot = l & 3;
    auto stage = [&](int bufi, int k0) {
#pragma unroll
        for (int i = 0; i < 2; i++) {
            const int row = w * 32 + i * 16 + srow;
            const int cs = (sslot ^ (row & 3)) * 8;
            const int ldsoff = (w * 32 + i * 16) * 32;
            __builtin_amdgcn_global_load_lds(
                (const __attribute__((address_space(1))) void*)(A + (size_t)(m0 + row) * K + k0 + cs),
                (__attribute__((address_space(3))) void*)&As[bufi][ldsoff], 16, 0, 0);
            __builtin_amdgcn_global_load_lds(
                (const __attribute__((address_space(1))) void*)(B + (size_t)(n0 + row) * K + k0 + cs),
                (__attribute__((address_space(3))) void*)&Bs[bufi][ldsoff], 16, 0, 0);
        }
    };

    const int nks = K >> 5;
    stage(0, 0);
    stage(1, 32);

    const int colA = (lh ^ (lr & 3)) << 3;
    int cur = 0;
    for (int ks = 0; ks < nks; ks++) {
        // barrier-in: own stage(ks) landed; one later stage may stay in flight
        if (ks == nks - 1)
            asm volatile("s_waitcnt vmcnt(0) lgkmcnt(0)" ::: "memory");
        else
            asm volatile("s_waitcnt vmcnt(4) lgkmcnt(0)" ::: "memory");
        __builtin_amdgcn_s_barrier();
        __builtin_amdgcn_sched_barrier(0);
        if (ks + 2 < nks) stage((ks + 2) % 3, (ks + 2) << 5);
        bf16x8 af[4], bfr[4];
#pragma unroll
        for (int i = 0; i < 4; i++)
            af[i] = *reinterpret_cast<const bf16x8*>(&As[cur][(wr * 64 + i * 16 + lr) * 32 + colA]);
#pragma unroll
        for (int i = 0; i < 4; i++)
            bfr[i] = *reinterpret_cast<const bf16x8*>(&Bs[cur][(wc * 64 + i * 16 + lr) * 32 + colA]);
        __builtin_amdgcn_s_setprio(1);
#pragma unroll
        for (int mi = 0; mi < 4; mi++)
#pragma unroll
            for (int ni = 0; ni < 4; ni++)
                acc[mi][ni] = __builtin_amdgcn_mfma_f32_16x16x32_bf16(af[mi], bfr[ni], acc[mi][ni], 0, 0, 0);
        __builtin_amdgcn_s_setprio(0);
        cur = (cur + 1) % 3;
    }

    float sgn = 0.f, qgn = 0.f;   // fused GN partial stats (EPI==0)
#pragma unroll
    for (int mi = 0; mi < 4; mi++) {
#pragma unroll
        for (int ni = 0; ni < 4; ni++) {
#pragma unroll
            for (int r = 0; r < 4; r++) {
                const int row = m0 + wr * 64 + mi * 16 + lh * 4 + r;
                const int col = n0 + wc * 64 + ni * 16 + lr;
                float v = acc[mi][ni][r];
                if constexpr (EPI == 0) {
                    v += bias[bz * 512 + col];
                    sgn += v; qgn += v * v;
                    ((unsigned short*)C0)[(size_t)bz * sC + (size_t)row * 512 + col] = f2bfu(v);
                } else if constexpr (EPI == 1) {
                    // col in [0,1536): j = part*512 + h*64 + d ; row = b*2048 + n
                    const int part = col >> 9, hh = (col >> 6) & 7, d = col & 63;
                    const int b = row >> 11, n = row & 2047;
                    const size_t bh = (size_t)(b * 8 + hh);
                    if (part == 0)
                        ((unsigned short*)C0)[(bh * 2048 + n) * 64 + d] = f2bfu(v * 0.1803368801111244f);
                    else if (part == 1)
                        ((unsigned short*)C1)[(bh * 2048 + n) * 64 + d] = f2bfu(v);
                    else
                        ((unsigned short*)C2)[(bh * 64 + d) * 2048 + n] = f2bfu(v);
                } else if constexpr (EPI == 2) {
                    const float sg = 1.0f / (1.0f + __expf(-v));
                    ((unsigned short*)C0)[(size_t)bz * sC + (size_t)row * 2048 + col] = f2bfu(sg);
                } else {
                    ((float*)C0)[(size_t)row * 512 + col] = v + bias[col];
                }
            }
        }
    }
    if constexpr (EPI == 0) {
        // wave holds one (b,g): b = by>>4, g = bx*2+wc
#pragma unroll
        for (int s = 1; s < 64; s <<= 1) {
            sgn += __shfl_xor(sgn, s);
            qgn += __shfl_xor(qgn, s);
        }
        if (l == 0) {
            const int bg = ((by >> 4) << 3) + bx * 2 + wc;
            float* part = (float*)C1;
            atomicAdd(&part[(bz * 32 + bg) * 2 + 0], sgn);
            atomicAdd(&part[(bz * 32 + bg) * 2 + 1], qgn);
        }
    }
}

// ---------------- GroupNorm apply (in place), stats finish folded in [R9-verified] ------
__global__ __launch_bounds__(256) void gn_apply(unsigned short* __restrict__ c1,
                                                unsigned short* __restrict__ c2,
                                                const float* __restrict__ part,
                                                const float* __restrict__ g1, const float* __restrict__ b1,
                                                const float* __restrict__ g2, const float* __restrict__ b2) {
    __shared__ float sst[2][32][2];
    const int tid = threadIdx.x;
    if (tid < 64) {
        const int z = tid >> 5, bg = tid & 31;
        const float S = part[(z * 32 + bg) * 2 + 0];
        const float Q = part[(z * 32 + bg) * 2 + 1];
        const float inv = 1.0f / 131072.0f;
        const float m = S * inv;
        const float v = fmaxf(Q * inv - m * m, 0.f);
        sst[z][bg][0] = m;
        sst[z][bg][1] = rsqrtf(v + 1e-5f);
    }
    __syncthreads();
    int i = blockIdx.x * 256 + tid;
    const int stride = gridDim.x * 256;
    for (; i < 524288; i += stride) {
        const size_t e = (size_t)i * 8;
        const int b = (int)(e >> 20);
        const int o = (int)(e & 511);
        const int g = o >> 6;
        const int bg = (b << 3) + g;
        const float m1 = sst[0][bg][0], r1 = sst[0][bg][1];
        const float m2 = sst[1][bg][0], r2 = sst[1][bg][1];
        uint4 v1 = *reinterpret_cast<const uint4*>(c1 + e);
        uint4 v2 = *reinterpret_cast<const uint4*>(c2 + e);
        unsigned int a1[4] = {v1.x, v1.y, v1.z, v1.w};
        unsigned int a2[4] = {v2.x, v2.y, v2.z, v2.w};
        unsigned int o1[4], o2[4];
#pragma unroll
        for (int j = 0; j < 4; j++) {
            const int oo = o + j * 2;
            float x0 = (bfu2f(a1[j] & 0xffffu) - m1) * r1 * g1[oo] + b1[oo];
            float x1 = (bfu2f(a1[j] >> 16) - m1) * r1 * g1[oo + 1] + b1[oo + 1];
            o1[j] = (unsigned int)f2bfu(x0) | ((unsigned int)f2bfu(x1) << 16);
            float y0 = (bfu2f(a2[j] & 0xffffu) - m2) * r2 * g2[oo] + b2[oo];
            float y1 = (bfu2f(a2[j] >> 16) - m2) * r2 * g2[oo + 1] + b2[oo + 1];
            o2[j] = (unsigned int)f2bfu(y0) | ((unsigned int)f2bfu(y1) << 16);
        }
        uint4 w1; w1.x = o1[0]; w1.y = o1[1]; w1.z = o1[2]; w1.w = o1[3];
        uint4 w2; w2.x = o2[0]; w2.y = o2[1]; w2.z = o2[2]; w2.w = o2[3];
        *reinterpret_cast<uint4*>(c1 + e) = w1;
        *reinterpret_cast<uint4*>(c2 + e) = w2;
    }
}

// ---------------- fused flash attention, 8-wave blocks, KVBLK=128 [R14-verified] --------
__global__ __launch_bounds__(512, 4) void attn_fused(
    const unsigned short* __restrict__ qb, const unsigned short* __restrict__ kb,
    const unsigned short* __restrict__ vT, const unsigned short* __restrict__ pea,
    unsigned short* __restrict__ hbuf) {
    __shared__ unsigned short Ks[2][128 * 64];
    __shared__ unsigned short Vs[2][64 * 128];
    __shared__ unsigned short Pl[8][16 * 64];
    const int tid = threadIdx.x, l = tid & 63, w = tid >> 6;
    const int lr = l & 15, lh = l >> 4;
    const int bid = blockIdx.x;
    const int h = bid >> 6, rst = bid & 63, nt = rst & 15, b = rst >> 4;
    const size_t bh = (size_t)(b * 8 + h);
    const unsigned short* qp = qb + bh * 2048 * 64;
    const unsigned short* kp = kb + bh * 2048 * 64;
    const unsigned short* vp = vT + bh * 64 * 2048;
    const unsigned short* pep = pea + (size_t)b * 2048 * 2048;   // [q][k] orientation
    const int qrow = nt * 128 + 16 * w + lr;                     // this lane's q-row

    bf16x8 qf[2];
    qf[0] = *reinterpret_cast<const bf16x8*>(qp + (size_t)qrow * 64 + lh * 8);
    qf[1] = *reinterpret_cast<const bf16x8*>(qp + (size_t)qrow * 64 + 32 + lh * 8);

    const int swz = (lr & 7) << 4;                       // byte XOR
    const int colK0 = ((16 * lh) ^ swz) >> 1;            // Ks row stride 64 shorts
    const int colK1 = ((64 + 16 * lh) ^ swz) >> 1;
    int colV[4];                                          // Vs row stride 128 shorts
#pragma unroll
    for (int c = 0; c < 4; c++) colV[c] = ((64 * c + 16 * lh) ^ swz) >> 1;

    const unsigned short* perp = pep + (size_t)qrow * 2048;
    uint2 peR[8];
#pragma unroll
    for (int mf = 0; mf < 8; mf++)
        peR[mf] = *reinterpret_cast<const uint2*>(perp + 16 * mf + 4 * lh);

    f32x4 oacc[4] = {};
    float mrun = -1e30f, lrun = 0.f;

    auto stage_kv = [&](int bufi, int m0) {
#pragma unroll
        for (int i = 0; i < 2; i++) {
            const int kc = w * 128 + i * 64 + l;          // K chunk id
            const int krow = kc >> 3, kslot = kc & 7;
            const int kcs = (kslot ^ (krow & 7)) * 8;
            __builtin_amdgcn_global_load_lds(
                (const __attribute__((address_space(1))) void*)(kp + (size_t)(m0 + krow) * 64 + kcs),
                (__attribute__((address_space(3))) void*)&Ks[bufi][(w * 128 + i * 64) * 8], 16, 0, 0);
            const int vrow = kc >> 4, vslot = kc & 15;
            const int vcs = (vslot ^ (vrow & 7)) * 8;
            __builtin_amdgcn_global_load_lds(
                (const __attribute__((address_space(1))) void*)(vp + (size_t)vrow * 2048 + m0 + vcs),
                (__attribute__((address_space(3))) void*)&Vs[bufi][(w * 128 + i * 64) * 8], 16, 0, 0);
        }
    };

    stage_kv(0, 0);
    asm volatile("s_waitcnt vmcnt(0)" ::: "memory");
    __builtin_amdgcn_s_barrier();
    __builtin_amdgcn_sched_barrier(0);

    for (int mt = 0; mt < 16; mt++) {
        const int cur = mt & 1;
        if (mt + 1 < 16) stage_kv(cur ^ 1, (mt + 1) * 128);
        const unsigned short* Kb = Ks[cur];
        const unsigned short* Vb = Vs[cur];

        f32x4 st[8];
        __builtin_amdgcn_s_setprio(1);
#pragma unroll
        for (int mf = 0; mf < 8; mf++) {
            f32x4 z = {};
            bf16x8 kf0 = *reinterpret_cast<const bf16x8*>(&Kb[(mf * 16 + lr) * 64 + colK0]);
            bf16x8 kf1 = *reinterpret_cast<const bf16x8*>(&Kb[(mf * 16 + lr) * 64 + colK1]);
            z = __builtin_amdgcn_mfma_f32_16x16x32_bf16(kf0, qf[0], z, 0, 0, 0);
            st[mf] = __builtin_amdgcn_mfma_f32_16x16x32_bf16(kf1, qf[1], z, 0, 0, 0);
        }
        __builtin_amdgcn_s_setprio(0);

        float p[8][4];
#pragma unroll
        for (int mf = 0; mf < 8; mf++) {
            p[mf][0] = st[mf][0] * bfu2f(peR[mf].x & 0xffffu);
            p[mf][1] = st[mf][1] * bfu2f(peR[mf].x >> 16);
            p[mf][2] = st[mf][2] * bfu2f(peR[mf].y & 0xffffu);
            p[mf][3] = st[mf][3] * bfu2f(peR[mf].y >> 16);
        }
        uint2 peN[8];
        if (mt + 1 < 16) {
            const unsigned short* pn = perp + (mt + 1) * 128;
#pragma unroll
            for (int mf = 0; mf < 8; mf++)
                peN[mf] = *reinterpret_cast<const uint2*>(pn + 16 * mf + 4 * lh);
        }
        float pm = fmaxf(p[0][0], p[0][1]);
        pm = fmaxf(fmaxf(pm, p[0][2]), p[0][3]);
#pragma unroll
        for (int mf = 1; mf < 8; mf++) {
            pm = fmaxf(fmaxf(pm, p[mf][0]), p[mf][1]);
            pm = fmaxf(fmaxf(pm, p[mf][2]), p[mf][3]);
        }
        pm = fmaxf(pm, __shfl_xor(pm, 16));
        pm = fmaxf(pm, __shfl_xor(pm, 32));
        if (__any(pm > mrun + 11.5416f)) {
            const float mnew = fmaxf(mrun, pm);
            const float fac = __builtin_amdgcn_exp2f(mrun - mnew);
            lrun *= fac;
#pragma unroll
            for (int df = 0; df < 4; df++)
#pragma unroll
                for (int r = 0; r < 4; r++) oacc[df][r] *= fac;
            mrun = mnew;
        }
        float ss = 0.f;
        unsigned int pk[16];
#pragma unroll
        for (int mf = 0; mf < 8; mf++) {
#pragma unroll
            for (int t = 0; t < 2; t++) {
                const float a = __builtin_amdgcn_exp2f(p[mf][2 * t] - mrun);
                const float c = __builtin_amdgcn_exp2f(p[mf][2 * t + 1] - mrun);
                unsigned int pkv;
                asm("v_cvt_pk_bf16_f32 %0, %1, %2" : "=v"(pkv) : "v"(a), "v"(c));
                pk[mf * 2 + t] = pkv;
                ss += a + c;
            }
        }
        ss += __shfl_xor(ss, 16);
        ss += __shfl_xor(ss, 32);
        lrun += ss;
        unsigned short* PlW = Pl[w];
        const int plswz = (lr & 7) << 4;               // byte XOR within 128B row
#pragma unroll
        for (int kh = 0; kh < 2; kh++) {
#pragma unroll
            for (int mq = 0; mq < 4; mq++)
#pragma unroll
                for (int t = 0; t < 2; t++) {
                    const int cb = (mq * 32 + lh * 8 + 4 * t) ^ plswz;
                    *reinterpret_cast<unsigned int*>(&PlW[lr * 64 + (cb >> 1)]) = pk[(kh * 4 + mq) * 2 + t];
                }
            bf16x8 pb0 = *reinterpret_cast<const bf16x8*>(&PlW[lr * 64 + (((lh * 16) ^ plswz) >> 1)]);
            bf16x8 pb1 = *reinterpret_cast<const bf16x8*>(&PlW[lr * 64 + (((64 + lh * 16) ^ plswz) >> 1)]);
            __builtin_amdgcn_s_setprio(1);
#pragma unroll
            for (int df = 0; df < 4; df++) {
                bf16x8 vf0 = *reinterpret_cast<const bf16x8*>(&Vb[(df * 16 + lr) * 128 + colV[kh * 2]]);
                bf16x8 vf1 = *reinterpret_cast<const bf16x8*>(&Vb[(df * 16 + lr) * 128 + colV[kh * 2 + 1]]);
                oacc[df] = __builtin_amdgcn_mfma_f32_16x16x32_bf16(vf0, pb0, oacc[df], 0, 0, 0);
                oacc[df] = __builtin_amdgcn_mfma_f32_16x16x32_bf16(vf1, pb1, oacc[df], 0, 0, 0);
            }
            __builtin_amdgcn_s_setprio(0);
        }
        if (mt + 1 < 16) {
            asm volatile("s_waitcnt vmcnt(0) lgkmcnt(0)" ::: "memory");
            __builtin_amdgcn_s_barrier();
            __builtin_amdgcn_sched_barrier(0);
#pragma unroll
            for (int mf = 0; mf < 8; mf++) peR[mf] = peN[mf];
        }
    }
    const float inv = 1.0f / lrun;
    const size_t base = ((size_t)b * 2048 + qrow) * 512 + h * 64;
#pragma unroll
    for (int df = 0; df < 4; df++) {
#pragma unroll
        for (int t = 0; t < 2; t++) {
            const unsigned int ua = f2bfu(oacc[df][2 * t] * inv);
            const unsigned int uc = f2bfu(oacc[df][2 * t + 1] * inv);
            *reinterpret_cast<unsigned int*>(&hbuf[base + 16 * df + 4 * lh + 2 * t]) = ua | (uc << 16);
        }
    }
}

extern "C" void kernel_launch(void* const* d_in, const int* in_sizes, int n_in,
                              void* d_out, int out_size, void* d_ws, size_t ws_size,
                              hipStream_t stream) {
    const float* x       = (const float*)d_in[0];
    const float* pe      = (const float*)d_in[1];
    const float* qkv_w   = (const float*)d_in[2];
    const float* proj_w  = (const float*)d_in[3];
    const float* proj_b  = (const float*)d_in[4];
    const float* conv1_w = (const float*)d_in[5];
    const float* conv1_b = (const float*)d_in[6];
    const float* gn1_g   = (const float*)d_in[7];
    const float* gn1_b   = (const float*)d_in[8];
    const float* conv2_w = (const float*)d_in[9];
    const float* conv2_b = (const float*)d_in[10];
    const float* gn2_g   = (const float*)d_in[11];
    const float* gn2_b   = (const float*)d_in[12];
    float* out = (float*)d_out;

    char* ws = (char*)d_ws;
    size_t off = 0;
    auto alloc = [&](size_t bytes) -> void* {
        void* p = ws + off;
        off += (bytes + 255) & ~(size_t)255;
        return p;
    };
    unsigned short* xb     = (unsigned short*)alloc(8388608);   // x bf16 [B*N, C]
    unsigned short* peb    = (unsigned short*)alloc(8388608);   // pe bf16
    unsigned short* qkvwb  = (unsigned short*)alloc(1572864);   // qkv_w bf16 [1536,512]
    unsigned short* projwb = (unsigned short*)alloc(524288);
    unsigned short* w1b    = (unsigned short*)alloc(524288);    // w1b/w2b contiguous (sB=262144)
    unsigned short* w2b    = (unsigned short*)alloc(524288);
    unsigned short* c1b    = (unsigned short*)alloc(8388608);   // c1b/c2b contiguous (sC=4194304)
    unsigned short* c2b    = (unsigned short*)alloc(8388608);
    unsigned short* qbuf   = (unsigned short*)alloc(8388608);   // [B,H,N,D] (q pre-scaled)
    unsigned short* kbuf   = (unsigned short*)alloc(8388608);
    unsigned short* vtb    = (unsigned short*)alloc(8388608);   // [B,H,D,N]
    unsigned short* peatt  = (unsigned short*)alloc(33554432);  // pe_attn [B,N(q),N(k)] bf16
    unsigned short* hbuf   = (unsigned short*)alloc(8388608);   // [B,N,C] bf16
    float* part            = (float*)alloc(512);                // GN stats [2][32][2]
    float* biasws          = (float*)alloc(4096);               // conv biases [2][512]

    dim3 blk(256);
    hipMemsetAsync(part, 0, 512, stream);
    cvt_all<<<2048, blk, 0, stream>>>(x, xb, pe, peb, qkv_w, qkvwb, proj_w, projwb,
                                      conv1_w, w1b, conv2_w, w2b, conv1_b, conv2_b, biasws);

    // conv1+conv2 in one launch (bz selects weights/bias/output); GN stats via atomics
    gemm_nt<0><<<dim3(512), blk, 0, stream>>>(peb, w1b, c1b, part, nullptr, biasws,
                                              512, 0, 262144, 4194304, 4, 64);
    gn_apply<<<1024, blk, 0, stream>>>(c1b, c2b, part, gn1_g, gn1_b, gn2_g, gn2_b);
    // qkv = x @ qkv_w.T, scattered to q (x0.125*log2e), k [B,H,N,D] and vT [B,H,D,N]
    gemm_nt<1><<<dim3(768), blk, 0, stream>>>(xb, qkvwb, qbuf, kbuf, vtb, nullptr,
                                              512, 0, 0, 0, 12, 64);
    // pe_attn[b][n][m] = sigmoid(sum_k p1[n][k] p2[m][k])  ([q][k] orientation)
    gemm_nt<2><<<dim3(1024), blk, 0, stream>>>(c1b, c2b, peatt, nullptr, nullptr, nullptr,
                                               512, 1048576, 1048576, 4194304, 16, 16);
    attn_fused<<<dim3(512), dim3(512), 0, stream>>>(qbuf, kbuf, vtb, peatt, hbuf);
    // proj: out = h @ proj_w.T + proj_b (f32)
    gemm_nt<3><<<dim3(256), blk, 0, stream>>>(hbuf, projwb, out, nullptr, nullptr, proj_b,
                                              512, 0, 0, 0, 4, 64);
}

// Round 16
// 214.920 us; speedup vs baseline: 1.5273x; 1.0062x over previous
//
#include <hip/hip_runtime.h>
#include <hip/hip_bf16.h>

// Shapes (fixed): B=4, N=2048, C=512, H=8, D=64, GROUPS=8, C/G=64
typedef __attribute__((ext_vector_type(8))) short bf16x8;
typedef __attribute__((ext_vector_type(4))) float f32x4;

__device__ __forceinline__ float bfu2f(unsigned int u) {
    return __uint_as_float(u << 16);
}
__device__ __forceinline__ unsigned short f2bfu(float f) {
    unsigned int u = __float_as_uint(f);
    u += 0x7fffu + ((u >> 16) & 1u);   // RNE
    return (unsigned short)(u >> 16);
}

// ---------------- all fp32->bf16 conversions + bias gather, one launch ----------------
__global__ __launch_bounds__(256) void cvt_all(
    const float* __restrict__ x, unsigned short* __restrict__ xb,
    const float* __restrict__ pe, unsigned short* __restrict__ peb,
    const float* __restrict__ w0, unsigned short* __restrict__ d0,
    const float* __restrict__ w1, unsigned short* __restrict__ d1,
    const float* __restrict__ w2, unsigned short* __restrict__ d2,
    const float* __restrict__ w3, unsigned short* __restrict__ d3,
    const float* __restrict__ c1bias, const float* __restrict__ c2bias,
    float* __restrict__ biasws) {
    const int tid = threadIdx.x;
    if (blockIdx.x == 0) {
        if (tid < 128) ((float4*)biasws)[tid] = ((const float4*)c1bias)[tid];
        else ((float4*)biasws)[tid] = ((const float4*)c2bias)[tid - 128];
    }
    int i = blockIdx.x * 256 + tid;
    const int stride = gridDim.x * 256;
    for (; i < 1441792; i += stride) {
        if (i < 1048576) {
            float4 v = reinterpret_cast<const float4*>(x)[i];
            ushort4 o;
            o.x = f2bfu(v.x); o.y = f2bfu(v.y); o.z = f2bfu(v.z); o.w = f2bfu(v.w);
            reinterpret_cast<ushort4*>(xb)[i] = o;
            float4 u = reinterpret_cast<const float4*>(pe)[i];
            ushort4 p;
            p.x = f2bfu(u.x); p.y = f2bfu(u.y); p.z = f2bfu(u.z); p.w = f2bfu(u.w);
            reinterpret_cast<ushort4*>(peb)[i] = p;
        } else {
            int j = i - 1048576;
            const float* s; unsigned short* d;
            if (j < 196608)      { s = w0; d = d0; }
            else if (j < 262144) { s = w1; d = d1; j -= 196608; }
            else if (j < 327680) { s = w2; d = d2; j -= 262144; }
            else                 { s = w3; d = d3; j -= 327680; }
            float4 v = reinterpret_cast<const float4*>(s)[j];
            ushort4 o;
            o.x = f2bfu(v.x); o.y = f2bfu(v.y); o.z = f2bfu(v.z); o.w = f2bfu(v.w);
            reinterpret_cast<ushort4*>(d)[j] = o;
        }
    }
}

// ---------------- generic NT GEMM, 3-buffer rotation + counted vmcnt [R15-verified] -----
// EPI: 0 = conv pair (bf16 out, +bias, GN stats atomics via C1),
//      2 = sigmoid bf16 (ld2048, batched), 3 = proj (f32 out, +bias)
template <int EPI>
__global__ __launch_bounds__(256) void gemm_nt(
    const unsigned short* __restrict__ A, const unsigned short* __restrict__ B,
    void* __restrict__ C0, void* __restrict__ C1, void* __restrict__ C2,
    const float* __restrict__ bias, int K, long sA, long sB, long sC,
    int nx, int ny) {
    __shared__ unsigned short As[3][128 * 32];
    __shared__ unsigned short Bs[3][128 * 32];
    int lin = blockIdx.x;
    const int qsw = gridDim.x >> 3;
    lin = (lin & 7) * qsw + (lin >> 3);          // bijective XCD swizzle (grid % 8 == 0)
    const int bx = lin % nx;
    const int t2 = lin / nx;
    const int by = t2 % ny;
    const int bz = t2 / ny;
    const int tid = threadIdx.x;
    const int l = tid & 63, w = tid >> 6;
    const int wr = w >> 1, wc = w & 1, lr = l & 15, lh = l >> 4;
    const int m0 = by * 128, n0 = bx * 128;
    A += (size_t)bz * sA;
    B += (size_t)bz * sB;
    f32x4 acc[4][4] = {};

    const int srow = l >> 2, sslot = l & 3;
    auto stage = [&](int bufi, int k0) {
#pragma unroll
        for (int i = 0; i < 2; i++) {
            const int row = w * 32 + i * 16 + srow;
            const int cs = (sslot ^ (row & 3)) * 8;
            const int ldsoff = (w * 32 + i * 16) * 32;
            __builtin_amdgcn_global_load_lds(
                (const __attribute__((address_space(1))) void*)(A + (size_t)(m0 + row) * K + k0 + cs),
                (__attribute__((address_space(3))) void*)&As[bufi][ldsoff], 16, 0, 0);
            __builtin_amdgcn_global_load_lds(
                (const __attribute__((address_space(1))) void*)(B + (size_t)(n0 + row) * K + k0 + cs),
                (__attribute__((address_space(3))) void*)&Bs[bufi][ldsoff], 16, 0, 0);
        }
    };

    const int nks = K >> 5;
    stage(0, 0);
    stage(1, 32);

    const int colA = (lh ^ (lr & 3)) << 3;
    int cur = 0;
    for (int ks = 0; ks < nks; ks++) {
        if (ks == nks - 1)
            asm volatile("s_waitcnt vmcnt(0) lgkmcnt(0)" ::: "memory");
        else
            asm volatile("s_waitcnt vmcnt(4) lgkmcnt(0)" ::: "memory");
        __builtin_amdgcn_s_barrier();
        __builtin_amdgcn_sched_barrier(0);
        if (ks + 2 < nks) stage((ks + 2) % 3, (ks + 2) << 5);
        bf16x8 af[4], bfr[4];
#pragma unroll
        for (int i = 0; i < 4; i++)
            af[i] = *reinterpret_cast<const bf16x8*>(&As[cur][(wr * 64 + i * 16 + lr) * 32 + colA]);
#pragma unroll
        for (int i = 0; i < 4; i++)
            bfr[i] = *reinterpret_cast<const bf16x8*>(&Bs[cur][(wc * 64 + i * 16 + lr) * 32 + colA]);
        __builtin_amdgcn_s_setprio(1);
#pragma unroll
        for (int mi = 0; mi < 4; mi++)
#pragma unroll
            for (int ni = 0; ni < 4; ni++)
                acc[mi][ni] = __builtin_amdgcn_mfma_f32_16x16x32_bf16(af[mi], bfr[ni], acc[mi][ni], 0, 0, 0);
        __builtin_amdgcn_s_setprio(0);
        cur = (cur + 1) % 3;
    }

    float sgn = 0.f, qgn = 0.f;   // fused GN partial stats (EPI==0)
#pragma unroll
    for (int mi = 0; mi < 4; mi++) {
#pragma unroll
        for (int ni = 0; ni < 4; ni++) {
#pragma unroll
            for (int r = 0; r < 4; r++) {
                const int row = m0 + wr * 64 + mi * 16 + lh * 4 + r;
                const int col = n0 + wc * 64 + ni * 16 + lr;
                float v = acc[mi][ni][r];
                if constexpr (EPI == 0) {
                    v += bias[bz * 512 + col];
                    sgn += v; qgn += v * v;
                    ((unsigned short*)C0)[(size_t)bz * sC + (size_t)row * 512 + col] = f2bfu(v);
                } else if constexpr (EPI == 2) {
                    const float sg = 1.0f / (1.0f + __expf(-v));
                    ((unsigned short*)C0)[(size_t)bz * sC + (size_t)row * 2048 + col] = f2bfu(sg);
                } else {
                    ((float*)C0)[(size_t)row * 512 + col] = v + bias[col];
                }
            }
        }
    }
    if constexpr (EPI == 0) {
        // wave holds one (b,g): b = by>>4, g = bx*2+wc
#pragma unroll
        for (int s = 1; s < 64; s <<= 1) {
            sgn += __shfl_xor(sgn, s);
            qgn += __shfl_xor(qgn, s);
        }
        if (l == 0) {
            const int bg = ((by >> 4) << 3) + bx * 2 + wc;
            float* part = (float*)C1;
            atomicAdd(&part[(bz * 32 + bg) * 2 + 0], sgn);
            atomicAdd(&part[(bz * 32 + bg) * 2 + 1], qgn);
        }
    }
}

// ---------------- qkv GEMM: same core, pooled LDS, vT tiles transposed via LDS ----------
// grid 768 (nx=12, ny=64).  bx<8: q/k scalar stores (coalesced along d).
// bx>=8: all-vT tile -> LDS transpose T[cg][n] (stride 136, 16B-aligned rows) -> uint4
// stores coalesced along n.  Kills the 16x write amplification of the d-major scatter.
__global__ __launch_bounds__(256) void gemm_qkv(
    const unsigned short* __restrict__ A, const unsigned short* __restrict__ B,
    unsigned short* __restrict__ qbuf, unsigned short* __restrict__ kbuf,
    unsigned short* __restrict__ vtb) {
    __shared__ unsigned short pool[24576];       // As = pool[0..12287], Bs = pool[12288..]
    int lin = blockIdx.x;
    lin = (lin & 7) * 96 + (lin >> 3);           // 768 = 8*96
    const int bx = lin % 12;
    const int by = lin / 12;
    const int tid = threadIdx.x;
    const int l = tid & 63, w = tid >> 6;
    const int wr = w >> 1, wc = w & 1, lr = l & 15, lh = l >> 4;
    const int m0 = by * 128, n0 = bx * 128;
    f32x4 acc[4][4] = {};

    const int srow = l >> 2, sslot = l & 3;
    auto stage = [&](int bufi, int k0) {
#pragma unroll
        for (int i = 0; i < 2; i++) {
            const int row = w * 32 + i * 16 + srow;
            const int cs = (sslot ^ (row & 3)) * 8;
            const int ldsoff = bufi * 4096 + (w * 32 + i * 16) * 32;
            __builtin_amdgcn_global_load_lds(
                (const __attribute__((address_space(1))) void*)(A + (size_t)(m0 + row) * 512 + k0 + cs),
                (__attribute__((address_space(3))) void*)&pool[ldsoff], 16, 0, 0);
            __builtin_amdgcn_global_load_lds(
                (const __attribute__((address_space(1))) void*)(B + (size_t)(n0 + row) * 512 + k0 + cs),
                (__attribute__((address_space(3))) void*)&pool[12288 + ldsoff], 16, 0, 0);
        }
    };

    stage(0, 0);
    stage(1, 32);

    const int colA = (lh ^ (lr & 3)) << 3;
    int cur = 0;
    for (int ks = 0; ks < 16; ks++) {
        if (ks == 15)
            asm volatile("s_waitcnt vmcnt(0) lgkmcnt(0)" ::: "memory");
        else
            asm volatile("s_waitcnt vmcnt(4) lgkmcnt(0)" ::: "memory");
        __builtin_amdgcn_s_barrier();
        __builtin_amdgcn_sched_barrier(0);
        if (ks + 2 < 16) stage((ks + 2) % 3, (ks + 2) << 5);
        bf16x8 af[4], bfr[4];
#pragma unroll
        for (int i = 0; i < 4; i++)
            af[i] = *reinterpret_cast<const bf16x8*>(&pool[cur * 4096 + (wr * 64 + i * 16 + lr) * 32 + colA]);
#pragma unroll
        for (int i = 0; i < 4; i++)
            bfr[i] = *reinterpret_cast<const bf16x8*>(&pool[12288 + cur * 4096 + (wc * 64 + i * 16 + lr) * 32 + colA]);
        __builtin_amdgcn_s_setprio(1);
#pragma unroll
        for (int mi = 0; mi < 4; mi++)
#pragma unroll
            for (int ni = 0; ni < 4; ni++)
                acc[mi][ni] = __builtin_amdgcn_mfma_f32_16x16x32_bf16(af[mi], bfr[ni], acc[mi][ni], 0, 0, 0);
        __builtin_amdgcn_s_setprio(0);
        cur = (cur + 1) % 3;
    }

    if (bx < 8) {
        // q/k tiles: scalar stores, coalesced along d (lr -> consecutive addresses)
#pragma unroll
        for (int mi = 0; mi < 4; mi++) {
#pragma unroll
            for (int ni = 0; ni < 4; ni++) {
#pragma unroll
                for (int r = 0; r < 4; r++) {
                    const int row = m0 + wr * 64 + mi * 16 + lh * 4 + r;
                    const int col = n0 + wc * 64 + ni * 16 + lr;
                    const float v = acc[mi][ni][r];
                    const int part_ = col >> 9, hh = (col >> 6) & 7, d = col & 63;
                    const int b = row >> 11, n = row & 2047;
                    const size_t bh = (size_t)(b * 8 + hh);
                    if (part_ == 0)
                        qbuf[(bh * 2048 + n) * 64 + d] = f2bfu(v * 0.1803368801111244f);
                    else
                        kbuf[(bh * 2048 + n) * 64 + d] = f2bfu(v);
                }
            }
        }
    } else {
        // vT tile (128 cg x 128 n): transpose through LDS, store coalesced along n.
        // All waves done reading pool (own reads drained + barrier) before overwrite.
        asm volatile("s_waitcnt lgkmcnt(0)" ::: "memory");
        __builtin_amdgcn_s_barrier();
        __builtin_amdgcn_sched_barrier(0);
        // write: T[cgrel*136 + n_rel], r-quad packed as uint2 (8B aligned)
#pragma unroll
        for (int mi = 0; mi < 4; mi++) {
#pragma unroll
            for (int ni = 0; ni < 4; ni++) {
                const int cgrel = wc * 64 + ni * 16 + lr;
                const int nr0 = wr * 64 + mi * 16 + lh * 4;
                unsigned int w0 = (unsigned int)f2bfu(acc[mi][ni][0]) | ((unsigned int)f2bfu(acc[mi][ni][1]) << 16);
                unsigned int w1 = (unsigned int)f2bfu(acc[mi][ni][2]) | ((unsigned int)f2bfu(acc[mi][ni][3]) << 16);
                uint2 pk2; pk2.x = w0; pk2.y = w1;
                *reinterpret_cast<uint2*>(&pool[cgrel * 136 + nr0]) = pk2;
            }
        }
        asm volatile("s_waitcnt lgkmcnt(0)" ::: "memory");
        __builtin_amdgcn_s_barrier();
        __builtin_amdgcn_sched_barrier(0);
        // read back + coalesced store: thread -> (cg = tid>>1, half = tid&1), 8 x uint4
        const int cg = tid >> 1, half = tid & 1;
        const int b = by >> 4;
        const int nbase = (by & 15) * 128;
        const int cg0 = n0 - 1024;
        unsigned short* dstp = vtb + ((size_t)(b * 512 + cg0 + cg)) * 2048 + nbase + half * 64;
#pragma unroll
        for (int c = 0; c < 8; c++) {
            uint4 vv = *reinterpret_cast<const uint4*>(&pool[cg * 136 + half * 64 + c * 8]);
            *reinterpret_cast<uint4*>(dstp + c * 8) = vv;
        }
    }
}

// ---------------- GroupNorm apply (in place), stats finish folded in [R9-verified] ------
__global__ __launch_bounds__(256) void gn_apply(unsigned short* __restrict__ c1,
                                                unsigned short* __restrict__ c2,
                                                const float* __restrict__ part,
                                                const float* __restrict__ g1, const float* __restrict__ b1,
                                                const float* __restrict__ g2, const float* __restrict__ b2) {
    __shared__ float sst[2][32][2];
    const int tid = threadIdx.x;
    if (tid < 64) {
        const int z = tid >> 5, bg = tid & 31;
        const float S = part[(z * 32 + bg) * 2 + 0];
        const float Q = part[(z * 32 + bg) * 2 + 1];
        const float inv = 1.0f / 131072.0f;
        const float m = S * inv;
        const float v = fmaxf(Q * inv - m * m, 0.f);
        sst[z][bg][0] = m;
        sst[z][bg][1] = rsqrtf(v + 1e-5f);
    }
    __syncthreads();
    int i = blockIdx.x * 256 + tid;
    const int stride = gridDim.x * 256;
    for (; i < 524288; i += stride) {
        const size_t e = (size_t)i * 8;
        const int b = (int)(e >> 20);
        const int o = (int)(e & 511);
        const int g = o >> 6;
        const int bg = (b << 3) + g;
        const float m1 = sst[0][bg][0], r1 = sst[0][bg][1];
        const float m2 = sst[1][bg][0], r2 = sst[1][bg][1];
        uint4 v1 = *reinterpret_cast<const uint4*>(c1 + e);
        uint4 v2 = *reinterpret_cast<const uint4*>(c2 + e);
        unsigned int a1[4] = {v1.x, v1.y, v1.z, v1.w};
        unsigned int a2[4] = {v2.x, v2.y, v2.z, v2.w};
        unsigned int o1[4], o2[4];
#pragma unroll
        for (int j = 0; j < 4; j++) {
            const int oo = o + j * 2;
            float x0 = (bfu2f(a1[j] & 0xffffu) - m1) * r1 * g1[oo] + b1[oo];
            float x1 = (bfu2f(a1[j] >> 16) - m1) * r1 * g1[oo + 1] + b1[oo + 1];
            o1[j] = (unsigned int)f2bfu(x0) | ((unsigned int)f2bfu(x1) << 16);
            float y0 = (bfu2f(a2[j] & 0xffffu) - m2) * r2 * g2[oo] + b2[oo];
            float y1 = (bfu2f(a2[j] >> 16) - m2) * r2 * g2[oo + 1] + b2[oo + 1];
            o2[j] = (unsigned int)f2bfu(y0) | ((unsigned int)f2bfu(y1) << 16);
        }
        uint4 w1; w1.x = o1[0]; w1.y = o1[1]; w1.z = o1[2]; w1.w = o1[3];
        uint4 w2; w2.x = o2[0]; w2.y = o2[1]; w2.z = o2[2]; w2.w = o2[3];
        *reinterpret_cast<uint4*>(c1 + e) = w1;
        *reinterpret_cast<uint4*>(c2 + e) = w2;
    }
}

// ---------------- fused flash attention, 8-wave blocks, KVBLK=128 [R14-verified] --------
__global__ __launch_bounds__(512, 4) void attn_fused(
    const unsigned short* __restrict__ qb, const unsigned short* __restrict__ kb,
    const unsigned short* __restrict__ vT, const unsigned short* __restrict__ pea,
    unsigned short* __restrict__ hbuf) {
    __shared__ unsigned short Ks[2][128 * 64];
    __shared__ unsigned short Vs[2][64 * 128];
    __shared__ unsigned short Pl[8][16 * 64];
    const int tid = threadIdx.x, l = tid & 63, w = tid >> 6;
    const int lr = l & 15, lh = l >> 4;
    const int bid = blockIdx.x;
    const int h = bid >> 6, rst = bid & 63, nt = rst & 15, b = rst >> 4;
    const size_t bh = (size_t)(b * 8 + h);
    const unsigned short* qp = qb + bh * 2048 * 64;
    const unsigned short* kp = kb + bh * 2048 * 64;
    const unsigned short* vp = vT + bh * 64 * 2048;
    const unsigned short* pep = pea + (size_t)b * 2048 * 2048;   // [q][k] orientation
    const int qrow = nt * 128 + 16 * w + lr;                     // this lane's q-row

    bf16x8 qf[2];
    qf[0] = *reinterpret_cast<const bf16x8*>(qp + (size_t)qrow * 64 + lh * 8);
    qf[1] = *reinterpret_cast<const bf16x8*>(qp + (size_t)qrow * 64 + 32 + lh * 8);

    const int swz = (lr & 7) << 4;                       // byte XOR
    const int colK0 = ((16 * lh) ^ swz) >> 1;            // Ks row stride 64 shorts
    const int colK1 = ((64 + 16 * lh) ^ swz) >> 1;
    int colV[4];                                          // Vs row stride 128 shorts
#pragma unroll
    for (int c = 0; c < 4; c++) colV[c] = ((64 * c + 16 * lh) ^ swz) >> 1;

    const unsigned short* perp = pep + (size_t)qrow * 2048;
    uint2 peR[8];
#pragma unroll
    for (int mf = 0; mf < 8; mf++)
        peR[mf] = *reinterpret_cast<const uint2*>(perp + 16 * mf + 4 * lh);

    f32x4 oacc[4] = {};
    float mrun = -1e30f, lrun = 0.f;

    auto stage_kv = [&](int bufi, int m0) {
#pragma unroll
        for (int i = 0; i < 2; i++) {
            const int kc = w * 128 + i * 64 + l;          // K chunk id
            const int krow = kc >> 3, kslot = kc & 7;
            const int kcs = (kslot ^ (krow & 7)) * 8;
            __builtin_amdgcn_global_load_lds(
                (const __attribute__((address_space(1))) void*)(kp + (size_t)(m0 + krow) * 64 + kcs),
                (__attribute__((address_space(3))) void*)&Ks[bufi][(w * 128 + i * 64) * 8], 16, 0, 0);
            const int vrow = kc >> 4, vslot = kc & 15;
            const int vcs = (vslot ^ (vrow & 7)) * 8;
            __builtin_amdgcn_global_load_lds(
                (const __attribute__((address_space(1))) void*)(vp + (size_t)vrow * 2048 + m0 + vcs),
                (__attribute__((address_space(3))) void*)&Vs[bufi][(w * 128 + i * 64) * 8], 16, 0, 0);
        }
    };

    stage_kv(0, 0);
    asm volatile("s_waitcnt vmcnt(0)" ::: "memory");
    __builtin_amdgcn_s_barrier();
    __builtin_amdgcn_sched_barrier(0);

    for (int mt = 0; mt < 16; mt++) {
        const int cur = mt & 1;
        if (mt + 1 < 16) stage_kv(cur ^ 1, (mt + 1) * 128);
        const unsigned short* Kb = Ks[cur];
        const unsigned short* Vb = Vs[cur];

        f32x4 st[8];
        __builtin_amdgcn_s_setprio(1);
#pragma unroll
        for (int mf = 0; mf < 8; mf++) {
            f32x4 z = {};
            bf16x8 kf0 = *reinterpret_cast<const bf16x8*>(&Kb[(mf * 16 + lr) * 64 + colK0]);
            bf16x8 kf1 = *reinterpret_cast<const bf16x8*>(&Kb[(mf * 16 + lr) * 64 + colK1]);
            z = __builtin_amdgcn_mfma_f32_16x16x32_bf16(kf0, qf[0], z, 0, 0, 0);
            st[mf] = __builtin_amdgcn_mfma_f32_16x16x32_bf16(kf1, qf[1], z, 0, 0, 0);
        }
        __builtin_amdgcn_s_setprio(0);

        float p[8][4];
#pragma unroll
        for (int mf = 0; mf < 8; mf++) {
            p[mf][0] = st[mf][0] * bfu2f(peR[mf].x & 0xffffu);
            p[mf][1] = st[mf][1] * bfu2f(peR[mf].x >> 16);
            p[mf][2] = st[mf][2] * bfu2f(peR[mf].y & 0xffffu);
            p[mf][3] = st[mf][3] * bfu2f(peR[mf].y >> 16);
        }
        uint2 peN[8];
        if (mt + 1 < 16) {
            const unsigned short* pn = perp + (mt + 1) * 128;
#pragma unroll
            for (int mf = 0; mf < 8; mf++)
                peN[mf] = *reinterpret_cast<const uint2*>(pn + 16 * mf + 4 * lh);
        }
        float pm = fmaxf(p[0][0], p[0][1]);
        pm = fmaxf(fmaxf(pm, p[0][2]), p[0][3]);
#pragma unroll
        for (int mf = 1; mf < 8; mf++) {
            pm = fmaxf(fmaxf(pm, p[mf][0]), p[mf][1]);
            pm = fmaxf(fmaxf(pm, p[mf][2]), p[mf][3]);
        }
        pm = fmaxf(pm, __shfl_xor(pm, 16));
        pm = fmaxf(pm, __shfl_xor(pm, 32));
        if (__any(pm > mrun + 11.5416f)) {
            const float mnew = fmaxf(mrun, pm);
            const float fac = __builtin_amdgcn_exp2f(mrun - mnew);
            lrun *= fac;
#pragma unroll
            for (int df = 0; df < 4; df++)
#pragma unroll
                for (int r = 0; r < 4; r++) oacc[df][r] *= fac;
            mrun = mnew;
        }
        float ss = 0.f;
        unsigned int pk[16];
#pragma unroll
        for (int mf = 0; mf < 8; mf++) {
#pragma unroll
            for (int t = 0; t < 2; t++) {
                const float a = __builtin_amdgcn_exp2f(p[mf][2 * t] - mrun);
                const float c = __builtin_amdgcn_exp2f(p[mf][2 * t + 1] - mrun);
                unsigned int pkv;
                asm("v_cvt_pk_bf16_f32 %0, %1, %2" : "=v"(pkv) : "v"(a), "v"(c));
                pk[mf * 2 + t] = pkv;
                ss += a + c;
            }
        }
        ss += __shfl_xor(ss, 16);
        ss += __shfl_xor(ss, 32);
        lrun += ss;
        unsigned short* PlW = Pl[w];
        const int plswz = (lr & 7) << 4;               // byte XOR within 128B row
#pragma unroll
        for (int kh = 0; kh < 2; kh++) {
#pragma unroll
            for (int mq = 0; mq < 4; mq++)
#pragma unroll
                for (int t = 0; t < 2; t++) {
                    const int cb = (mq * 32 + lh * 8 + 4 * t) ^ plswz;
                    *reinterpret_cast<unsigned int*>(&PlW[lr * 64 + (cb >> 1)]) = pk[(kh * 4 + mq) * 2 + t];
                }
            bf16x8 pb0 = *reinterpret_cast<const bf16x8*>(&PlW[lr * 64 + (((lh * 16) ^ plswz) >> 1)]);
            bf16x8 pb1 = *reinterpret_cast<const bf16x8*>(&PlW[lr * 64 + (((64 + lh * 16) ^ plswz) >> 1)]);
            __builtin_amdgcn_s_setprio(1);
#pragma unroll
            for (int df = 0; df < 4; df++) {
                bf16x8 vf0 = *reinterpret_cast<const bf16x8*>(&Vb[(df * 16 + lr) * 128 + colV[kh * 2]]);
                bf16x8 vf1 = *reinterpret_cast<const bf16x8*>(&Vb[(df * 16 + lr) * 128 + colV[kh * 2 + 1]]);
                oacc[df] = __builtin_amdgcn_mfma_f32_16x16x32_bf16(vf0, pb0, oacc[df], 0, 0, 0);
                oacc[df] = __builtin_amdgcn_mfma_f32_16x16x32_bf16(vf1, pb1, oacc[df], 0, 0, 0);
            }
            __builtin_amdgcn_s_setprio(0);
        }
        if (mt + 1 < 16) {
            asm volatile("s_waitcnt vmcnt(0) lgkmcnt(0)" ::: "memory");
            __builtin_amdgcn_s_barrier();
            __builtin_amdgcn_sched_barrier(0);
#pragma unroll
            for (int mf = 0; mf < 8; mf++) peR[mf] = peN[mf];
        }
    }
    const float inv = 1.0f / lrun;
    const size_t base = ((size_t)b * 2048 + qrow) * 512 + h * 64;
#pragma unroll
    for (int df = 0; df < 4; df++) {
#pragma unroll
        for (int t = 0; t < 2; t++) {
            const unsigned int ua = f2bfu(oacc[df][2 * t] * inv);
            const unsigned int uc = f2bfu(oacc[df][2 * t + 1] * inv);
            *reinterpret_cast<unsigned int*>(&hbuf[base + 16 * df + 4 * lh + 2 * t]) = ua | (uc << 16);
        }
    }
}

extern "C" void kernel_launch(void* const* d_in, const int* in_sizes, int n_in,
                              void* d_out, int out_size, void* d_ws, size_t ws_size,
                              hipStream_t stream) {
    const float* x       = (const float*)d_in[0];
    const float* pe      = (const float*)d_in[1];
    const float* qkv_w   = (const float*)d_in[2];
    const float* proj_w  = (const float*)d_in[3];
    const float* proj_b  = (const float*)d_in[4];
    const float* conv1_w = (const float*)d_in[5];
    const float* conv1_b = (const float*)d_in[6];
    const float* gn1_g   = (const float*)d_in[7];
    const float* gn1_b   = (const float*)d_in[8];
    const float* conv2_w = (const float*)d_in[9];
    const float* conv2_b = (const float*)d_in[10];
    const float* gn2_g   = (const float*)d_in[11];
    const float* gn2_b   = (const float*)d_in[12];
    float* out = (float*)d_out;

    char* ws = (char*)d_ws;
    size_t off = 0;
    auto alloc = [&](size_t bytes) -> void* {
        void* p = ws + off;
        off += (bytes + 255) & ~(size_t)255;
        return p;
    };
    unsigned short* xb     = (unsigned short*)alloc(8388608);   // x bf16 [B*N, C]
    unsigned short* peb    = (unsigned short*)alloc(8388608);   // pe bf16
    unsigned short* qkvwb  = (unsigned short*)alloc(1572864);   // qkv_w bf16 [1536,512]
    unsigned short* projwb = (unsigned short*)alloc(524288);
    unsigned short* w1b    = (unsigned short*)alloc(524288);    // w1b/w2b contiguous (sB=262144)
    unsigned short* w2b    = (unsigned short*)alloc(524288);
    unsigned short* c1b    = (unsigned short*)alloc(8388608);   // c1b/c2b contiguous (sC=4194304)
    unsigned short* c2b    = (unsigned short*)alloc(8388608);
    unsigned short* qbuf   = (unsigned short*)alloc(8388608);   // [B,H,N,D] (q pre-scaled)
    unsigned short* kbuf   = (unsigned short*)alloc(8388608);
    unsigned short* vtb    = (unsigned short*)alloc(8388608);   // [B,H,D,N]
    unsigned short* peatt  = (unsigned short*)alloc(33554432);  // pe_attn [B,N(q),N(k)] bf16
    unsigned short* hbuf   = (unsigned short*)alloc(8388608);   // [B,N,C] bf16
    float* part            = (float*)alloc(512);                // GN stats [2][32][2]
    float* biasws          = (float*)alloc(4096);               // conv biases [2][512]

    dim3 blk(256);
    hipMemsetAsync(part, 0, 512, stream);
    cvt_all<<<2048, blk, 0, stream>>>(x, xb, pe, peb, qkv_w, qkvwb, proj_w, projwb,
                                      conv1_w, w1b, conv2_w, w2b, conv1_b, conv2_b, biasws);

    // conv1+conv2 in one launch (bz selects weights/bias/output); GN stats via atomics
    gemm_nt<0><<<dim3(512), blk, 0, stream>>>(peb, w1b, c1b, part, nullptr, biasws,
                                              512, 0, 262144, 4194304, 4, 64);
    gn_apply<<<1024, blk, 0, stream>>>(c1b, c2b, part, gn1_g, gn1_b, gn2_g, gn2_b);
    // qkv = x @ qkv_w.T -> q (x0.125*log2e), k [B,H,N,D]; vT [B,H,D,N] via LDS transpose
    gemm_qkv<<<dim3(768), blk, 0, stream>>>(xb, qkvwb, qbuf, kbuf, vtb);
    // pe_attn[b][n][m] = sigmoid(sum_k p1[n][k] p2[m][k])  ([q][k] orientation)
    gemm_nt<2><<<dim3(1024), blk, 0, stream>>>(c1b, c2b, peatt, nullptr, nullptr, nullptr,
                                               512, 1048576, 1048576, 4194304, 16, 16);
    attn_fused<<<dim3(512), dim3(512), 0, stream>>>(qbuf, kbuf, vtb, peatt, hbuf);
    // proj: out = h @ proj_w.T + proj_b (f32)
    gemm_nt<3><<<dim3(256), blk, 0, stream>>>(hbuf, projwb, out, nullptr, nullptr, proj_b,
                                              512, 0, 0, 0, 4, 64);
}